// Round 3
// baseline (15128.860 us; speedup 1.0000x reference)
//
#include <hip/hip_runtime.h>
#include <hip/hip_bf16.h>
#include <cstddef>
#include <cstdint>

#define BB 1024
#define TT 64
#define CC 66
#define HH 1024
#define SS 12
#define LL 12
#define XROW (TT*CC)   // 4224 floats per batch row of x

typedef __attribute__((ext_vector_type(8))) __bf16 bfrag;
typedef __attribute__((ext_vector_type(4))) float f32x4;
typedef __attribute__((ext_vector_type(8))) short s8v;

__device__ __forceinline__ unsigned short f2bf(float f) {
  unsigned int u = __builtin_bit_cast(unsigned int, f);
  unsigned int r = u + 0x7FFFu + ((u >> 16) & 1u);
  return (unsigned short)(r >> 16);
}
__device__ __forceinline__ float bf2f(unsigned short h) {
  unsigned int u = ((unsigned int)h) << 16;
  return __builtin_bit_cast(float, u);
}

__device__ __forceinline__ void gload16(const void* g, void* l) {
  __builtin_amdgcn_global_load_lds(
      (const __attribute__((address_space(1))) unsigned int*)g,
      (__attribute__((address_space(3))) unsigned int*)l, 16, 0, 0);
}

// ---------------------------------------------------------------------------
// Split-bf16 MFMA GRU step, v2.
// Wgc row mapping within each 128-row jb tile: r = jhi*64 + g*16 + jlo,
// j = jb*32 + jhi*16 + jlo, g in {r,z,n_h,n_x}. So one wave (wn = jhi) holds
// all 4 gate groups for its 16 j's in its 4 N-fragments -> register epilogue.
// 16B-unit swizzle cb ^= (row&3) baked into global layouts (A and B sides).
// 2-phase pipelined K loop: stage(next buf) -> compute(cur buf) -> sync.
// Flat grid 512, XCD-chunked: each XCD owns 4 jb values (weights L2-resident).
// ---------------------------------------------------------------------------
__global__ __launch_bounds__(256) void gru_mfma(
    const unsigned short* __restrict__ Ahi, const unsigned short* __restrict__ Alo,
    const float* __restrict__ hprev,
    const unsigned short* __restrict__ Xhi, const unsigned short* __restrict__ Xlo,
    const unsigned short* __restrict__ Whi, const unsigned short* __restrict__ Wlo,
    const float* __restrict__ bi, const float* __restrict__ bh,
    float* __restrict__ hout_f32,
    unsigned short* __restrict__ hout_hi, unsigned short* __restrict__ hout_lo)
{
  __shared__ __align__(16) unsigned short AsH[2][64*32];
  __shared__ __align__(16) unsigned short AsL[2][64*32];
  __shared__ __align__(16) unsigned short BsH[2][128*32];
  __shared__ __align__(16) unsigned short BsL[2][128*32];

  const int tid = threadIdx.x, lane = tid & 63, wid = tid >> 6;
  // XCD-chunked decode: xcd = bid&7 owns jb in [4*xcd, 4*xcd+4)
  const int bid = blockIdx.x;
  const int idx = bid >> 3;
  const int jb = (bid & 7) * 4 + (idx & 3);
  const int b0 = (idx >> 2) * 64;
  const int wm = wid >> 1, wn = wid & 1;

  // epilogue coordinates: one j per lane, 8 m's per lane
  const int j = jb * 32 + wn * 16 + (lane & 15);
  const float b_r  = bi[j] + bh[j];
  const float b_z  = bi[HH + j] + bh[HH + j];
  const float b_nh = bh[2 * HH + j];
  const float b_nx = bi[2 * HH + j];
  float hp[2][4];
  #pragma unroll
  for (int mh = 0; mh < 2; ++mh)
    #pragma unroll
    for (int q = 0; q < 4; ++q) {
      int m = b0 + wm * 32 + mh * 16 + (lane >> 4) * 4 + q;
      hp[mh][q] = hprev[(size_t)m * HH + j];
    }

  const int aR = lane >> 2, aC = lane & 3;

  auto stage = [&](int bs, int kc) {
    const unsigned short *shi, *slo; size_t go;
    int row = wid * 16 + aR;
    if (kc < 32) {
      go = (size_t)(b0 + row) * 1024 + (size_t)kc * 32 + aC * 8;
      shi = Ahi; slo = Alo;
    } else {
      go = (size_t)(b0 + row) * 96 + (size_t)(kc - 32) * 32 + aC * 8;
      shi = Xhi; slo = Xlo;
    }
    gload16(shi + go, &AsH[bs][wid * 512]);
    gload16(slo + go, &AsL[bs][wid * 512]);
    size_t base = ((size_t)jb * 35 + kc) * 4096;
    size_t go0 = base + (size_t)(wid * 32 + aR) * 32 + aC * 8;
    gload16(Whi + go0,       &BsH[bs][wid * 1024]);
    gload16(Whi + go0 + 512, &BsH[bs][wid * 1024 + 512]);
    gload16(Wlo + go0,       &BsL[bs][wid * 1024]);
    gload16(Wlo + go0 + 512, &BsL[bs][wid * 1024 + 512]);
  };

  f32x4 acc[2][4] = {};

  stage(0, 0);
  __syncthreads();

  for (int kc = 0; kc < 35; ++kc) {
    const int cur = kc & 1;
    if (kc < 34) stage(cur ^ 1, kc + 1);   // prefetch flies under the MFMAs

    bfrag ah[2], al[2], bhf[4], blf[4];
    #pragma unroll
    for (int mh = 0; mh < 2; ++mh) {
      int r = wm * 32 + mh * 16 + (lane & 15);
      int cb = (lane >> 4) ^ (r & 3);
      int off = r * 32 + cb * 8;
      ah[mh] = __builtin_bit_cast(bfrag, *(const s8v*)(&AsH[cur][off]));
      al[mh] = __builtin_bit_cast(bfrag, *(const s8v*)(&AsL[cur][off]));
    }
    #pragma unroll
    for (int g = 0; g < 4; ++g) {
      int r = wn * 64 + g * 16 + (lane & 15);
      int cb = (lane >> 4) ^ (r & 3);
      int off = r * 32 + cb * 8;
      bhf[g] = __builtin_bit_cast(bfrag, *(const s8v*)(&BsH[cur][off]));
      blf[g] = __builtin_bit_cast(bfrag, *(const s8v*)(&BsL[cur][off]));
    }
    #pragma unroll
    for (int mh = 0; mh < 2; ++mh)
      #pragma unroll
      for (int g = 0; g < 4; ++g) {
        acc[mh][g] = __builtin_amdgcn_mfma_f32_16x16x32_bf16(ah[mh], bhf[g], acc[mh][g], 0, 0, 0);
        acc[mh][g] = __builtin_amdgcn_mfma_f32_16x16x32_bf16(ah[mh], blf[g], acc[mh][g], 0, 0, 0);
        acc[mh][g] = __builtin_amdgcn_mfma_f32_16x16x32_bf16(al[mh], bhf[g], acc[mh][g], 0, 0, 0);
      }
    __syncthreads();   // drains prefetch + makes next-buf write safe
  }

  // register-local gates epilogue
  #pragma unroll
  for (int mh = 0; mh < 2; ++mh)
    #pragma unroll
    for (int q = 0; q < 4; ++q) {
      int m = b0 + wm * 32 + mh * 16 + (lane >> 4) * 4 + q;
      float rr = acc[mh][0][q] + b_r;
      float zz = acc[mh][1][q] + b_z;
      float nh = acc[mh][2][q] + b_nh;
      float nx = acc[mh][3][q] + b_nx;
      float r = 1.f / (1.f + __expf(-rr));
      float z = 1.f / (1.f + __expf(-zz));
      float n = tanhf(nx + r * nh);
      float hv = (1.f - z) * n + z * hp[mh][q];
      hout_f32[(size_t)m * HH + j] = hv;
      unsigned short hi = f2bf(hv);
      float lo = hv - bf2f(hi);
      int cb = ((j >> 3) & 3) ^ (m & 3);
      size_t dst = (size_t)m * 1024 + (size_t)(j & ~31) + cb * 8 + (j & 7);
      hout_hi[dst] = hi;
      hout_lo[dst] = f2bf(lo);
    }
}

// ---------------------------------------------------------------------------
// Prep: build Wgc hi/lo. Row mapping: r = jhi*64 + g*16 + jlo.
// ---------------------------------------------------------------------------
__global__ __launch_bounds__(256) void prep_wgc(
    const float* __restrict__ Wh, const float* __restrict__ Wi,
    unsigned short* __restrict__ Whi, unsigned short* __restrict__ Wlo)
{
  size_t idx = (size_t)blockIdx.x * 256 + threadIdx.x;
  if (idx >= (size_t)4096 * 1120) return;
  int k = (int)(idx % 1120);
  int rg = (int)(idx / 1120);
  int jbv = rg >> 7, r = rg & 127;
  int jhi = r >> 6, rem = r & 63, g = rem >> 4, jlo = rem & 15;
  int j = jbv * 32 + jhi * 16 + jlo;
  float v = 0.f;
  if (g == 0)      v = (k < 1024) ? Wh[(size_t)j * HH + k]            : ((k < 1090) ? Wi[(size_t)j * CC + (k - 1024)] : 0.f);
  else if (g == 1) v = (k < 1024) ? Wh[(size_t)(HH + j) * HH + k]     : ((k < 1090) ? Wi[(size_t)(HH + j) * CC + (k - 1024)] : 0.f);
  else if (g == 2) v = (k < 1024) ? Wh[(size_t)(2 * HH + j) * HH + k] : 0.f;
  else             v = (k >= 1024 && k < 1090) ? Wi[(size_t)(2 * HH + j) * CC + (k - 1024)] : 0.f;
  unsigned short hi = f2bf(v);
  float lo = v - bf2f(hi);
  int kc = k >> 5, kk = k & 31;
  int cb = ((kk >> 3) ^ (r & 3)) & 3;
  size_t dst = (((size_t)jbv * 35 + kc) * 128 + r) * 32 + cb * 8 + (kk & 7);
  Whi[dst] = hi;
  Wlo[dst] = f2bf(lo);
}

// Prep: x tails for all 64 steps, padded 66->96, hi/lo, swizzle-baked
__global__ __launch_bounds__(256) void prep_xall(
    const float* __restrict__ x,
    unsigned short* __restrict__ Xhi, unsigned short* __restrict__ Xlo)
{
  size_t idx = (size_t)blockIdx.x * 256 + threadIdx.x;
  if (idx >= (size_t)TT * BB * 96) return;
  int kx = (int)(idx % 96);
  size_t rem = idx / 96;
  int b = (int)(rem % BB);
  int t = (int)(rem / BB);
  float v = (kx < CC) ? x[(size_t)b * XROW + (size_t)t * CC + kx] : 0.f;
  unsigned short hi = f2bf(v);
  float lo = v - bf2f(hi);
  int cb = (((kx >> 3) & 3) ^ (b & 3)) & 3;
  size_t dst = ((size_t)t * BB + b) * 96 + (size_t)(kx & ~31) + cb * 8 + (kx & 7);
  Xhi[dst] = hi;
  Xlo[dst] = f2bf(lo);
}

// ---------------------------------------------------------------------------
// wst row kernel (init only): dst[b*10*H + h] = enc_b[h] + src_row(b).encWT[:,h]
// ---------------------------------------------------------------------------
__global__ __launch_bounds__(256) void wst_row_kernel(
    const float* __restrict__ src, int src_stride,
    const float* __restrict__ encWT, const float* __restrict__ encb,
    float* __restrict__ dst)
{
  __shared__ float s[CC];
  int b = blockIdx.y;
  int h = blockIdx.x * 256 + threadIdx.x;
  if (threadIdx.x < CC) s[threadIdx.x] = src[(size_t)b * src_stride + threadIdx.x];
  __syncthreads();
  float acc = encb[h];
  #pragma unroll
  for (int k = 0; k < CC; ++k) acc = fmaf(s[k], encWT[(size_t)k * HH + h], acc);
  dst[(size_t)b * (10 * HH) + h] = acc;
}

__global__ __launch_bounds__(256) void transpose_encW(
    const float* __restrict__ W, float* __restrict__ WT)
{
  int k = blockIdx.x;
  int h = blockIdx.y * 256 + threadIdx.x;
  WT[(size_t)k * HH + h] = W[(size_t)h * CC + k];
}

__global__ __launch_bounds__(256) void copy_last_kernel(
    const float* __restrict__ x, float* __restrict__ last)
{
  int idx = blockIdx.x * 256 + threadIdx.x;
  if (idx < BB * CC) {
    int b = idx / CC, c = idx - b * CC;
    last[idx] = x[(size_t)b * XROW + 63 * CC + c];
  }
}

// ---------------------------------------------------------------------------
// MLP-mini kernel with fused wst-row: computes the new enc(last) row at the
// head (identical FMA order to wst_row_kernel), writes it to the ring for
// future steps, and uses it directly as f[:,10].
// ---------------------------------------------------------------------------
__global__ __launch_bounds__(256) void mlp_kernel(
    const float* __restrict__ whp, const float* __restrict__ hdec,
    float* __restrict__ wst, int ring0,
    const float* __restrict__ encWT, const float* __restrict__ encb,
    const float* __restrict__ seqW, const float* __restrict__ seqb,
    const float* __restrict__ lnA, const float* __restrict__ lnB,
    const float* __restrict__ outW, const float* __restrict__ outb,
    const float* __restrict__ mrgW, const float* __restrict__ mrgb,
    float* __restrict__ last, float* __restrict__ outp,
    unsigned short* __restrict__ lpH, unsigned short* __restrict__ lpL)
{
  int b = blockIdx.x, tid = threadIdx.x;
  int lane = tid & 63, wid = tid >> 6;
  __shared__ float sw[LL][SS][SS];
  __shared__ float sb[LL][SS];
  __shared__ float red[4][24];
  __shared__ float mustd[24];
  __shared__ float g_lds[HH];
  __shared__ float nc[CC];
  __shared__ float s_last[CC];
  for (int idx = tid; idx < LL*SS*SS; idx += 256) (&sw[0][0][0])[idx] = seqW[idx];
  for (int idx = tid; idx < LL*SS; idx += 256) (&sb[0][0])[idx] = seqb[idx];
  if (tid < CC) s_last[tid] = last[(size_t)b * CC + tid];
  __syncthreads();

  // fused wst row: enc projection of `last` (frame from previous step)
  const int slot9 = (ring0 == 0) ? 9 : ring0 - 1;   // == (ring0+9)%10
  float wnew[4];
  #pragma unroll
  for (int r = 0; r < 4; ++r) {
    int h = tid + r * 256;
    float a = encb[h];
    #pragma unroll 11
    for (int k = 0; k < CC; ++k) a = fmaf(s_last[k], encWT[(size_t)k * HH + h], a);
    wnew[r] = a;
    wst[((size_t)b * 10 + slot9) * HH + h] = a;
  }

  float fr[4][SS];
  {
    const float* whb = whp + (size_t)b * HH;
    const float* hb  = hdec + (size_t)b * HH;
    #pragma unroll
    for (int r = 0; r < 4; ++r) {
      int h = tid + r * 256;
      fr[r][0]  = whb[h];
      fr[r][11] = hb[h];
      #pragma unroll
      for (int w = 0; w < 9; ++w) {
        int slot = ring0 + w; if (slot >= 10) slot -= 10;
        fr[r][1 + w] = wst[((size_t)b * 10 + slot) * HH + h];
      }
      fr[r][10] = wnew[r];
    }
  }

  float y[4][SS];
  for (int l = 0; l < LL; ++l) {
    float ps[SS], pq[SS];
    #pragma unroll
    for (int s = 0; s < SS; ++s) {
      float bv = sb[l][s];
      float a0 = bv, a1 = bv, a2 = bv, a3 = bv;
      #pragma unroll
      for (int k = 0; k < SS; ++k) {
        float wv = sw[l][s][k];
        a0 = fmaf(fr[0][k], wv, a0);
        a1 = fmaf(fr[1][k], wv, a1);
        a2 = fmaf(fr[2][k], wv, a2);
        a3 = fmaf(fr[3][k], wv, a3);
      }
      y[0][s] = a0; y[1][s] = a1; y[2][s] = a2; y[3][s] = a3;
      ps[s] = a0 + a1 + a2 + a3;
      pq[s] = a0*a0 + a1*a1 + a2*a2 + a3*a3;
    }
    #pragma unroll
    for (int s = 0; s < SS; ++s) {
      #pragma unroll
      for (int o = 32; o > 0; o >>= 1) {
        ps[s] += __shfl_xor(ps[s], o);
        pq[s] += __shfl_xor(pq[s], o);
      }
    }
    if (lane == 0) {
      #pragma unroll
      for (int s = 0; s < SS; ++s) { red[wid][s] = ps[s]; red[wid][12 + s] = pq[s]; }
    }
    __syncthreads();
    if (tid < 12) {
      float S = red[0][tid] + red[1][tid] + red[2][tid] + red[3][tid];
      float Q = red[0][12+tid] + red[1][12+tid] + red[2][12+tid] + red[3][12+tid];
      float mu = S * (1.f / HH);
      float var = Q * (1.f / HH) - mu * mu;
      mustd[tid] = mu;
      mustd[12 + tid] = 1.f / sqrtf(var + 1e-5f);
    }
    __syncthreads();
    #pragma unroll
    for (int r = 0; r < 4; ++r) {
      int h = tid + r * 256;
      float al = lnA[(size_t)l * HH + h];
      float be = lnB[(size_t)l * HH + h];
      #pragma unroll
      for (int s = 0; s < SS; ++s)
        fr[r][s] += (y[r][s] - mustd[s]) * mustd[12 + s] * al + be;
    }
  }

  float mwv[SS];
  #pragma unroll
  for (int s = 0; s < SS; ++s) mwv[s] = mrgW[s];
  float smw = 0.f;
  #pragma unroll
  for (int s = 0; s < SS; ++s) smw += mwv[s];
  float mbv = mrgb[0];
  #pragma unroll
  for (int r = 0; r < 4; ++r) {
    float g = 0.f;
    #pragma unroll
    for (int s = 0; s < SS; ++s) g = fmaf(mwv[s], fr[r][s], g);
    g_lds[tid + r * 256] = g;
  }
  __syncthreads();
  for (int i = 0; i < 17; ++i) {
    int c = wid + 4 * i;
    if (c < CC) {
      const float* ow = outW + (size_t)c * HH;
      float acc = 0.f;
      #pragma unroll
      for (int q = 0; q < 16; ++q) acc = fmaf(g_lds[lane + q*64], ow[lane + q*64], acc);
      #pragma unroll
      for (int o = 32; o > 0; o >>= 1) acc += __shfl_xor(acc, o);
      if (lane == 0) nc[c] = acc + outb[c] * smw + mbv + s_last[c];
    }
  }
  __syncthreads();
  if (tid < CC) {
    float nv = nc[tid];
    outp[(size_t)b * XROW + tid] = nv;
    last[(size_t)b * CC + tid] = nv;
    unsigned short hi = f2bf(nv);
    float lo = nv - bf2f(hi);
    int cb = (((tid >> 3) & 3) ^ (b & 3)) & 3;
    size_t dst = (size_t)b * 96 + (size_t)(tid & ~31) + cb * 8 + (tid & 7);
    lpH[dst] = hi;
    lpL[dst] = f2bf(lo);
  }
}

// ---------------------------------------------------------------------------
extern "C" void kernel_launch(void* const* d_in, const int* in_sizes, int n_in,
                              void* d_out, int out_size, void* d_ws, size_t ws_size,
                              hipStream_t stream) {
  const float* x    = (const float*)d_in[0];
  const float* gWi  = (const float*)d_in[1];
  const float* gWh  = (const float*)d_in[2];
  const float* gbi  = (const float*)d_in[3];
  const float* gbh  = (const float*)d_in[4];
  const float* encW = (const float*)d_in[5];
  const float* encb = (const float*)d_in[6];
  const float* seqW = (const float*)d_in[7];
  const float* seqb = (const float*)d_in[8];
  const float* lnA  = (const float*)d_in[9];
  const float* lnB  = (const float*)d_in[10];
  const float* outW = (const float*)d_in[11];
  const float* outb = (const float*)d_in[12];
  const float* mrgW = (const float*)d_in[13];
  const float* mrgb = (const float*)d_in[14];
  float* out = (float*)d_out;

  char* p = (char*)d_ws;
  auto alloc = [&](size_t bytes) { char* r = p; p += (bytes + 255) & ~(size_t)255; return r; };
  float* encWT = (float*)alloc((size_t)CC * HH * 4);
  float* last  = (float*)alloc((size_t)BB * CC * 4);
  float* wst   = (float*)alloc((size_t)BB * 10 * HH * 4);
  float* hf[3];
  for (int i = 0; i < 3; ++i) hf[i] = (float*)alloc((size_t)BB * HH * 4);
  unsigned short* WgH = (unsigned short*)alloc((size_t)4096 * 1120 * 2);
  unsigned short* WgL = (unsigned short*)alloc((size_t)4096 * 1120 * 2);
  unsigned short* XaH = (unsigned short*)alloc((size_t)TT * BB * 96 * 2);
  unsigned short* XaL = (unsigned short*)alloc((size_t)TT * BB * 96 * 2);
  unsigned short* hhi[3]; unsigned short* hlo[3];
  for (int i = 0; i < 3; ++i) {
    hhi[i] = (unsigned short*)alloc((size_t)BB * HH * 2);
    hlo[i] = (unsigned short*)alloc((size_t)BB * HH * 2);
  }
  unsigned short* lpH = (unsigned short*)alloc((size_t)BB * 96 * 2);
  unsigned short* lpL = (unsigned short*)alloc((size_t)BB * 96 * 2);
  if ((size_t)(p - (char*)d_ws) > ws_size) return;  // insufficient workspace

  // ---- one-time prep ----
  prep_wgc<<<dim3((4096u * 1120u) / 256u), 256, 0, stream>>>(gWh, gWi, WgH, WgL);
  prep_xall<<<dim3(((unsigned)TT * BB * 96) / 256u), 256, 0, stream>>>(x, XaH, XaL);
  transpose_encW<<<dim3(CC, HH/256), 256, 0, stream>>>(encW, encWT);
  copy_last_kernel<<<dim3((BB*CC + 255)/256), 256, 0, stream>>>(x, last);
  hipMemsetAsync(hf[0], 0, (size_t)BB * HH * 4, stream);
  hipMemsetAsync(hhi[0], 0, (size_t)BB * HH * 2, stream);
  hipMemsetAsync(hlo[0], 0, (size_t)BB * HH * 2, stream);

  const dim3 ggrid(512);   // flat; XCD-chunked decode inside

  // ---- encoder: 63 GRU steps over x[:, 0..62, :] ----
  int cur = 0;
  for (int t = 0; t < 63; ++t) {
    int nxt = 1 - cur;
    gru_mfma<<<ggrid, 256, 0, stream>>>(
        hhi[cur], hlo[cur], hf[cur],
        XaH + (size_t)t * BB * 96, XaL + (size_t)t * BB * 96,
        WgH, WgL, gbi, gbh, hf[nxt], hhi[nxt], hlo[nxt]);
    cur = nxt;
  }
  // window_history = GRU(h_enc, x[:,63,:]) -> set 2 (persistent)
  gru_mfma<<<ggrid, 256, 0, stream>>>(
      hhi[cur], hlo[cur], hf[cur],
      XaH + (size_t)63 * BB * 96, XaL + (size_t)63 * BB * 96,
      WgH, WgL, gbi, gbh, hf[2], hhi[2], hlo[2]);

  // ---- initial wst ring: slots 0..8 = enc(x[:, 54..62, :]) ----
  for (int w = 0; w < 9; ++w)
    wst_row_kernel<<<dim3(HH/256, BB), 256, 0, stream>>>(
        x + (size_t)(54 + w) * CC, XROW, encWT, encb, wst + (size_t)w * HH);

  // ---- decoder: 64 steps (wst row for the new frame fused into mlp) ----
  int hc = 2;
  for (int t = 0; t < 64; ++t) {
    if (t > 0) {
      int hn = (t - 1) & 1;
      gru_mfma<<<ggrid, 256, 0, stream>>>(
          hhi[hc], hlo[hc], hf[hc], lpH, lpL,
          WgH, WgL, gbi, gbh, hf[hn], hhi[hn], hlo[hn]);
      hc = hn;
    }
    mlp_kernel<<<dim3(BB), 256, 0, stream>>>(
        hf[2], hf[hc], wst, t % 10, encWT, encb,
        seqW, seqb, lnA, lnB, outW, outb, mrgW, mrgb,
        last, out + (size_t)t * CC, lpH, lpL);
  }
}

// Round 4
// 10492.007 us; speedup vs baseline: 1.4419x; 1.4419x over previous
//
#include <hip/hip_runtime.h>
#include <hip/hip_bf16.h>
#include <cstddef>
#include <cstdint>

#define BB 1024
#define TT 64
#define CC 66
#define HH 1024
#define SS 12
#define LL 12
#define XROW (TT*CC)   // 4224 floats per batch row of x

typedef __attribute__((ext_vector_type(8))) __bf16 bfrag;
typedef __attribute__((ext_vector_type(4))) float f32x4;
typedef __attribute__((ext_vector_type(8))) short s8v;
typedef __attribute__((ext_vector_type(2))) float f2;

__device__ __forceinline__ unsigned short f2bf(float f) {
  unsigned int u = __builtin_bit_cast(unsigned int, f);
  unsigned int r = u + 0x7FFFu + ((u >> 16) & 1u);
  return (unsigned short)(r >> 16);
}
__device__ __forceinline__ float bf2f(unsigned short h) {
  unsigned int u = ((unsigned int)h) << 16;
  return __builtin_bit_cast(float, u);
}

__device__ __forceinline__ void gload16(const void* g, void* l) {
  __builtin_amdgcn_global_load_lds(
      (const __attribute__((address_space(1))) unsigned int*)g,
      (__attribute__((address_space(3))) unsigned int*)l, 16, 0, 0);
}

// DPP-based wave64 sum: result lands in lane 63. VALU-only (no LDS pipe).
template<int CTRL, int RM>
__device__ __forceinline__ float dppadd(float v) {
  int x = __builtin_amdgcn_update_dpp(0, __builtin_bit_cast(int, v),
                                      CTRL, RM, 0xF, true);
  return v + __builtin_bit_cast(float, x);
}
__device__ __forceinline__ float wave_sum63(float v) {
  v = dppadd<0x111, 0xF>(v);   // row_shr:1
  v = dppadd<0x112, 0xF>(v);   // row_shr:2
  v = dppadd<0x114, 0xF>(v);   // row_shr:4
  v = dppadd<0x118, 0xF>(v);   // row_shr:8  -> lane 15/31/47/63 hold row sums
  v = dppadd<0x142, 0xa>(v);   // row_bcast:15 -> lanes 31, 63 accumulate
  v = dppadd<0x143, 0xc>(v);   // row_bcast:31 -> lane 63 = full sum
  return v;
}

// ---------------------------------------------------------------------------
// Split-bf16 MFMA GRU step (unchanged from round 3).
// ---------------------------------------------------------------------------
__global__ __launch_bounds__(256) void gru_mfma(
    const unsigned short* __restrict__ Ahi, const unsigned short* __restrict__ Alo,
    const float* __restrict__ hprev,
    const unsigned short* __restrict__ Xhi, const unsigned short* __restrict__ Xlo,
    const unsigned short* __restrict__ Whi, const unsigned short* __restrict__ Wlo,
    const float* __restrict__ bi, const float* __restrict__ bh,
    float* __restrict__ hout_f32,
    unsigned short* __restrict__ hout_hi, unsigned short* __restrict__ hout_lo)
{
  __shared__ __align__(16) unsigned short AsH[2][64*32];
  __shared__ __align__(16) unsigned short AsL[2][64*32];
  __shared__ __align__(16) unsigned short BsH[2][128*32];
  __shared__ __align__(16) unsigned short BsL[2][128*32];

  const int tid = threadIdx.x, lane = tid & 63, wid = tid >> 6;
  const int bid = blockIdx.x;
  const int idx = bid >> 3;
  const int jb = (bid & 7) * 4 + (idx & 3);
  const int b0 = (idx >> 2) * 64;
  const int wm = wid >> 1, wn = wid & 1;

  const int j = jb * 32 + wn * 16 + (lane & 15);
  const float b_r  = bi[j] + bh[j];
  const float b_z  = bi[HH + j] + bh[HH + j];
  const float b_nh = bh[2 * HH + j];
  const float b_nx = bi[2 * HH + j];
  float hp[2][4];
  #pragma unroll
  for (int mh = 0; mh < 2; ++mh)
    #pragma unroll
    for (int q = 0; q < 4; ++q) {
      int m = b0 + wm * 32 + mh * 16 + (lane >> 4) * 4 + q;
      hp[mh][q] = hprev[(size_t)m * HH + j];
    }

  const int aR = lane >> 2, aC = lane & 3;

  auto stage = [&](int bs, int kc) {
    const unsigned short *shi, *slo; size_t go;
    int row = wid * 16 + aR;
    if (kc < 32) {
      go = (size_t)(b0 + row) * 1024 + (size_t)kc * 32 + aC * 8;
      shi = Ahi; slo = Alo;
    } else {
      go = (size_t)(b0 + row) * 96 + (size_t)(kc - 32) * 32 + aC * 8;
      shi = Xhi; slo = Xlo;
    }
    gload16(shi + go, &AsH[bs][wid * 512]);
    gload16(slo + go, &AsL[bs][wid * 512]);
    size_t base = ((size_t)jb * 35 + kc) * 4096;
    size_t go0 = base + (size_t)(wid * 32 + aR) * 32 + aC * 8;
    gload16(Whi + go0,       &BsH[bs][wid * 1024]);
    gload16(Whi + go0 + 512, &BsH[bs][wid * 1024 + 512]);
    gload16(Wlo + go0,       &BsL[bs][wid * 1024]);
    gload16(Wlo + go0 + 512, &BsL[bs][wid * 1024 + 512]);
  };

  f32x4 acc[2][4] = {};

  stage(0, 0);
  __syncthreads();

  for (int kc = 0; kc < 35; ++kc) {
    const int cur = kc & 1;
    if (kc < 34) stage(cur ^ 1, kc + 1);

    bfrag ah[2], al[2], bhf[4], blf[4];
    #pragma unroll
    for (int mh = 0; mh < 2; ++mh) {
      int r = wm * 32 + mh * 16 + (lane & 15);
      int cb = (lane >> 4) ^ (r & 3);
      int off = r * 32 + cb * 8;
      ah[mh] = __builtin_bit_cast(bfrag, *(const s8v*)(&AsH[cur][off]));
      al[mh] = __builtin_bit_cast(bfrag, *(const s8v*)(&AsL[cur][off]));
    }
    #pragma unroll
    for (int g = 0; g < 4; ++g) {
      int r = wn * 64 + g * 16 + (lane & 15);
      int cb = (lane >> 4) ^ (r & 3);
      int off = r * 32 + cb * 8;
      bhf[g] = __builtin_bit_cast(bfrag, *(const s8v*)(&BsH[cur][off]));
      blf[g] = __builtin_bit_cast(bfrag, *(const s8v*)(&BsL[cur][off]));
    }
    #pragma unroll
    for (int mh = 0; mh < 2; ++mh)
      #pragma unroll
      for (int g = 0; g < 4; ++g) {
        acc[mh][g] = __builtin_amdgcn_mfma_f32_16x16x32_bf16(ah[mh], bhf[g], acc[mh][g], 0, 0, 0);
        acc[mh][g] = __builtin_amdgcn_mfma_f32_16x16x32_bf16(ah[mh], blf[g], acc[mh][g], 0, 0, 0);
        acc[mh][g] = __builtin_amdgcn_mfma_f32_16x16x32_bf16(al[mh], bhf[g], acc[mh][g], 0, 0, 0);
      }
    __syncthreads();
  }

  #pragma unroll
  for (int mh = 0; mh < 2; ++mh)
    #pragma unroll
    for (int q = 0; q < 4; ++q) {
      int m = b0 + wm * 32 + mh * 16 + (lane >> 4) * 4 + q;
      float rr = acc[mh][0][q] + b_r;
      float zz = acc[mh][1][q] + b_z;
      float nh = acc[mh][2][q] + b_nh;
      float nx = acc[mh][3][q] + b_nx;
      float r = 1.f / (1.f + __expf(-rr));
      float z = 1.f / (1.f + __expf(-zz));
      float n = tanhf(nx + r * nh);
      float hv = (1.f - z) * n + z * hp[mh][q];
      hout_f32[(size_t)m * HH + j] = hv;
      unsigned short hi = f2bf(hv);
      float lo = hv - bf2f(hi);
      int cb = ((j >> 3) & 3) ^ (m & 3);
      size_t dst = (size_t)m * 1024 + (size_t)(j & ~31) + cb * 8 + (j & 7);
      hout_hi[dst] = hi;
      hout_lo[dst] = f2bf(lo);
    }
}

// ---------------------------------------------------------------------------
// Prep kernels (unchanged).
// ---------------------------------------------------------------------------
__global__ __launch_bounds__(256) void prep_wgc(
    const float* __restrict__ Wh, const float* __restrict__ Wi,
    unsigned short* __restrict__ Whi, unsigned short* __restrict__ Wlo)
{
  size_t idx = (size_t)blockIdx.x * 256 + threadIdx.x;
  if (idx >= (size_t)4096 * 1120) return;
  int k = (int)(idx % 1120);
  int rg = (int)(idx / 1120);
  int jbv = rg >> 7, r = rg & 127;
  int jhi = r >> 6, rem = r & 63, g = rem >> 4, jlo = rem & 15;
  int j = jbv * 32 + jhi * 16 + jlo;
  float v = 0.f;
  if (g == 0)      v = (k < 1024) ? Wh[(size_t)j * HH + k]            : ((k < 1090) ? Wi[(size_t)j * CC + (k - 1024)] : 0.f);
  else if (g == 1) v = (k < 1024) ? Wh[(size_t)(HH + j) * HH + k]     : ((k < 1090) ? Wi[(size_t)(HH + j) * CC + (k - 1024)] : 0.f);
  else if (g == 2) v = (k < 1024) ? Wh[(size_t)(2 * HH + j) * HH + k] : 0.f;
  else             v = (k >= 1024 && k < 1090) ? Wi[(size_t)(2 * HH + j) * CC + (k - 1024)] : 0.f;
  unsigned short hi = f2bf(v);
  float lo = v - bf2f(hi);
  int kc = k >> 5, kk = k & 31;
  int cb = ((kk >> 3) ^ (r & 3)) & 3;
  size_t dst = (((size_t)jbv * 35 + kc) * 128 + r) * 32 + cb * 8 + (kk & 7);
  Whi[dst] = hi;
  Wlo[dst] = f2bf(lo);
}

__global__ __launch_bounds__(256) void prep_xall(
    const float* __restrict__ x,
    unsigned short* __restrict__ Xhi, unsigned short* __restrict__ Xlo)
{
  size_t idx = (size_t)blockIdx.x * 256 + threadIdx.x;
  if (idx >= (size_t)TT * BB * 96) return;
  int kx = (int)(idx % 96);
  size_t rem = idx / 96;
  int b = (int)(rem % BB);
  int t = (int)(rem / BB);
  float v = (kx < CC) ? x[(size_t)b * XROW + (size_t)t * CC + kx] : 0.f;
  unsigned short hi = f2bf(v);
  float lo = v - bf2f(hi);
  int cb = (((kx >> 3) & 3) ^ (b & 3)) & 3;
  size_t dst = ((size_t)t * BB + b) * 96 + (size_t)(kx & ~31) + cb * 8 + (kx & 7);
  Xhi[dst] = hi;
  Xlo[dst] = f2bf(lo);
}

__global__ __launch_bounds__(256) void wst_row_kernel(
    const float* __restrict__ src, int src_stride,
    const float* __restrict__ encWT, const float* __restrict__ encb,
    float* __restrict__ dst)
{
  __shared__ float s[CC];
  int b = blockIdx.y;
  int h = blockIdx.x * 256 + threadIdx.x;
  if (threadIdx.x < CC) s[threadIdx.x] = src[(size_t)b * src_stride + threadIdx.x];
  __syncthreads();
  float acc = encb[h];
  #pragma unroll
  for (int k = 0; k < CC; ++k) acc = fmaf(s[k], encWT[(size_t)k * HH + h], acc);
  dst[(size_t)b * (10 * HH) + h] = acc;
}

__global__ __launch_bounds__(256) void transpose_encW(
    const float* __restrict__ W, float* __restrict__ WT)
{
  int k = blockIdx.x;
  int h = blockIdx.y * 256 + threadIdx.x;
  WT[(size_t)k * HH + h] = W[(size_t)h * CC + k];
}

__global__ __launch_bounds__(256) void copy_last_kernel(
    const float* __restrict__ x, float* __restrict__ last)
{
  int idx = blockIdx.x * 256 + threadIdx.x;
  if (idx < BB * CC) {
    int b = idx / CC, c = idx - b * CC;
    last[idx] = x[(size_t)b * XROW + 63 * CC + c];
  }
}

// ---------------------------------------------------------------------------
// MLP-mini v2: seqW/seqb via uniform scalar loads (SGPRs, no LDS staging);
// DPP wave reductions (no ds_swizzle); packed-f32 (v_pk_fma) row-pair math.
// Rows packed: pack p holds h = tid + 2p*256 (.x) and h = tid + (2p+1)*256 (.y).
// ---------------------------------------------------------------------------
__global__ __launch_bounds__(256) void mlp_kernel(
    const float* __restrict__ whp, const float* __restrict__ hdec,
    float* __restrict__ wst, int ring0,
    const float* __restrict__ encWT, const float* __restrict__ encb,
    const float* __restrict__ seqW, const float* __restrict__ seqb,
    const float* __restrict__ lnA, const float* __restrict__ lnB,
    const float* __restrict__ outW, const float* __restrict__ outb,
    const float* __restrict__ mrgW, const float* __restrict__ mrgb,
    float* __restrict__ last, float* __restrict__ outp,
    unsigned short* __restrict__ lpH, unsigned short* __restrict__ lpL)
{
  const int b = blockIdx.x, tid = threadIdx.x;
  const int lane = tid & 63, wid = tid >> 6;
  __shared__ float red[4][24];
  __shared__ f2 mustd2[SS];
  __shared__ float g_lds[HH];
  __shared__ float nc[CC];

  const int h0 = tid;          // pack 0: h0, h0+256
  const int h1 = tid + 512;    // pack 1: h1, h1+256

  // ---- fused wst row: enc projection of `last` (scalar-uniform reads) ----
  const int slot9 = (ring0 == 0) ? 9 : ring0 - 1;
  const float* lrow = last + (size_t)b * CC;   // uniform base -> s_load path
  f2 wnew[2];
  {
    f2 a0 = { encb[h0], encb[h0 + 256] };
    f2 a1 = { encb[h1], encb[h1 + 256] };
    #pragma unroll 11
    for (int k = 0; k < CC; ++k) {
      float lv = lrow[k];
      f2 lv2 = { lv, lv };
      f2 w0 = { encWT[(size_t)k * HH + h0], encWT[(size_t)k * HH + h0 + 256] };
      f2 w1 = { encWT[(size_t)k * HH + h1], encWT[(size_t)k * HH + h1 + 256] };
      a0 = __builtin_elementwise_fma(lv2, w0, a0);
      a1 = __builtin_elementwise_fma(lv2, w1, a1);
    }
    wnew[0] = a0; wnew[1] = a1;
    float* wd = wst + ((size_t)b * 10 + slot9) * HH;
    wd[h0] = a0.x; wd[h0 + 256] = a0.y;
    wd[h1] = a1.x; wd[h1 + 256] = a1.y;
  }

  // ---- load f (packed) ----
  f2 fr[2][SS];
  {
    const float* whb = whp + (size_t)b * HH;
    const float* hb  = hdec + (size_t)b * HH;
    fr[0][0]  = { whb[h0], whb[h0 + 256] };
    fr[1][0]  = { whb[h1], whb[h1 + 256] };
    fr[0][11] = { hb[h0], hb[h0 + 256] };
    fr[1][11] = { hb[h1], hb[h1 + 256] };
    #pragma unroll
    for (int w = 0; w < 9; ++w) {
      int slot = ring0 + w; if (slot >= 10) slot -= 10;
      const float* ws_ = wst + ((size_t)b * 10 + slot) * HH;
      fr[0][1 + w] = { ws_[h0], ws_[h0 + 256] };
      fr[1][1 + w] = { ws_[h1], ws_[h1 + 256] };
    }
    fr[0][10] = wnew[0];
    fr[1][10] = wnew[1];
  }

  // ---- 12 layers ----
  #pragma unroll 1
  for (int l = 0; l < LL; ++l) {
    const float* W  = seqW + (size_t)l * SS * SS;  // uniform -> SGPR loads
    const float* Bv = seqb + (size_t)l * SS;
    const float* lA = lnA + (size_t)l * HH;
    const float* lB = lnB + (size_t)l * HH;
    // per-h LN params (vector loads; issue early)
    f2 al[2], be[2];
    al[0] = { lA[h0], lA[h0 + 256] };  al[1] = { lA[h1], lA[h1 + 256] };
    be[0] = { lB[h0], lB[h0 + 256] };  be[1] = { lB[h1], lB[h1 + 256] };

    f2 y[2][SS];
    #pragma unroll
    for (int s = 0; s < SS; ++s) {
      float bv = Bv[s];
      f2 a0 = { bv, bv }, a1 = { bv, bv };
      #pragma unroll
      for (int k = 0; k < SS; ++k) {
        float wv = W[s * SS + k];
        f2 wv2 = { wv, wv };
        a0 = __builtin_elementwise_fma(fr[0][k], wv2, a0);
        a1 = __builtin_elementwise_fma(fr[1][k], wv2, a1);
      }
      y[0][s] = a0; y[1][s] = a1;
      f2 pp = a0 + a1;
      float ps = wave_sum63(pp.x + pp.y);
      f2 qq = __builtin_elementwise_fma(a0, a0, a1 * a1);
      float pq = wave_sum63(qq.x + qq.y);
      if (lane == 63) { red[wid][s] = ps; red[wid][12 + s] = pq; }
    }
    __syncthreads();
    if (tid < SS) {
      float S = red[0][tid] + red[1][tid] + red[2][tid] + red[3][tid];
      float Q = red[0][12 + tid] + red[1][12 + tid] + red[2][12 + tid] + red[3][12 + tid];
      float mu = S * (1.f / HH);
      float var = Q * (1.f / HH) - mu * mu;
      mustd2[tid] = { mu, 1.f / sqrtf(var + 1e-5f) };
    }
    __syncthreads();
    #pragma unroll
    for (int s = 0; s < SS; ++s) {
      f2 mi = mustd2[s];
      f2 mus = { mi.x, mi.x };
      f2 isd = { mi.y, mi.y };
      #pragma unroll
      for (int p = 0; p < 2; ++p) {
        f2 t = (y[p][s] - mus) * isd;
        fr[p][s] = __builtin_elementwise_fma(t, al[p], fr[p][s]) + be[p];
      }
    }
    __syncthreads();   // protect red/mustd2 reuse next layer
  }

  // ---- epilogue: g[h] = sum_s mrgW[s]*f[h][s]; new[c] = g . outW[c] + ... ----
  float smw = 0.f;
  f2 g[2] = { {0.f, 0.f}, {0.f, 0.f} };
  #pragma unroll
  for (int s = 0; s < SS; ++s) {
    float mv = mrgW[s];   // uniform -> SGPR
    smw += mv;
    f2 mv2 = { mv, mv };
    g[0] = __builtin_elementwise_fma(mv2, fr[0][s], g[0]);
    g[1] = __builtin_elementwise_fma(mv2, fr[1][s], g[1]);
  }
  g_lds[h0] = g[0].x; g_lds[h0 + 256] = g[0].y;
  g_lds[h1] = g[1].x; g_lds[h1 + 256] = g[1].y;
  const float mbv = mrgb[0];
  __syncthreads();
  #pragma unroll 1
  for (int i = 0; i < 17; ++i) {
    int c = wid + 4 * i;
    if (c < CC) {
      const float* ow = outW + (size_t)c * HH;
      float acc = 0.f;
      #pragma unroll
      for (int q = 0; q < 16; ++q) acc = fmaf(g_lds[lane + q * 64], ow[lane + q * 64], acc);
      acc = wave_sum63(acc);
      if (lane == 63) nc[c] = acc + outb[c] * smw + mbv + lrow[c];
    }
  }
  __syncthreads();
  if (tid < CC) {
    float nv = nc[tid];
    outp[(size_t)b * XROW + tid] = nv;
    last[(size_t)b * CC + tid] = nv;
    unsigned short hi = f2bf(nv);
    float lo = nv - bf2f(hi);
    int cb = (((tid >> 3) & 3) ^ (b & 3)) & 3;
    size_t dst = (size_t)b * 96 + (size_t)(tid & ~31) + cb * 8 + (tid & 7);
    lpH[dst] = hi;
    lpL[dst] = f2bf(lo);
  }
}

// ---------------------------------------------------------------------------
extern "C" void kernel_launch(void* const* d_in, const int* in_sizes, int n_in,
                              void* d_out, int out_size, void* d_ws, size_t ws_size,
                              hipStream_t stream) {
  const float* x    = (const float*)d_in[0];
  const float* gWi  = (const float*)d_in[1];
  const float* gWh  = (const float*)d_in[2];
  const float* gbi  = (const float*)d_in[3];
  const float* gbh  = (const float*)d_in[4];
  const float* encW = (const float*)d_in[5];
  const float* encb = (const float*)d_in[6];
  const float* seqW = (const float*)d_in[7];
  const float* seqb = (const float*)d_in[8];
  const float* lnA  = (const float*)d_in[9];
  const float* lnB  = (const float*)d_in[10];
  const float* outW = (const float*)d_in[11];
  const float* outb = (const float*)d_in[12];
  const float* mrgW = (const float*)d_in[13];
  const float* mrgb = (const float*)d_in[14];
  float* out = (float*)d_out;

  char* p = (char*)d_ws;
  auto alloc = [&](size_t bytes) { char* r = p; p += (bytes + 255) & ~(size_t)255; return r; };
  float* encWT = (float*)alloc((size_t)CC * HH * 4);
  float* last  = (float*)alloc((size_t)BB * CC * 4);
  float* wst   = (float*)alloc((size_t)BB * 10 * HH * 4);
  float* hf[3];
  for (int i = 0; i < 3; ++i) hf[i] = (float*)alloc((size_t)BB * HH * 4);
  unsigned short* WgH = (unsigned short*)alloc((size_t)4096 * 1120 * 2);
  unsigned short* WgL = (unsigned short*)alloc((size_t)4096 * 1120 * 2);
  unsigned short* XaH = (unsigned short*)alloc((size_t)TT * BB * 96 * 2);
  unsigned short* XaL = (unsigned short*)alloc((size_t)TT * BB * 96 * 2);
  unsigned short* hhi[3]; unsigned short* hlo[3];
  for (int i = 0; i < 3; ++i) {
    hhi[i] = (unsigned short*)alloc((size_t)BB * HH * 2);
    hlo[i] = (unsigned short*)alloc((size_t)BB * HH * 2);
  }
  unsigned short* lpH = (unsigned short*)alloc((size_t)BB * 96 * 2);
  unsigned short* lpL = (unsigned short*)alloc((size_t)BB * 96 * 2);
  if ((size_t)(p - (char*)d_ws) > ws_size) return;  // insufficient workspace

  // ---- one-time prep ----
  prep_wgc<<<dim3((4096u * 1120u) / 256u), 256, 0, stream>>>(gWh, gWi, WgH, WgL);
  prep_xall<<<dim3(((unsigned)TT * BB * 96) / 256u), 256, 0, stream>>>(x, XaH, XaL);
  transpose_encW<<<dim3(CC, HH/256), 256, 0, stream>>>(encW, encWT);
  copy_last_kernel<<<dim3((BB*CC + 255)/256), 256, 0, stream>>>(x, last);
  hipMemsetAsync(hf[0], 0, (size_t)BB * HH * 4, stream);
  hipMemsetAsync(hhi[0], 0, (size_t)BB * HH * 2, stream);
  hipMemsetAsync(hlo[0], 0, (size_t)BB * HH * 2, stream);

  const dim3 ggrid(512);   // flat; XCD-chunked decode inside

  // ---- encoder: 63 GRU steps over x[:, 0..62, :] ----
  int cur = 0;
  for (int t = 0; t < 63; ++t) {
    int nxt = 1 - cur;
    gru_mfma<<<ggrid, 256, 0, stream>>>(
        hhi[cur], hlo[cur], hf[cur],
        XaH + (size_t)t * BB * 96, XaL + (size_t)t * BB * 96,
        WgH, WgL, gbi, gbh, hf[nxt], hhi[nxt], hlo[nxt]);
    cur = nxt;
  }
  // window_history = GRU(h_enc, x[:,63,:]) -> set 2 (persistent)
  gru_mfma<<<ggrid, 256, 0, stream>>>(
      hhi[cur], hlo[cur], hf[cur],
      XaH + (size_t)63 * BB * 96, XaL + (size_t)63 * BB * 96,
      WgH, WgL, gbi, gbh, hf[2], hhi[2], hlo[2]);

  // ---- initial wst ring: slots 0..8 = enc(x[:, 54..62, :]) ----
  for (int w = 0; w < 9; ++w)
    wst_row_kernel<<<dim3(HH/256, BB), 256, 0, stream>>>(
        x + (size_t)(54 + w) * CC, XROW, encWT, encb, wst + (size_t)w * HH);

  // ---- decoder: 64 steps (wst row for the new frame fused into mlp) ----
  int hc = 2;
  for (int t = 0; t < 64; ++t) {
    if (t > 0) {
      int hn = (t - 1) & 1;
      gru_mfma<<<ggrid, 256, 0, stream>>>(
          hhi[hc], hlo[hc], hf[hc], lpH, lpL,
          WgH, WgL, gbi, gbh, hf[hn], hhi[hn], hlo[hn]);
      hc = hn;
    }
    mlp_kernel<<<dim3(BB), 256, 0, stream>>>(
        hf[2], hf[hc], wst, t % 10, encWT, encb,
        seqW, seqb, lnA, lnB, outW, outb, mrgW, mrgb,
        last, out + (size_t)t * CC, lpH, lpL);
  }
}

// Round 5
// 9577.439 us; speedup vs baseline: 1.5796x; 1.0955x over previous
//
#include <hip/hip_runtime.h>
#include <hip/hip_bf16.h>
#include <cstddef>
#include <cstdint>

#define BB 1024
#define TT 64
#define CC 66
#define HH 1024
#define SS 12
#define LL 12
#define XROW (TT*CC)   // 4224 floats per batch row of x
#define KSEG 8

typedef __attribute__((ext_vector_type(8))) __bf16 bfrag;
typedef __attribute__((ext_vector_type(4))) float f32x4;
typedef __attribute__((ext_vector_type(8))) short s8v;
typedef __attribute__((ext_vector_type(2))) float f2;

__device__ __forceinline__ unsigned short f2bf(float f) {
  unsigned int u = __builtin_bit_cast(unsigned int, f);
  unsigned int r = u + 0x7FFFu + ((u >> 16) & 1u);
  return (unsigned short)(r >> 16);
}
__device__ __forceinline__ float bf2f(unsigned short h) {
  unsigned int u = ((unsigned int)h) << 16;
  return __builtin_bit_cast(float, u);
}

__device__ __forceinline__ void gload16(const void* g, void* l) {
  __builtin_amdgcn_global_load_lds(
      (const __attribute__((address_space(1))) unsigned int*)g,
      (__attribute__((address_space(3))) unsigned int*)l, 16, 0, 0);
}

// DPP-based wave64 sum: result lands in lane 63. VALU-only (no LDS pipe).
template<int CTRL, int RM>
__device__ __forceinline__ float dppadd(float v) {
  int x = __builtin_amdgcn_update_dpp(0, __builtin_bit_cast(int, v),
                                      CTRL, RM, 0xF, true);
  return v + __builtin_bit_cast(float, x);
}
__device__ __forceinline__ float wave_sum63(float v) {
  v = dppadd<0x111, 0xF>(v);   // row_shr:1
  v = dppadd<0x112, 0xF>(v);   // row_shr:2
  v = dppadd<0x114, 0xF>(v);   // row_shr:4
  v = dppadd<0x118, 0xF>(v);   // row_shr:8
  v = dppadd<0x142, 0xa>(v);   // row_bcast:15
  v = dppadd<0x143, 0xc>(v);   // row_bcast:31 -> lane 63 = full sum
  return v;
}

// ---------------------------------------------------------------------------
// Split-bf16 MFMA GRU step (unchanged from round 3/4).
// ---------------------------------------------------------------------------
__global__ __launch_bounds__(256) void gru_mfma(
    const unsigned short* __restrict__ Ahi, const unsigned short* __restrict__ Alo,
    const float* __restrict__ hprev,
    const unsigned short* __restrict__ Xhi, const unsigned short* __restrict__ Xlo,
    const unsigned short* __restrict__ Whi, const unsigned short* __restrict__ Wlo,
    const float* __restrict__ bi, const float* __restrict__ bh,
    float* __restrict__ hout_f32,
    unsigned short* __restrict__ hout_hi, unsigned short* __restrict__ hout_lo)
{
  __shared__ __align__(16) unsigned short AsH[2][64*32];
  __shared__ __align__(16) unsigned short AsL[2][64*32];
  __shared__ __align__(16) unsigned short BsH[2][128*32];
  __shared__ __align__(16) unsigned short BsL[2][128*32];

  const int tid = threadIdx.x, lane = tid & 63, wid = tid >> 6;
  const int bid = blockIdx.x;
  const int idx = bid >> 3;
  const int jb = (bid & 7) * 4 + (idx & 3);
  const int b0 = (idx >> 2) * 64;
  const int wm = wid >> 1, wn = wid & 1;

  const int j = jb * 32 + wn * 16 + (lane & 15);
  const float b_r  = bi[j] + bh[j];
  const float b_z  = bi[HH + j] + bh[HH + j];
  const float b_nh = bh[2 * HH + j];
  const float b_nx = bi[2 * HH + j];
  float hp[2][4];
  #pragma unroll
  for (int mh = 0; mh < 2; ++mh)
    #pragma unroll
    for (int q = 0; q < 4; ++q) {
      int m = b0 + wm * 32 + mh * 16 + (lane >> 4) * 4 + q;
      hp[mh][q] = hprev[(size_t)m * HH + j];
    }

  const int aR = lane >> 2, aC = lane & 3;

  auto stage = [&](int bs, int kc) {
    const unsigned short *shi, *slo; size_t go;
    int row = wid * 16 + aR;
    if (kc < 32) {
      go = (size_t)(b0 + row) * 1024 + (size_t)kc * 32 + aC * 8;
      shi = Ahi; slo = Alo;
    } else {
      go = (size_t)(b0 + row) * 96 + (size_t)(kc - 32) * 32 + aC * 8;
      shi = Xhi; slo = Xlo;
    }
    gload16(shi + go, &AsH[bs][wid * 512]);
    gload16(slo + go, &AsL[bs][wid * 512]);
    size_t base = ((size_t)jb * 35 + kc) * 4096;
    size_t go0 = base + (size_t)(wid * 32 + aR) * 32 + aC * 8;
    gload16(Whi + go0,       &BsH[bs][wid * 1024]);
    gload16(Whi + go0 + 512, &BsH[bs][wid * 1024 + 512]);
    gload16(Wlo + go0,       &BsL[bs][wid * 1024]);
    gload16(Wlo + go0 + 512, &BsL[bs][wid * 1024 + 512]);
  };

  f32x4 acc[2][4] = {};

  stage(0, 0);
  __syncthreads();

  for (int kc = 0; kc < 35; ++kc) {
    const int cur = kc & 1;
    if (kc < 34) stage(cur ^ 1, kc + 1);

    bfrag ah[2], al[2], bhf[4], blf[4];
    #pragma unroll
    for (int mh = 0; mh < 2; ++mh) {
      int r = wm * 32 + mh * 16 + (lane & 15);
      int cb = (lane >> 4) ^ (r & 3);
      int off = r * 32 + cb * 8;
      ah[mh] = __builtin_bit_cast(bfrag, *(const s8v*)(&AsH[cur][off]));
      al[mh] = __builtin_bit_cast(bfrag, *(const s8v*)(&AsL[cur][off]));
    }
    #pragma unroll
    for (int g = 0; g < 4; ++g) {
      int r = wn * 64 + g * 16 + (lane & 15);
      int cb = (lane >> 4) ^ (r & 3);
      int off = r * 32 + cb * 8;
      bhf[g] = __builtin_bit_cast(bfrag, *(const s8v*)(&BsH[cur][off]));
      blf[g] = __builtin_bit_cast(bfrag, *(const s8v*)(&BsL[cur][off]));
    }
    #pragma unroll
    for (int mh = 0; mh < 2; ++mh)
      #pragma unroll
      for (int g = 0; g < 4; ++g) {
        acc[mh][g] = __builtin_amdgcn_mfma_f32_16x16x32_bf16(ah[mh], bhf[g], acc[mh][g], 0, 0, 0);
        acc[mh][g] = __builtin_amdgcn_mfma_f32_16x16x32_bf16(ah[mh], blf[g], acc[mh][g], 0, 0, 0);
        acc[mh][g] = __builtin_amdgcn_mfma_f32_16x16x32_bf16(al[mh], bhf[g], acc[mh][g], 0, 0, 0);
      }
    __syncthreads();
  }

  #pragma unroll
  for (int mh = 0; mh < 2; ++mh)
    #pragma unroll
    for (int q = 0; q < 4; ++q) {
      int m = b0 + wm * 32 + mh * 16 + (lane >> 4) * 4 + q;
      float rr = acc[mh][0][q] + b_r;
      float zz = acc[mh][1][q] + b_z;
      float nh = acc[mh][2][q] + b_nh;
      float nx = acc[mh][3][q] + b_nx;
      float r = 1.f / (1.f + __expf(-rr));
      float z = 1.f / (1.f + __expf(-zz));
      float n = tanhf(nx + r * nh);
      float hv = (1.f - z) * n + z * hp[mh][q];
      hout_f32[(size_t)m * HH + j] = hv;
      unsigned short hi = f2bf(hv);
      float lo = hv - bf2f(hi);
      int cb = ((j >> 3) & 3) ^ (m & 3);
      size_t dst = (size_t)m * 1024 + (size_t)(j & ~31) + cb * 8 + (j & 7);
      hout_hi[dst] = hi;
      hout_lo[dst] = f2bf(lo);
    }
}

// ---------------------------------------------------------------------------
// Prep kernels (unchanged).
// ---------------------------------------------------------------------------
__global__ __launch_bounds__(256) void prep_wgc(
    const float* __restrict__ Wh, const float* __restrict__ Wi,
    unsigned short* __restrict__ Whi, unsigned short* __restrict__ Wlo)
{
  size_t idx = (size_t)blockIdx.x * 256 + threadIdx.x;
  if (idx >= (size_t)4096 * 1120) return;
  int k = (int)(idx % 1120);
  int rg = (int)(idx / 1120);
  int jbv = rg >> 7, r = rg & 127;
  int jhi = r >> 6, rem = r & 63, g = rem >> 4, jlo = rem & 15;
  int j = jbv * 32 + jhi * 16 + jlo;
  float v = 0.f;
  if (g == 0)      v = (k < 1024) ? Wh[(size_t)j * HH + k]            : ((k < 1090) ? Wi[(size_t)j * CC + (k - 1024)] : 0.f);
  else if (g == 1) v = (k < 1024) ? Wh[(size_t)(HH + j) * HH + k]     : ((k < 1090) ? Wi[(size_t)(HH + j) * CC + (k - 1024)] : 0.f);
  else if (g == 2) v = (k < 1024) ? Wh[(size_t)(2 * HH + j) * HH + k] : 0.f;
  else             v = (k >= 1024 && k < 1090) ? Wi[(size_t)(2 * HH + j) * CC + (k - 1024)] : 0.f;
  unsigned short hi = f2bf(v);
  float lo = v - bf2f(hi);
  int kc = k >> 5, kk = k & 31;
  int cb = ((kk >> 3) ^ (r & 3)) & 3;
  size_t dst = (((size_t)jbv * 35 + kc) * 128 + r) * 32 + cb * 8 + (kk & 7);
  Whi[dst] = hi;
  Wlo[dst] = f2bf(lo);
}

__global__ __launch_bounds__(256) void prep_xall(
    const float* __restrict__ x,
    unsigned short* __restrict__ Xhi, unsigned short* __restrict__ Xlo)
{
  size_t idx = (size_t)blockIdx.x * 256 + threadIdx.x;
  if (idx >= (size_t)TT * BB * 96) return;
  int kx = (int)(idx % 96);
  size_t rem = idx / 96;
  int b = (int)(rem % BB);
  int t = (int)(rem / BB);
  float v = (kx < CC) ? x[(size_t)b * XROW + (size_t)t * CC + kx] : 0.f;
  unsigned short hi = f2bf(v);
  float lo = v - bf2f(hi);
  int cb = (((kx >> 3) & 3) ^ (b & 3)) & 3;
  size_t dst = ((size_t)t * BB + b) * 96 + (size_t)(kx & ~31) + cb * 8 + (kx & 7);
  Xhi[dst] = hi;
  Xlo[dst] = f2bf(lo);
}

__global__ __launch_bounds__(256) void wst_row_kernel(
    const float* __restrict__ src, int src_stride,
    const float* __restrict__ encWT, const float* __restrict__ encb,
    float* __restrict__ dst, const int* __restrict__ flagp)
{
  if (*flagp) return;   // fast path active: wst not used (region overlaid)
  __shared__ float s[CC];
  int b = blockIdx.y;
  int h = blockIdx.x * 256 + threadIdx.x;
  if (threadIdx.x < CC) s[threadIdx.x] = src[(size_t)b * src_stride + threadIdx.x];
  __syncthreads();
  float acc = encb[h];
  #pragma unroll
  for (int k = 0; k < CC; ++k) acc = fmaf(s[k], encWT[(size_t)k * HH + h], acc);
  dst[(size_t)b * (10 * HH) + h] = acc;
}

__global__ __launch_bounds__(256) void transpose_encW(
    const float* __restrict__ W, float* __restrict__ WT)
{
  int k = blockIdx.x;
  int h = blockIdx.y * 256 + threadIdx.x;
  WT[(size_t)k * HH + h] = W[(size_t)h * CC + k];
}

__global__ __launch_bounds__(256) void copy_last_kernel(
    const float* __restrict__ x, float* __restrict__ last)
{
  int idx = blockIdx.x * 256 + threadIdx.x;
  if (idx < BB * CC) {
    int b = idx / CC, c = idx - b * CC;
    last[idx] = x[(size_t)b * XROW + 63 * CC + c];
  }
}

// ---------------------------------------------------------------------------
// flag: 1 iff ln_alpha==1 and ln_beta==0 everywhere (enables fast path)
// ---------------------------------------------------------------------------
__global__ __launch_bounds__(256) void flag_kernel(
    const float* __restrict__ lnA, const float* __restrict__ lnB, int* flagp)
{
  int idx = blockIdx.x * 256 + threadIdx.x;   // 24576 total
  bool ok;
  if (idx < LL * HH) ok = (lnA[idx] == 1.0f);
  else ok = (lnB[idx - LL * HH] == 0.0f);
  if (!ok) atomicAnd(flagp, 0);
}

// ---------------------------------------------------------------------------
// Fast-path preps (overlay region; harmless if generic path later overwrites)
// tabs layout (floats): K3[4356] | K2T[4356] | e1[66] | csE[66] | g0[66] |
//                       R[66] | be | sum_encb   (8978 floats)
// ---------------------------------------------------------------------------
__global__ __launch_bounds__(256) void prep_tabs(
    const float* __restrict__ encW, const float* __restrict__ encb,
    const float* __restrict__ outW, float* __restrict__ tabs)
{
  int idx = blockIdx.x * 256 + threadIdx.x;
  if (idx >= 8978) return;
  float a = 0.f;
  if (idx < 4356) {
    int c1 = idx / 66, c2 = idx % 66;
    for (int h = 0; h < HH; ++h) a = fmaf(encW[h * CC + c1], encW[h * CC + c2], a);
  } else if (idx < 8712) {
    int p = idx - 4356; int c = p / 66, c1 = p % 66;
    for (int h = 0; h < HH; ++h) a = fmaf(encW[h * CC + c1], outW[(size_t)c * HH + h], a);
  } else if (idx < 8778) {
    int c1 = idx - 8712;
    for (int h = 0; h < HH; ++h) a = fmaf(encW[h * CC + c1], encb[h], a);
  } else if (idx < 8844) {
    int c1 = idx - 8778;
    for (int h = 0; h < HH; ++h) a += encW[h * CC + c1];
  } else if (idx < 8910) {
    int c = idx - 8844;
    for (int h = 0; h < HH; ++h) a = fmaf(encb[h], outW[(size_t)c * HH + h], a);
  } else if (idx < 8976) {
    int c = idx - 8910;
    for (int h = 0; h < HH; ++h) a += outW[(size_t)c * HH + h];
  } else if (idx == 8976) {
    for (int h = 0; h < HH; ++h) a = fmaf(encb[h], encb[h], a);
  } else {
    for (int h = 0; h < HH; ++h) a += encb[h];
  }
  tabs[idx] = a;
}

// B144[k][n]: n<66: encW[k][n]; n<132: outW[n-66][k]; 132: encb[k]; 133: 1; else 0
__global__ __launch_bounds__(256) void prep_b144(
    const float* __restrict__ encW, const float* __restrict__ outW,
    const float* __restrict__ encb, float* __restrict__ B144)
{
  int idx = blockIdx.x * 256 + threadIdx.x;
  if (idx >= 1024 * 144) return;
  int k = idx / 144, n = idx % 144;
  float v;
  if (n < 66) v = encW[k * CC + n];
  else if (n < 132) v = outW[(size_t)(n - 66) * HH + k];
  else if (n == 132) v = encb[k];
  else if (n == 133) v = 1.f;
  else v = 0.f;
  B144[idx] = v;
}

__global__ __launch_bounds__(256) void linit_kernel(
    const float* __restrict__ x, float* __restrict__ l_ring,
    const int* __restrict__ flagp)
{
  if (!*flagp) return;
  int idx = blockIdx.x * 256 + threadIdx.x;
  if (idx >= 1024 * 9 * 66) return;
  int c = idx % 66; int r = idx / 66; int w = r % 9; int b = r / 9;
  l_ring[((size_t)b * 10 + w) * 66 + c] = x[(size_t)b * XROW + (54 + w) * CC + c];
}

// q = K3 @ l (66x66 MV per b), into ring slot
__global__ __launch_bounds__(256) void qnew_kernel(
    const float* __restrict__ src, int sstride, const float* __restrict__ K3,
    float* __restrict__ q_ring, int slot, const int* __restrict__ flagp)
{
  if (!*flagp) return;
  __shared__ float Ks[4356];
  __shared__ float ls[8][66];
  int tid = threadIdx.x, b0 = blockIdx.x * 8;
  for (int i = tid; i < 4356; i += 256) Ks[i] = K3[i];
  for (int i = tid; i < 8 * 66; i += 256)
    ls[i / 66][i % 66] = src[(size_t)(b0 + i / 66) * sstride + (i % 66)];
  __syncthreads();
  for (int o = tid; o < 528; o += 256) {
    int bi = o / 66, c1 = o % 66;
    float a = 0.f;
    for (int c2 = 0; c2 < 66; ++c2) a = fmaf(Ks[c1 * 66 + c2], ls[bi][c2], a);
    q_ring[((size_t)(b0 + bi) * 10 + slot) * 66 + c1] = a;
  }
}

// dec_gemm: dp[kseg][b][144] partial of A[b][:] @ B144  (A = hdec or whp)
__global__ __launch_bounds__(256) void dec_gemm(
    const float* __restrict__ A, const float* __restrict__ B144,
    float* __restrict__ dp, const int* __restrict__ flagp)
{
  if (!*flagp) return;
  __shared__ float As[64][132];
  const int tid = threadIdx.x;
  const int b0 = blockIdx.x * 64;
  const int k0 = blockIdx.y * 128;
  #pragma unroll
  for (int p = 0; p < 8; ++p) {
    int f4 = tid + p * 256;
    int r = f4 >> 5, c4 = f4 & 31;
    *(f32x4*)&As[r][c4 * 4] = *(const f32x4*)&A[(size_t)(b0 + r) * 1024 + k0 + c4 * 4];
  }
  __syncthreads();
  const int b_sub = tid & 63, cg = tid >> 6;
  const int base_c = cg * 36;
  float acc[36];
  #pragma unroll
  for (int i = 0; i < 36; ++i) acc[i] = 0.f;
  for (int kk4 = 0; kk4 < 32; ++kk4) {
    f32x4 a4 = *(const f32x4*)&As[b_sub][kk4 * 4];
    #pragma unroll
    for (int r = 0; r < 4; ++r) {
      float av = a4[r];
      const float* brow = B144 + (size_t)(k0 + kk4 * 4 + r) * 144 + base_c;
      #pragma unroll
      for (int q = 0; q < 9; ++q) {
        f32x4 b4 = *(const f32x4*)(brow + q * 4);
        acc[q * 4 + 0] = fmaf(av, b4[0], acc[q * 4 + 0]);
        acc[q * 4 + 1] = fmaf(av, b4[1], acc[q * 4 + 1]);
        acc[q * 4 + 2] = fmaf(av, b4[2], acc[q * 4 + 2]);
        acc[q * 4 + 3] = fmaf(av, b4[3], acc[q * 4 + 3]);
      }
    }
  }
  float* drow = dp + ((size_t)blockIdx.y * 1024 + b0 + b_sub) * 144 + base_c;
  #pragma unroll
  for (int i = 0; i < 36; ++i) drow[i] = acc[i];
}

// sums dp into whp-persistent arrays (run once, for whp)
__global__ __launch_bounds__(256) void fast_combine(
    const float* __restrict__ dp, float* __restrict__ u, float* __restrict__ G,
    float* __restrict__ e, float* __restrict__ s, const int* __restrict__ flagp)
{
  if (!*flagp) return;
  int o = blockIdx.x * 256 + threadIdx.x;
  if (o >= 1024 * 144) return;
  int b = o / 144, c = o % 144;
  float a = 0.f;
  #pragma unroll
  for (int g = 0; g < KSEG; ++g) a += dp[((size_t)g * 1024 + b) * 144 + c];
  if (c < 66) u[b * 66 + c] = a;
  else if (c < 132) G[b * 66 + (c - 66)] = a;
  else if (c == 132) e[b] = a;
  else if (c == 133) s[b] = a;
}

// ---------------------------------------------------------------------------
// solve: per-b Gram assembly (66-dim frame space) + 12-layer affine-LN
// recursion on (T, d, M) + output combine. Valid only when alpha==1,beta==0.
// ---------------------------------------------------------------------------
__global__ __launch_bounds__(256) void solve_kernel(
    const float* __restrict__ hdec, const float* __restrict__ whp,
    float* __restrict__ last, float* __restrict__ l_ring,
    const float* __restrict__ q_ring, const float* __restrict__ dp,
    const float* __restrict__ u_whp, const float* __restrict__ G_whp,
    const float* __restrict__ e_whp, const float* __restrict__ s_whp,
    const float* __restrict__ tabs,
    const float* __restrict__ seqW, const float* __restrict__ seqb,
    const float* __restrict__ outb, const float* __restrict__ mrgW,
    const float* __restrict__ mrgb, int ring0,
    float* __restrict__ outp,
    unsigned short* __restrict__ lpH, unsigned short* __restrict__ lpL,
    const int* __restrict__ flagp)
{
  if (!*flagp) return;
  const int b = blockIdx.x, tid = threadIdx.x;
  const int lane = tid & 63, wid = tid >> 6;
  __shared__ float l_all[10][66], Qv[10][66];
  __shared__ float yd[66], gd[66], uw[66], se1[66], scs[66], lmix[66];
  __shared__ float sW[156], sMm[156], sTt[156], sPp[156], sNn[156], sQq[156];
  __shared__ float sb12[12], sistd[12], scc[12], sfb[12], sdd12[12], swd[12], sVv[12], smrg[12];
  __shared__ float sred[12], misc[8];

  const float* K2T   = tabs + 4356;
  const float* tb_e1 = tabs + 8712;
  const float* tb_cs = tabs + 8778;
  const float* tb_g0 = tabs + 8844;
  const float* tb_R  = tabs + 8910;

  // ---- phase 0: staging + reductions ----
  for (int i = tid; i < 660; i += 256) {
    int w = i / 66, c = i % 66;
    int slot = ring0 + w; if (slot >= 10) slot -= 10;
    Qv[w][c] = q_ring[((size_t)b * 10 + slot) * 66 + c];
    if (w < 9) l_all[w][c] = l_ring[((size_t)b * 10 + slot) * 66 + c];
    else       l_all[9][c] = last[(size_t)b * 66 + c];
  }
  for (int i = tid; i < 66; i += 256) {
    uw[i]  = u_whp[(size_t)b * 66 + i];
    se1[i] = tb_e1[i];
    scs[i] = tb_cs[i];
  }
  if (tid < 134) {
    float a = 0.f;
    #pragma unroll
    for (int g = 0; g < KSEG; ++g) a += dp[((size_t)g * 1024 + b) * 144 + tid];
    if (tid < 66) yd[tid] = a;
    else if (tid < 132) gd[tid - 66] = a;
    else if (tid == 132) misc[1] = a;   // <hdec, encb>
    else misc[2] = a;                   // sum_h hdec
  }
  if (tid >= 160 && tid < 172) smrg[tid - 160] = mrgW[tid - 160];
  {
    f32x4 hv = *(const f32x4*)&hdec[(size_t)b * 1024 + tid * 4];
    f32x4 wv = *(const f32x4*)&whp[(size_t)b * 1024 + tid * 4];
    float d2 = hv[0]*hv[0] + hv[1]*hv[1] + hv[2]*hv[2] + hv[3]*hv[3];
    float dw = hv[0]*wv[0] + hv[1]*wv[1] + hv[2]*wv[2] + hv[3]*wv[3];
    float w2 = wv[0]*wv[0] + wv[1]*wv[1] + wv[2]*wv[2] + wv[3]*wv[3];
    d2 = wave_sum63(d2); dw = wave_sum63(dw); w2 = wave_sum63(w2);
    if (lane == 63) { sred[wid*3] = d2; sred[wid*3+1] = dw; sred[wid*3+2] = w2; }
  }
  __syncthreads();
  if (tid < 3) misc[3 + tid] = sred[tid] + sred[3 + tid] + sred[6 + tid] + sred[9 + tid];
  if (tid == 4) misc[6] = tabs[8976];   // be
  if (tid == 5) misc[7] = tabs[8977];   // sum_encb
  __syncthreads();

  // ---- phase 1: Gram + fbar0 + init (T=I, d=0, M=Gram/H) ----
  if (tid < 144) {
    int i = tid / 12, j = tid % 12;
    float gv;
    if (i == 0 && j == 0) gv = misc[5];                         // <whp,whp>
    else if (i == 11 && j == 11) gv = misc[3];                  // <dec,dec>
    else if ((i == 0 && j == 11) || (i == 11 && j == 0)) gv = misc[4];
    else if (i == 0 || j == 0) {                                // whp x ring
      int w = (i == 0 ? j : i) - 1;
      float a = e_whp[b];
      for (int c = 0; c < 66; ++c) a = fmaf(uw[c], l_all[w][c], a);
      gv = a;
    } else if (i == 11 || j == 11) {                            // dec x ring
      int w = (i == 11 ? j : i) - 1;
      float a = misc[1];
      for (int c = 0; c < 66; ++c) a = fmaf(yd[c], l_all[w][c], a);
      gv = a;
    } else {                                                    // ring x ring
      int wi = i - 1, wj = j - 1;
      float a = misc[6];
      for (int c = 0; c < 66; ++c) a = fmaf(se1[c], l_all[wi][c] + l_all[wj][c], a);
      for (int c = 0; c < 66; ++c) a = fmaf(l_all[wi][c], Qv[wj][c], a);
      gv = a;
    }
    sMm[i * 13 + j] = gv * (1.f / 1024.f);
    sTt[i * 13 + j] = (i == j) ? 1.f : 0.f;
  }
  if (tid >= 144 && tid < 156) {
    int k = tid - 144;
    float fb;
    if (k == 0) fb = s_whp[b] * (1.f / 1024.f);
    else if (k == 11) fb = misc[2] * (1.f / 1024.f);
    else {
      float a = misc[7];
      for (int c = 0; c < 66; ++c) a = fmaf(scs[c], l_all[k - 1][c], a);
      fb = a * (1.f / 1024.f);
    }
    sfb[k] = fb;
    sdd12[k] = 0.f;
  }
  __syncthreads();

  // ---- phase 2: 12-layer recursion ----
  for (int l = 0; l < LL; ++l) {
    if (tid < 144) sW[(tid / 12) * 13 + (tid % 12)] = seqW[l * 144 + tid];
    if (tid >= 160 && tid < 172) sb12[tid - 160] = seqb[l * 12 + (tid - 160)];
    __syncthreads();
    if (tid < 144) {                          // P = W * M
      int s = tid / 12, k = tid % 12;
      float a = 0.f;
      #pragma unroll
      for (int k2 = 0; k2 < 12; ++k2) a = fmaf(sW[s * 13 + k2], sMm[k2 * 13 + k], a);
      sPp[s * 13 + k] = a;
    }
    __syncthreads();
    if (tid < 12) {                           // stats
      int s = tid;
      float mu = sb12[s];
      #pragma unroll
      for (int k = 0; k < 12; ++k) mu = fmaf(sW[s * 13 + k], sfb[k], mu);
      float e2 = 0.f;
      #pragma unroll
      for (int k = 0; k < 12; ++k) e2 = fmaf(sPp[s * 13 + k], sW[s * 13 + k], e2);
      float wf = mu - sb12[s];
      float var = fmaxf(e2 - wf * wf, 0.f);
      float is = 1.f / sqrtf(var + 1e-5f);
      sistd[s] = is;
      scc[s] = is * (sb12[s] - mu);
    }
    __syncthreads();
    if (tid < 144) {                          // Q = W*T ; N1 = M + D*P
      int i = tid / 12, j = tid % 12;
      float a = 0.f;
      #pragma unroll
      for (int k = 0; k < 12; ++k) a = fmaf(sW[i * 13 + k], sTt[k * 13 + j], a);
      sQq[i * 13 + j] = a;
      sNn[i * 13 + j] = sMm[i * 13 + j] + sistd[i] * sPp[i * 13 + j];
    }
    if (tid >= 144 && tid < 156) {            // Wd
      int i = tid - 144;
      float a = 0.f;
      #pragma unroll
      for (int k = 0; k < 12; ++k) a = fmaf(sW[i * 13 + k], sdd12[k], a);
      swd[i] = a;
    }
    __syncthreads();
    if (tid < 144) {                          // T += D*Q ; P2 = N1*W^T
      int i = tid / 12, j = tid % 12;
      sTt[i * 13 + j] += sistd[i] * sQq[i * 13 + j];
      float a = 0.f;
      #pragma unroll
      for (int k = 0; k < 12; ++k) a = fmaf(sNn[i * 13 + k], sW[j * 13 + k], a);
      sPp[i * 13 + j] = a;
    }
    if (tid >= 144 && tid < 156) {
      int i = tid - 144;
      sdd12[i] = sdd12[i] + sistd[i] * swd[i] + scc[i];
    }
    __syncthreads();
    if (tid < 144) {                          // M' = N1 + P2*D + rank-1
      int i = tid / 12, j = tid % 12;
      sMm[i * 13 + j] = sNn[i * 13 + j] + sPp[i * 13 + j] * sistd[j]
                      + sfb[i] * scc[j] + scc[i] * sfb[j] - scc[i] * scc[j];
    }
    __syncthreads();
  }

  // ---- phase 3: v, cv, lmix, output ----
  if (tid < 12) {
    float a = 0.f;
    #pragma unroll
    for (int s = 0; s < 12; ++s) a = fmaf(smrg[s], sTt[s * 13 + tid], a);
    sVv[tid] = a;
  }
  if (tid == 200) {
    float a = 0.f;
    for (int s = 0; s < 12; ++s) a = fmaf(smrg[s], sdd12[s], a);
    misc[0] = a;  // cv
  }
  __syncthreads();
  if (tid < 66) {
    float a = 0.f;
    #pragma unroll
    for (int w = 0; w < 9; ++w) a = fmaf(sVv[1 + w], l_all[w][tid], a);
    a = fmaf(sVv[10], l_all[9][tid], a);
    lmix[tid] = a;
  }
  __syncthreads();
  if (tid < 66) {
    int c = tid;
    float vsr = 0.f, smw = 0.f;
    #pragma unroll
    for (int k = 1; k <= 10; ++k) vsr += sVv[k];
    #pragma unroll
    for (int s = 0; s < 12; ++s) smw += smrg[s];
    float lastv = l_all[9][c];
    float acc = sVv[0] * G_whp[(size_t)b * 66 + c]
              + vsr * tb_g0[c]
              + sVv[11] * gd[c]
              + misc[0] * tb_R[c]
              + smw * outb[c] + mrgb[0] + lastv;
    const float* krow = K2T + c * 66;
    for (int c2 = 0; c2 < 66; ++c2) acc = fmaf(lmix[c2], krow[c2], acc);
    outp[(size_t)b * XROW + c] = acc;
    last[(size_t)b * 66 + c] = acc;
    int slot9 = (ring0 == 0) ? 9 : ring0 - 1;
    l_ring[((size_t)b * 10 + slot9) * 66 + c] = lastv;
    unsigned short hi = f2bf(acc);
    float lo = acc - bf2f(hi);
    int cb = (((c >> 3) & 3) ^ (b & 3)) & 3;
    size_t dst = (size_t)b * 96 + (size_t)(c & ~31) + cb * 8 + (c & 7);
    lpH[dst] = hi;
    lpL[dst] = f2bf(lo);
  }
}

// ---------------------------------------------------------------------------
// MLP-mini v2 (generic fallback; unchanged math from round 4) + flag guard.
// ---------------------------------------------------------------------------
__global__ __launch_bounds__(256) void mlp_kernel(
    const float* __restrict__ whp, const float* __restrict__ hdec,
    float* __restrict__ wst, int ring0,
    const float* __restrict__ encWT, const float* __restrict__ encb,
    const float* __restrict__ seqW, const float* __restrict__ seqb,
    const float* __restrict__ lnA, const float* __restrict__ lnB,
    const float* __restrict__ outW, const float* __restrict__ outb,
    const float* __restrict__ mrgW, const float* __restrict__ mrgb,
    float* __restrict__ last, float* __restrict__ outp,
    unsigned short* __restrict__ lpH, unsigned short* __restrict__ lpL,
    const int* __restrict__ flagp)
{
  if (*flagp) return;   // fast path handled this step
  const int b = blockIdx.x, tid = threadIdx.x;
  const int lane = tid & 63, wid = tid >> 6;
  __shared__ float red[4][24];
  __shared__ f2 mustd2[SS];
  __shared__ float g_lds[HH];
  __shared__ float nc[CC];

  const int h0 = tid;
  const int h1 = tid + 512;

  const int slot9 = (ring0 == 0) ? 9 : ring0 - 1;
  const float* lrow = last + (size_t)b * CC;
  f2 wnew[2];
  {
    f2 a0 = { encb[h0], encb[h0 + 256] };
    f2 a1 = { encb[h1], encb[h1 + 256] };
    #pragma unroll 11
    for (int k = 0; k < CC; ++k) {
      float lv = lrow[k];
      f2 lv2 = { lv, lv };
      f2 w0 = { encWT[(size_t)k * HH + h0], encWT[(size_t)k * HH + h0 + 256] };
      f2 w1 = { encWT[(size_t)k * HH + h1], encWT[(size_t)k * HH + h1 + 256] };
      a0 = __builtin_elementwise_fma(lv2, w0, a0);
      a1 = __builtin_elementwise_fma(lv2, w1, a1);
    }
    wnew[0] = a0; wnew[1] = a1;
    float* wd = wst + ((size_t)b * 10 + slot9) * HH;
    wd[h0] = a0.x; wd[h0 + 256] = a0.y;
    wd[h1] = a1.x; wd[h1 + 256] = a1.y;
  }

  f2 fr[2][SS];
  {
    const float* whb = whp + (size_t)b * HH;
    const float* hb  = hdec + (size_t)b * HH;
    fr[0][0]  = { whb[h0], whb[h0 + 256] };
    fr[1][0]  = { whb[h1], whb[h1 + 256] };
    fr[0][11] = { hb[h0], hb[h0 + 256] };
    fr[1][11] = { hb[h1], hb[h1 + 256] };
    #pragma unroll
    for (int w = 0; w < 9; ++w) {
      int slot = ring0 + w; if (slot >= 10) slot -= 10;
      const float* ws_ = wst + ((size_t)b * 10 + slot) * HH;
      fr[0][1 + w] = { ws_[h0], ws_[h0 + 256] };
      fr[1][1 + w] = { ws_[h1], ws_[h1 + 256] };
    }
    fr[0][10] = wnew[0];
    fr[1][10] = wnew[1];
  }

  #pragma unroll 1
  for (int l = 0; l < LL; ++l) {
    const float* W  = seqW + (size_t)l * SS * SS;
    const float* Bv = seqb + (size_t)l * SS;
    const float* lA = lnA + (size_t)l * HH;
    const float* lB = lnB + (size_t)l * HH;
    f2 al[2], be[2];
    al[0] = { lA[h0], lA[h0 + 256] };  al[1] = { lA[h1], lA[h1 + 256] };
    be[0] = { lB[h0], lB[h0 + 256] };  be[1] = { lB[h1], lB[h1 + 256] };

    f2 y[2][SS];
    #pragma unroll
    for (int s = 0; s < SS; ++s) {
      float bv = Bv[s];
      f2 a0 = { bv, bv }, a1 = { bv, bv };
      #pragma unroll
      for (int k = 0; k < SS; ++k) {
        float wv = W[s * SS + k];
        f2 wv2 = { wv, wv };
        a0 = __builtin_elementwise_fma(fr[0][k], wv2, a0);
        a1 = __builtin_elementwise_fma(fr[1][k], wv2, a1);
      }
      y[0][s] = a0; y[1][s] = a1;
      f2 pp = a0 + a1;
      float ps = wave_sum63(pp.x + pp.y);
      f2 qq = __builtin_elementwise_fma(a0, a0, a1 * a1);
      float pq = wave_sum63(qq.x + qq.y);
      if (lane == 63) { red[wid][s] = ps; red[wid][12 + s] = pq; }
    }
    __syncthreads();
    if (tid < SS) {
      float S = red[0][tid] + red[1][tid] + red[2][tid] + red[3][tid];
      float Q = red[0][12 + tid] + red[1][12 + tid] + red[2][12 + tid] + red[3][12 + tid];
      float mu = S * (1.f / HH);
      float var = Q * (1.f / HH) - mu * mu;
      mustd2[tid] = { mu, 1.f / sqrtf(var + 1e-5f) };
    }
    __syncthreads();
    #pragma unroll
    for (int s = 0; s < SS; ++s) {
      f2 mi = mustd2[s];
      f2 mus = { mi.x, mi.x };
      f2 isd = { mi.y, mi.y };
      #pragma unroll
      for (int p = 0; p < 2; ++p) {
        f2 t = (y[p][s] - mus) * isd;
        fr[p][s] = __builtin_elementwise_fma(t, al[p], fr[p][s]) + be[p];
      }
    }
    __syncthreads();
  }

  float smw = 0.f;
  f2 g[2] = { {0.f, 0.f}, {0.f, 0.f} };
  #pragma unroll
  for (int s = 0; s < SS; ++s) {
    float mv = mrgW[s];
    smw += mv;
    f2 mv2 = { mv, mv };
    g[0] = __builtin_elementwise_fma(mv2, fr[0][s], g[0]);
    g[1] = __builtin_elementwise_fma(mv2, fr[1][s], g[1]);
  }
  g_lds[h0] = g[0].x; g_lds[h0 + 256] = g[0].y;
  g_lds[h1] = g[1].x; g_lds[h1 + 256] = g[1].y;
  const float mbv = mrgb[0];
  __syncthreads();
  #pragma unroll 1
  for (int i = 0; i < 17; ++i) {
    int c = wid + 4 * i;
    if (c < CC) {
      const float* ow = outW + (size_t)c * HH;
      float acc = 0.f;
      #pragma unroll
      for (int q = 0; q < 16; ++q) acc = fmaf(g_lds[lane + q * 64], ow[lane + q * 64], acc);
      acc = wave_sum63(acc);
      if (lane == 63) nc[c] = acc + outb[c] * smw + mbv + lrow[c];
    }
  }
  __syncthreads();
  if (tid < CC) {
    float nv = nc[tid];
    outp[(size_t)b * XROW + tid] = nv;
    last[(size_t)b * CC + tid] = nv;
    unsigned short hi = f2bf(nv);
    float lo = nv - bf2f(hi);
    int cb = (((tid >> 3) & 3) ^ (b & 3)) & 3;
    size_t dst = (size_t)b * 96 + (size_t)(tid & ~31) + cb * 8 + (tid & 7);
    lpH[dst] = hi;
    lpL[dst] = f2bf(lo);
  }
}

// ---------------------------------------------------------------------------
extern "C" void kernel_launch(void* const* d_in, const int* in_sizes, int n_in,
                              void* d_out, int out_size, void* d_ws, size_t ws_size,
                              hipStream_t stream) {
  const float* x    = (const float*)d_in[0];
  const float* gWi  = (const float*)d_in[1];
  const float* gWh  = (const float*)d_in[2];
  const float* gbi  = (const float*)d_in[3];
  const float* gbh  = (const float*)d_in[4];
  const float* encW = (const float*)d_in[5];
  const float* encb = (const float*)d_in[6];
  const float* seqW = (const float*)d_in[7];
  const float* seqb = (const float*)d_in[8];
  const float* lnA  = (const float*)d_in[9];
  const float* lnB  = (const float*)d_in[10];
  const float* outW = (const float*)d_in[11];
  const float* outb = (const float*)d_in[12];
  const float* mrgW = (const float*)d_in[13];
  const float* mrgb = (const float*)d_in[14];
  float* out = (float*)d_out;

  char* p = (char*)d_ws;
  auto alloc = [&](size_t bytes) { char* r = p; p += (bytes + 255) & ~(size_t)255; return r; };
  float* encWT = (float*)alloc((size_t)CC * HH * 4);
  float* last  = (float*)alloc((size_t)BB * CC * 4);
  float* wst   = (float*)alloc((size_t)BB * 10 * HH * 4);   // generic ring / fast overlay
  float* hf[3];
  for (int i = 0; i < 3; ++i) hf[i] = (float*)alloc((size_t)BB * HH * 4);
  unsigned short* WgH = (unsigned short*)alloc((size_t)4096 * 1120 * 2);
  unsigned short* WgL = (unsigned short*)alloc((size_t)4096 * 1120 * 2);
  unsigned short* XaH = (unsigned short*)alloc((size_t)TT * BB * 96 * 2);
  unsigned short* XaL = (unsigned short*)alloc((size_t)TT * BB * 96 * 2);
  unsigned short* hhi[3]; unsigned short* hlo[3];
  for (int i = 0; i < 3; ++i) {
    hhi[i] = (unsigned short*)alloc((size_t)BB * HH * 2);
    hlo[i] = (unsigned short*)alloc((size_t)BB * HH * 2);
  }
  unsigned short* lpH = (unsigned short*)alloc((size_t)BB * 96 * 2);
  unsigned short* lpL = (unsigned short*)alloc((size_t)BB * 96 * 2);
  int* flag = (int*)alloc(256);
  if ((size_t)(p - (char*)d_ws) > ws_size) return;  // insufficient workspace

  // fast-path overlay inside the wst region (mutually exclusive by flag)
  char* ov = (char*)wst;
  float* B144  = (float*)ov;                 ov += (size_t)1024 * 144 * 4;       // 589,824
  float* dp    = (float*)ov;                 ov += (size_t)KSEG * 1024 * 144 * 4;// 4,718,592
  float* l_ring= (float*)ov;                 ov += (size_t)1024 * 10 * 66 * 4;
  float* q_ring= (float*)ov;                 ov += (size_t)1024 * 10 * 66 * 4;
  float* u_whp = (float*)ov;                 ov += (size_t)1024 * 66 * 4;
  float* G_whp = (float*)ov;                 ov += (size_t)1024 * 66 * 4;
  float* e_whp = (float*)ov;                 ov += 4096;
  float* s_whp = (float*)ov;                 ov += 4096;
  float* tabs  = (float*)ov;                 ov += 9216 * 4;

  // ---- one-time prep ----
  hipMemsetAsync(flag, 0xFF, 4, stream);
  flag_kernel<<<dim3(96), 256, 0, stream>>>(lnA, lnB, flag);
  prep_wgc<<<dim3((4096u * 1120u) / 256u), 256, 0, stream>>>(gWh, gWi, WgH, WgL);
  prep_xall<<<dim3(((unsigned)TT * BB * 96) / 256u), 256, 0, stream>>>(x, XaH, XaL);
  transpose_encW<<<dim3(CC, HH/256), 256, 0, stream>>>(encW, encWT);
  copy_last_kernel<<<dim3((BB*CC + 255)/256), 256, 0, stream>>>(x, last);
  prep_b144<<<dim3(576), 256, 0, stream>>>(encW, outW, encb, B144);
  prep_tabs<<<dim3(36), 256, 0, stream>>>(encW, encb, outW, tabs);
  linit_kernel<<<dim3((1024*9*66)/256), 256, 0, stream>>>(x, l_ring, flag);
  for (int w = 0; w < 9; ++w)
    qnew_kernel<<<dim3(128), 256, 0, stream>>>(x + (size_t)(54 + w) * CC, XROW,
                                               tabs, q_ring, w, flag);
  hipMemsetAsync(hf[0], 0, (size_t)BB * HH * 4, stream);
  hipMemsetAsync(hhi[0], 0, (size_t)BB * HH * 2, stream);
  hipMemsetAsync(hlo[0], 0, (size_t)BB * HH * 2, stream);

  const dim3 ggrid(512);

  // ---- encoder: 63 GRU steps ----
  int cur = 0;
  for (int t = 0; t < 63; ++t) {
    int nxt = 1 - cur;
    gru_mfma<<<ggrid, 256, 0, stream>>>(
        hhi[cur], hlo[cur], hf[cur],
        XaH + (size_t)t * BB * 96, XaL + (size_t)t * BB * 96,
        WgH, WgL, gbi, gbh, hf[nxt], hhi[nxt], hlo[nxt]);
    cur = nxt;
  }
  gru_mfma<<<ggrid, 256, 0, stream>>>(
      hhi[cur], hlo[cur], hf[cur],
      XaH + (size_t)63 * BB * 96, XaL + (size_t)63 * BB * 96,
      WgH, WgL, gbi, gbh, hf[2], hhi[2], hlo[2]);

  // whp-derived persistent fast-path arrays
  dec_gemm<<<dim3(16, KSEG), 256, 0, stream>>>(hf[2], B144, dp, flag);
  fast_combine<<<dim3(576), 256, 0, stream>>>(dp, u_whp, G_whp, e_whp, s_whp, flag);

  // generic-path wst init (skipped when fast)
  for (int w = 0; w < 9; ++w)
    wst_row_kernel<<<dim3(HH/256, BB), 256, 0, stream>>>(
        x + (size_t)(54 + w) * CC, XROW, encWT, encb, wst + (size_t)w * HH, flag);

  // ---- decoder: 64 steps ----
  int hc = 2;
  for (int t = 0; t < 64; ++t) {
    if (t > 0) {
      int hn = (t - 1) & 1;
      gru_mfma<<<ggrid, 256, 0, stream>>>(
          hhi[hc], hlo[hc], hf[hc], lpH, lpL,
          WgH, WgL, gbi, gbh, hf[hn], hhi[hn], hlo[hn]);
      hc = hn;
    }
    // fast path
    dec_gemm<<<dim3(16, KSEG), 256, 0, stream>>>(hf[hc], B144, dp, flag);
    qnew_kernel<<<dim3(128), 256, 0, stream>>>(last, CC, tabs, q_ring, (t + 9) % 10, flag);
    solve_kernel<<<dim3(BB), 256, 0, stream>>>(
        hf[hc], hf[2], last, l_ring, q_ring, dp,
        u_whp, G_whp, e_whp, s_whp, tabs,
        seqW, seqb, outb, mrgW, mrgb, t % 10,
        out + (size_t)t * CC, lpH, lpL, flag);
    // generic fallback (skips when fast)
    mlp_kernel<<<dim3(BB), 256, 0, stream>>>(
        hf[2], hf[hc], wst, t % 10, encWT, encb,
        seqW, seqb, lnA, lnB, outW, outb, mrgW, mrgb,
        last, out + (size_t)t * CC, lpH, lpL, flag);
  }
}

// Round 6
// 8802.403 us; speedup vs baseline: 1.7187x; 1.0880x over previous
//
#include <hip/hip_runtime.h>
#include <hip/hip_bf16.h>
#include <cstddef>
#include <cstdint>

#define BB 1024
#define TT 64
#define CC 66
#define HH 1024
#define SS 12
#define LL 12
#define XROW (TT*CC)   // 4224 floats per batch row of x
#define KSEG 16

typedef __attribute__((ext_vector_type(8))) __bf16 bfrag;
typedef __attribute__((ext_vector_type(4))) float f32x4;
typedef __attribute__((ext_vector_type(8))) short s8v;
typedef __attribute__((ext_vector_type(2))) float f2;

__device__ __forceinline__ unsigned short f2bf(float f) {
  unsigned int u = __builtin_bit_cast(unsigned int, f);
  unsigned int r = u + 0x7FFFu + ((u >> 16) & 1u);
  return (unsigned short)(r >> 16);
}
__device__ __forceinline__ float bf2f(unsigned short h) {
  unsigned int u = ((unsigned int)h) << 16;
  return __builtin_bit_cast(float, u);
}

__device__ __forceinline__ void gload16(const void* g, void* l) {
  __builtin_amdgcn_global_load_lds(
      (const __attribute__((address_space(1))) unsigned int*)g,
      (__attribute__((address_space(3))) unsigned int*)l, 16, 0, 0);
}

// DPP-based wave64 sum: result lands in lane 63. VALU-only (no LDS pipe).
template<int CTRL, int RM>
__device__ __forceinline__ float dppadd(float v) {
  int x = __builtin_amdgcn_update_dpp(0, __builtin_bit_cast(int, v),
                                      CTRL, RM, 0xF, true);
  return v + __builtin_bit_cast(float, x);
}
__device__ __forceinline__ float wave_sum63(float v) {
  v = dppadd<0x111, 0xF>(v);   // row_shr:1
  v = dppadd<0x112, 0xF>(v);   // row_shr:2
  v = dppadd<0x114, 0xF>(v);   // row_shr:4
  v = dppadd<0x118, 0xF>(v);   // row_shr:8
  v = dppadd<0x142, 0xa>(v);   // row_bcast:15
  v = dppadd<0x143, 0xc>(v);   // row_bcast:31 -> lane 63 = full sum
  return v;
}

// ---------------------------------------------------------------------------
// Split-bf16 MFMA GRU step, v3: 3-buffer LDS pipeline with counted
// s_waitcnt vmcnt(6) + raw s_barrier (1 barrier/iter; loads stay 2 stages
// deep in flight across barriers). Frag/gate layouts unchanged from v2.
// ---------------------------------------------------------------------------
__global__ __launch_bounds__(256) void gru_mfma(
    const unsigned short* __restrict__ Ahi, const unsigned short* __restrict__ Alo,
    const float* __restrict__ hprev,
    const unsigned short* __restrict__ Xhi, const unsigned short* __restrict__ Xlo,
    const unsigned short* __restrict__ Whi, const unsigned short* __restrict__ Wlo,
    const float* __restrict__ bi, const float* __restrict__ bh,
    float* __restrict__ hout_f32,
    unsigned short* __restrict__ hout_hi, unsigned short* __restrict__ hout_lo)
{
  __shared__ __align__(16) unsigned short AsH[3][64*32];
  __shared__ __align__(16) unsigned short AsL[3][64*32];
  __shared__ __align__(16) unsigned short BsH[3][128*32];
  __shared__ __align__(16) unsigned short BsL[3][128*32];

  const int tid = threadIdx.x, lane = tid & 63, wid = tid >> 6;
  const int bid = blockIdx.x;
  const int idx = bid >> 3;
  const int jb = (bid & 7) * 4 + (idx & 3);
  const int b0 = (idx >> 2) * 64;
  const int wm = wid >> 1, wn = wid & 1;
  const int aR = lane >> 2, aC = lane & 3;

  auto stage = [&](int bs, int kc) {
    const unsigned short *shi, *slo; size_t go;
    int row = wid * 16 + aR;
    if (kc < 32) {
      go = (size_t)(b0 + row) * 1024 + (size_t)kc * 32 + aC * 8;
      shi = Ahi; slo = Alo;
    } else {
      go = (size_t)(b0 + row) * 96 + (size_t)(kc - 32) * 32 + aC * 8;
      shi = Xhi; slo = Xlo;
    }
    gload16(shi + go, &AsH[bs][wid * 512]);
    gload16(slo + go, &AsL[bs][wid * 512]);
    size_t base = ((size_t)jb * 35 + kc) * 4096;
    size_t go0 = base + (size_t)(wid * 32 + aR) * 32 + aC * 8;
    gload16(Whi + go0,       &BsH[bs][wid * 1024]);
    gload16(Whi + go0 + 512, &BsH[bs][wid * 1024 + 512]);
    gload16(Wlo + go0,       &BsL[bs][wid * 1024]);
    gload16(Wlo + go0 + 512, &BsL[bs][wid * 1024 + 512]);
  };

  // fragment offsets (compile-time per-lane)
  int offA[2], offB[4];
  #pragma unroll
  for (int mh = 0; mh < 2; ++mh) {
    int r = wm * 32 + mh * 16 + (lane & 15);
    int cb = (lane >> 4) ^ (r & 3);
    offA[mh] = r * 32 + cb * 8;
  }
  #pragma unroll
  for (int g = 0; g < 4; ++g) {
    int r = wn * 64 + g * 16 + (lane & 15);
    int cb = (lane >> 4) ^ (r & 3);
    offB[g] = r * 32 + cb * 8;
  }

  f32x4 acc[2][4] = {};

  stage(0, 0);
  stage(1, 1);

  int cur = 0;
  for (int kc = 0; kc < 34; ++kc) {
    asm volatile("s_waitcnt vmcnt(6)" ::: "memory");
    __builtin_amdgcn_s_barrier();
    asm volatile("" ::: "memory");

    bfrag ah[2], al[2], bhf[4], blf[4];
    #pragma unroll
    for (int mh = 0; mh < 2; ++mh) {
      ah[mh] = __builtin_bit_cast(bfrag, *(const s8v*)(&AsH[cur][offA[mh]]));
      al[mh] = __builtin_bit_cast(bfrag, *(const s8v*)(&AsL[cur][offA[mh]]));
    }
    #pragma unroll
    for (int g = 0; g < 4; ++g) {
      bhf[g] = __builtin_bit_cast(bfrag, *(const s8v*)(&BsH[cur][offB[g]]));
      blf[g] = __builtin_bit_cast(bfrag, *(const s8v*)(&BsL[cur][offB[g]]));
    }
    if (kc < 33) {
      int st = (cur >= 1) ? cur - 1 : 2;   // (cur+2)%3
      stage(st, kc + 2);
    }
    #pragma unroll
    for (int mh = 0; mh < 2; ++mh)
      #pragma unroll
      for (int g = 0; g < 4; ++g) {
        acc[mh][g] = __builtin_amdgcn_mfma_f32_16x16x32_bf16(ah[mh], bhf[g], acc[mh][g], 0, 0, 0);
        acc[mh][g] = __builtin_amdgcn_mfma_f32_16x16x32_bf16(ah[mh], blf[g], acc[mh][g], 0, 0, 0);
        acc[mh][g] = __builtin_amdgcn_mfma_f32_16x16x32_bf16(al[mh], bhf[g], acc[mh][g], 0, 0, 0);
      }
    cur = (cur < 2) ? cur + 1 : 0;
  }
  // peeled kc = 34 (cur == 34%3 == 1)
  {
    asm volatile("s_waitcnt vmcnt(0)" ::: "memory");
    __builtin_amdgcn_s_barrier();
    asm volatile("" ::: "memory");
    bfrag ah[2], al[2], bhf[4], blf[4];
    #pragma unroll
    for (int mh = 0; mh < 2; ++mh) {
      ah[mh] = __builtin_bit_cast(bfrag, *(const s8v*)(&AsH[1][offA[mh]]));
      al[mh] = __builtin_bit_cast(bfrag, *(const s8v*)(&AsL[1][offA[mh]]));
    }
    #pragma unroll
    for (int g = 0; g < 4; ++g) {
      bhf[g] = __builtin_bit_cast(bfrag, *(const s8v*)(&BsH[1][offB[g]]));
      blf[g] = __builtin_bit_cast(bfrag, *(const s8v*)(&BsL[1][offB[g]]));
    }
    #pragma unroll
    for (int mh = 0; mh < 2; ++mh)
      #pragma unroll
      for (int g = 0; g < 4; ++g) {
        acc[mh][g] = __builtin_amdgcn_mfma_f32_16x16x32_bf16(ah[mh], bhf[g], acc[mh][g], 0, 0, 0);
        acc[mh][g] = __builtin_amdgcn_mfma_f32_16x16x32_bf16(ah[mh], blf[g], acc[mh][g], 0, 0, 0);
        acc[mh][g] = __builtin_amdgcn_mfma_f32_16x16x32_bf16(al[mh], bhf[g], acc[mh][g], 0, 0, 0);
      }
  }

  // epilogue (biases + hprev loaded here, after all counted waits)
  const int j = jb * 32 + wn * 16 + (lane & 15);
  const float b_r  = bi[j] + bh[j];
  const float b_z  = bi[HH + j] + bh[HH + j];
  const float b_nh = bh[2 * HH + j];
  const float b_nx = bi[2 * HH + j];
  #pragma unroll
  for (int mh = 0; mh < 2; ++mh)
    #pragma unroll
    for (int q = 0; q < 4; ++q) {
      int m = b0 + wm * 32 + mh * 16 + (lane >> 4) * 4 + q;
      float hpv = hprev[(size_t)m * HH + j];
      float rr = acc[mh][0][q] + b_r;
      float zz = acc[mh][1][q] + b_z;
      float nh = acc[mh][2][q] + b_nh;
      float nx = acc[mh][3][q] + b_nx;
      float r = 1.f / (1.f + __expf(-rr));
      float z = 1.f / (1.f + __expf(-zz));
      float n = tanhf(nx + r * nh);
      float hv = (1.f - z) * n + z * hpv;
      hout_f32[(size_t)m * HH + j] = hv;
      unsigned short hi = f2bf(hv);
      float lo = hv - bf2f(hi);
      int cb = ((j >> 3) & 3) ^ (m & 3);
      size_t dst = (size_t)m * 1024 + (size_t)(j & ~31) + cb * 8 + (j & 7);
      hout_hi[dst] = hi;
      hout_lo[dst] = f2bf(lo);
    }
}

// ---------------------------------------------------------------------------
// Prep kernels (unchanged).
// ---------------------------------------------------------------------------
__global__ __launch_bounds__(256) void prep_wgc(
    const float* __restrict__ Wh, const float* __restrict__ Wi,
    unsigned short* __restrict__ Whi, unsigned short* __restrict__ Wlo)
{
  size_t idx = (size_t)blockIdx.x * 256 + threadIdx.x;
  if (idx >= (size_t)4096 * 1120) return;
  int k = (int)(idx % 1120);
  int rg = (int)(idx / 1120);
  int jbv = rg >> 7, r = rg & 127;
  int jhi = r >> 6, rem = r & 63, g = rem >> 4, jlo = rem & 15;
  int j = jbv * 32 + jhi * 16 + jlo;
  float v = 0.f;
  if (g == 0)      v = (k < 1024) ? Wh[(size_t)j * HH + k]            : ((k < 1090) ? Wi[(size_t)j * CC + (k - 1024)] : 0.f);
  else if (g == 1) v = (k < 1024) ? Wh[(size_t)(HH + j) * HH + k]     : ((k < 1090) ? Wi[(size_t)(HH + j) * CC + (k - 1024)] : 0.f);
  else if (g == 2) v = (k < 1024) ? Wh[(size_t)(2 * HH + j) * HH + k] : 0.f;
  else             v = (k >= 1024 && k < 1090) ? Wi[(size_t)(2 * HH + j) * CC + (k - 1024)] : 0.f;
  unsigned short hi = f2bf(v);
  float lo = v - bf2f(hi);
  int kc = k >> 5, kk = k & 31;
  int cb = ((kk >> 3) ^ (r & 3)) & 3;
  size_t dst = (((size_t)jbv * 35 + kc) * 128 + r) * 32 + cb * 8 + (kk & 7);
  Whi[dst] = hi;
  Wlo[dst] = f2bf(lo);
}

__global__ __launch_bounds__(256) void prep_xall(
    const float* __restrict__ x,
    unsigned short* __restrict__ Xhi, unsigned short* __restrict__ Xlo)
{
  size_t idx = (size_t)blockIdx.x * 256 + threadIdx.x;
  if (idx >= (size_t)TT * BB * 96) return;
  int kx = (int)(idx % 96);
  size_t rem = idx / 96;
  int b = (int)(rem % BB);
  int t = (int)(rem / BB);
  float v = (kx < CC) ? x[(size_t)b * XROW + (size_t)t * CC + kx] : 0.f;
  unsigned short hi = f2bf(v);
  float lo = v - bf2f(hi);
  int cb = (((kx >> 3) & 3) ^ (b & 3)) & 3;
  size_t dst = ((size_t)t * BB + b) * 96 + (size_t)(kx & ~31) + cb * 8 + (kx & 7);
  Xhi[dst] = hi;
  Xlo[dst] = f2bf(lo);
}

__global__ __launch_bounds__(256) void wst_row_kernel(
    const float* __restrict__ src, int src_stride,
    const float* __restrict__ encWT, const float* __restrict__ encb,
    float* __restrict__ dst, const int* __restrict__ flagp)
{
  if (*flagp) return;   // fast path active: wst not used (region overlaid)
  __shared__ float s[CC];
  int b = blockIdx.y;
  int h = blockIdx.x * 256 + threadIdx.x;
  if (threadIdx.x < CC) s[threadIdx.x] = src[(size_t)b * src_stride + threadIdx.x];
  __syncthreads();
  float acc = encb[h];
  #pragma unroll
  for (int k = 0; k < CC; ++k) acc = fmaf(s[k], encWT[(size_t)k * HH + h], acc);
  dst[(size_t)b * (10 * HH) + h] = acc;
}

__global__ __launch_bounds__(256) void transpose_encW(
    const float* __restrict__ W, float* __restrict__ WT)
{
  int k = blockIdx.x;
  int h = blockIdx.y * 256 + threadIdx.x;
  WT[(size_t)k * HH + h] = W[(size_t)h * CC + k];
}

__global__ __launch_bounds__(256) void copy_last_kernel(
    const float* __restrict__ x, float* __restrict__ last)
{
  int idx = blockIdx.x * 256 + threadIdx.x;
  if (idx < BB * CC) {
    int b = idx / CC, c = idx - b * CC;
    last[idx] = x[(size_t)b * XROW + 63 * CC + c];
  }
}

__global__ __launch_bounds__(256) void flag_kernel(
    const float* __restrict__ lnA, const float* __restrict__ lnB, int* flagp)
{
  int idx = blockIdx.x * 256 + threadIdx.x;
  bool ok;
  if (idx < LL * HH) ok = (lnA[idx] == 1.0f);
  else ok = (lnB[idx - LL * HH] == 0.0f);
  if (!ok) atomicAnd(flagp, 0);
}

// ---------------------------------------------------------------------------
// Fast-path preps. tabs layout: K3[4356] | K2T[4356] | e1[66] | csE[66] |
// g0[66] | R[66] | be | sum_encb  (8978 floats)
// ---------------------------------------------------------------------------
__global__ __launch_bounds__(256) void prep_tabs(
    const float* __restrict__ encW, const float* __restrict__ encb,
    const float* __restrict__ outW, float* __restrict__ tabs)
{
  int idx = blockIdx.x * 256 + threadIdx.x;
  if (idx >= 8978) return;
  float a = 0.f;
  if (idx < 4356) {
    int c1 = idx / 66, c2 = idx % 66;
    for (int h = 0; h < HH; ++h) a = fmaf(encW[h * CC + c1], encW[h * CC + c2], a);
  } else if (idx < 8712) {
    int p = idx - 4356; int c = p / 66, c1 = p % 66;
    for (int h = 0; h < HH; ++h) a = fmaf(encW[h * CC + c1], outW[(size_t)c * HH + h], a);
  } else if (idx < 8778) {
    int c1 = idx - 8712;
    for (int h = 0; h < HH; ++h) a = fmaf(encW[h * CC + c1], encb[h], a);
  } else if (idx < 8844) {
    int c1 = idx - 8778;
    for (int h = 0; h < HH; ++h) a += encW[h * CC + c1];
  } else if (idx < 8910) {
    int c = idx - 8844;
    for (int h = 0; h < HH; ++h) a = fmaf(encb[h], outW[(size_t)c * HH + h], a);
  } else if (idx < 8976) {
    int c = idx - 8910;
    for (int h = 0; h < HH; ++h) a += outW[(size_t)c * HH + h];
  } else if (idx == 8976) {
    for (int h = 0; h < HH; ++h) a = fmaf(encb[h], encb[h], a);
  } else {
    for (int h = 0; h < HH; ++h) a += encb[h];
  }
  tabs[idx] = a;
}

__global__ __launch_bounds__(256) void prep_b144(
    const float* __restrict__ encW, const float* __restrict__ outW,
    const float* __restrict__ encb, float* __restrict__ B144)
{
  int idx = blockIdx.x * 256 + threadIdx.x;
  if (idx >= 1024 * 144) return;
  int k = idx / 144, n = idx % 144;
  float v;
  if (n < 66) v = encW[k * CC + n];
  else if (n < 132) v = outW[(size_t)(n - 66) * HH + k];
  else if (n == 132) v = encb[k];
  else if (n == 133) v = 1.f;
  else v = 0.f;
  B144[idx] = v;
}

__global__ __launch_bounds__(256) void linit_kernel(
    const float* __restrict__ x, float* __restrict__ l_ring,
    const int* __restrict__ flagp)
{
  if (!*flagp) return;
  int idx = blockIdx.x * 256 + threadIdx.x;
  if (idx >= 1024 * 9 * 66) return;
  int c = idx % 66; int r = idx / 66; int w = r % 9; int b = r / 9;
  l_ring[((size_t)b * 10 + w) * 66 + c] = x[(size_t)b * XROW + (54 + w) * CC + c];
}

// init-only: q = K3 @ l into ring slot (decoder steps fold this into tail)
__global__ __launch_bounds__(256) void qnew_kernel(
    const float* __restrict__ src, int sstride, const float* __restrict__ K3,
    float* __restrict__ q_ring, int slot, const int* __restrict__ flagp)
{
  if (!*flagp) return;
  __shared__ float Ks[4356];
  __shared__ float ls[8][66];
  int tid = threadIdx.x, b0 = blockIdx.x * 8;
  for (int i = tid; i < 4356; i += 256) Ks[i] = K3[i];
  for (int i = tid; i < 8 * 66; i += 256)
    ls[i / 66][i % 66] = src[(size_t)(b0 + i / 66) * sstride + (i % 66)];
  __syncthreads();
  for (int o = tid; o < 528; o += 256) {
    int bi = o / 66, c1 = o % 66;
    float a = 0.f;
    for (int c2 = 0; c2 < 66; ++c2) a = fmaf(Ks[c1 * 66 + c2], ls[bi][c2], a);
    q_ring[((size_t)(b0 + bi) * 10 + slot) * 66 + c1] = a;
  }
}

// dec_gemm: dp[kseg][b][144] partial of A[b][:] @ B144, k-chunks of 64
__global__ __launch_bounds__(256) void dec_gemm(
    const float* __restrict__ A, const float* __restrict__ B144,
    float* __restrict__ dp, const int* __restrict__ flagp)
{
  if (!*flagp) return;
  __shared__ float As[64][65];
  const int tid = threadIdx.x;
  const int b0 = blockIdx.x * 64;
  const int k0 = blockIdx.y * 64;
  for (int i = tid; i < 64 * 64; i += 256) {
    int r = i >> 6, c = i & 63;
    As[r][c] = A[(size_t)(b0 + r) * 1024 + k0 + c];
  }
  __syncthreads();
  const int b_sub = tid & 63;
  const int cg = __builtin_amdgcn_readfirstlane(tid >> 6);   // wave-uniform
  const int base_c = cg * 36;
  float acc[36];
  #pragma unroll
  for (int i = 0; i < 36; ++i) acc[i] = 0.f;
  for (int kk = 0; kk < 64; ++kk) {
    float av = As[b_sub][kk];
    const float* brow = B144 + (size_t)(k0 + kk) * 144 + base_c;  // uniform
    #pragma unroll
    for (int q = 0; q < 9; ++q) {
      f32x4 b4 = *(const f32x4*)(brow + q * 4);
      acc[q * 4 + 0] = fmaf(av, b4[0], acc[q * 4 + 0]);
      acc[q * 4 + 1] = fmaf(av, b4[1], acc[q * 4 + 1]);
      acc[q * 4 + 2] = fmaf(av, b4[2], acc[q * 4 + 2]);
      acc[q * 4 + 3] = fmaf(av, b4[3], acc[q * 4 + 3]);
    }
  }
  float* drow = dp + ((size_t)blockIdx.y * 1024 + b0 + b_sub) * 144 + base_c;
  #pragma unroll
  for (int q = 0; q < 9; ++q)
    *(f32x4*)(drow + q * 4) = { acc[q*4+0], acc[q*4+1], acc[q*4+2], acc[q*4+3] };
}

__global__ __launch_bounds__(256) void fast_combine(
    const float* __restrict__ dp, float* __restrict__ u, float* __restrict__ G,
    float* __restrict__ e, float* __restrict__ s, const int* __restrict__ flagp)
{
  if (!*flagp) return;
  int o = blockIdx.x * 256 + threadIdx.x;
  if (o >= 1024 * 144) return;
  int b = o / 144, c = o % 144;
  float a = 0.f;
  #pragma unroll
  for (int g = 0; g < KSEG; ++g) a += dp[((size_t)g * 1024 + b) * 144 + c];
  if (c < 66) u[b * 66 + c] = a;
  else if (c < 132) G[b * 66 + (c - 66)] = a;
  else if (c == 132) e[b] = a;
  else if (c == 133) s[b] = a;
}

// ---------------------------------------------------------------------------
// tail_kernel: per-b tail of a decode step. Fast path = qnew-fold + Gram +
// 12-layer affine-LN recursion + output. Generic path = round-4 mlp (exact).
// ---------------------------------------------------------------------------
__global__ __launch_bounds__(256) void tail_kernel(
    const float* __restrict__ hdec, const float* __restrict__ whp,
    float* __restrict__ last, float* __restrict__ l_ring,
    float* __restrict__ q_ring, const float* __restrict__ dp,
    const float* __restrict__ u_whp, const float* __restrict__ G_whp,
    const float* __restrict__ e_whp, const float* __restrict__ s_whp,
    const float* __restrict__ tabs,
    float* __restrict__ wst, const float* __restrict__ encWT,
    const float* __restrict__ encb,
    const float* __restrict__ seqW, const float* __restrict__ seqb,
    const float* __restrict__ lnA, const float* __restrict__ lnB,
    const float* __restrict__ outW, const float* __restrict__ outb,
    const float* __restrict__ mrgW, const float* __restrict__ mrgb,
    int ring0, float* __restrict__ outp,
    unsigned short* __restrict__ lpH, unsigned short* __restrict__ lpL,
    const int* __restrict__ flagp)
{
  const int b = blockIdx.x, tid = threadIdx.x;
  const int lane = tid & 63, wid = tid >> 6;
  const int slot9 = (ring0 == 0) ? 9 : ring0 - 1;   // == (ring0+9)%10

  if (*flagp) {
    // ================= fast path =================
    __shared__ float Ks[4356];
    __shared__ float l_all[10][66], Qv[10][66];
    __shared__ float yd[66], gd[66], uw[66], se1[66], scs[66], lmix[66];
    __shared__ float sW[156], sMm[156], sTt[156], sPp[156], sNn[156], sQq[156];
    __shared__ float sb12[12], sistd[12], scc[12], sfb[12], sdd12[12], swd[12], sVv[12], smrg[12];
    __shared__ float sred[12], misc[8];

    const float* K2T   = tabs + 4356;
    const float* tb_e1 = tabs + 8712;
    const float* tb_cs = tabs + 8778;
    const float* tb_g0 = tabs + 8844;
    const float* tb_R  = tabs + 8910;

    // ---- phase 0 ----
    for (int i = tid; i < 4356; i += 256) Ks[i] = tabs[i];
    for (int i = tid; i < 660; i += 256) {
      int w = i / 66, c = i % 66;
      int slot = ring0 + w; if (slot >= 10) slot -= 10;
      if (w < 9) {
        Qv[w][c] = q_ring[((size_t)b * 10 + slot) * 66 + c];
        l_all[w][c] = l_ring[((size_t)b * 10 + slot) * 66 + c];
      } else {
        l_all[9][c] = last[(size_t)b * 66 + c];
      }
    }
    for (int i = tid; i < 66; i += 256) {
      uw[i]  = u_whp[(size_t)b * 66 + i];
      se1[i] = tb_e1[i];
      scs[i] = tb_cs[i];
    }
    if (tid < 134) {
      float a = 0.f;
      #pragma unroll
      for (int g = 0; g < KSEG; ++g) a += dp[((size_t)g * 1024 + b) * 144 + tid];
      if (tid < 66) yd[tid] = a;
      else if (tid < 132) gd[tid - 66] = a;
      else if (tid == 132) misc[1] = a;   // <hdec, encb>
      else misc[2] = a;                   // sum_h hdec
    }
    if (tid >= 160 && tid < 172) smrg[tid - 160] = mrgW[tid - 160];
    {
      f32x4 hv = *(const f32x4*)&hdec[(size_t)b * 1024 + tid * 4];
      f32x4 wv = *(const f32x4*)&whp[(size_t)b * 1024 + tid * 4];
      float d2 = hv[0]*hv[0] + hv[1]*hv[1] + hv[2]*hv[2] + hv[3]*hv[3];
      float dw = hv[0]*wv[0] + hv[1]*wv[1] + hv[2]*wv[2] + hv[3]*wv[3];
      float w2 = wv[0]*wv[0] + wv[1]*wv[1] + wv[2]*wv[2] + wv[3]*wv[3];
      d2 = wave_sum63(d2); dw = wave_sum63(dw); w2 = wave_sum63(w2);
      if (lane == 63) { sred[wid*3] = d2; sred[wid*3+1] = dw; sred[wid*3+2] = w2; }
    }
    __syncthreads();
    // gap: qnew-fold (tid<66) + misc combines (tid>=128, disjoint)
    if (tid < 66) {
      float a = 0.f;
      for (int c2 = 0; c2 < 66; ++c2) a = fmaf(Ks[tid * 66 + c2], l_all[9][c2], a);
      Qv[9][tid] = a;
      q_ring[((size_t)b * 10 + slot9) * 66 + tid] = a;
    }
    if (tid >= 128 && tid < 131) {
      int i = tid - 128;
      misc[3 + i] = sred[i] + sred[3 + i] + sred[6 + i] + sred[9 + i];
    }
    if (tid == 132) misc[6] = tabs[8976];   // be
    if (tid == 133) misc[7] = tabs[8977];   // sum_encb
    __syncthreads();

    // ---- phase 1: Gram + fbar + init ----
    if (tid < 144) {
      int i = tid / 12, j = tid % 12;
      float gv;
      if (i == 0 && j == 0) gv = misc[5];
      else if (i == 11 && j == 11) gv = misc[3];
      else if ((i == 0 && j == 11) || (i == 11 && j == 0)) gv = misc[4];
      else if (i == 0 || j == 0) {
        int w = (i == 0 ? j : i) - 1;
        float a = e_whp[b];
        for (int c = 0; c < 66; ++c) a = fmaf(uw[c], l_all[w][c], a);
        gv = a;
      } else if (i == 11 || j == 11) {
        int w = (i == 11 ? j : i) - 1;
        float a = misc[1];
        for (int c = 0; c < 66; ++c) a = fmaf(yd[c], l_all[w][c], a);
        gv = a;
      } else {
        int wi = i - 1, wj = j - 1;
        float a = misc[6];
        for (int c = 0; c < 66; ++c) a = fmaf(se1[c], l_all[wi][c] + l_all[wj][c], a);
        for (int c = 0; c < 66; ++c) a = fmaf(l_all[wi][c], Qv[wj][c], a);
        gv = a;
      }
      sMm[i * 13 + j] = gv * (1.f / 1024.f);
      sTt[i * 13 + j] = (i == j) ? 1.f : 0.f;
    }
    if (tid >= 144 && tid < 156) {
      int k = tid - 144;
      float fb;
      if (k == 0) fb = s_whp[b] * (1.f / 1024.f);
      else if (k == 11) fb = misc[2] * (1.f / 1024.f);
      else {
        float a = misc[7];
        for (int c = 0; c < 66; ++c) a = fmaf(scs[c], l_all[k - 1][c], a);
        fb = a * (1.f / 1024.f);
      }
      sfb[k] = fb;
      sdd12[k] = 0.f;
    }
    __syncthreads();

    // ---- phase 2: 12-layer recursion ----
    for (int l = 0; l < LL; ++l) {
      if (tid < 144) sW[(tid / 12) * 13 + (tid % 12)] = seqW[l * 144 + tid];
      if (tid >= 160 && tid < 172) sb12[tid - 160] = seqb[l * 12 + (tid - 160)];
      __syncthreads();
      if (tid < 144) {
        int s = tid / 12, k = tid % 12;
        float a = 0.f;
        #pragma unroll
        for (int k2 = 0; k2 < 12; ++k2) a = fmaf(sW[s * 13 + k2], sMm[k2 * 13 + k], a);
        sPp[s * 13 + k] = a;
      }
      __syncthreads();
      if (tid < 12) {
        int s = tid;
        float mu = sb12[s];
        #pragma unroll
        for (int k = 0; k < 12; ++k) mu = fmaf(sW[s * 13 + k], sfb[k], mu);
        float e2 = 0.f;
        #pragma unroll
        for (int k = 0; k < 12; ++k) e2 = fmaf(sPp[s * 13 + k], sW[s * 13 + k], e2);
        float wf = mu - sb12[s];
        float var = fmaxf(e2 - wf * wf, 0.f);
        float is = 1.f / sqrtf(var + 1e-5f);
        sistd[s] = is;
        scc[s] = is * (sb12[s] - mu);
      }
      __syncthreads();
      if (tid < 144) {
        int i = tid / 12, j = tid % 12;
        float a = 0.f;
        #pragma unroll
        for (int k = 0; k < 12; ++k) a = fmaf(sW[i * 13 + k], sTt[k * 13 + j], a);
        sQq[i * 13 + j] = a;
        sNn[i * 13 + j] = sMm[i * 13 + j] + sistd[i] * sPp[i * 13 + j];
      }
      if (tid >= 144 && tid < 156) {
        int i = tid - 144;
        float a = 0.f;
        #pragma unroll
        for (int k = 0; k < 12; ++k) a = fmaf(sW[i * 13 + k], sdd12[k], a);
        swd[i] = a;
      }
      __syncthreads();
      if (tid < 144) {
        int i = tid / 12, j = tid % 12;
        sTt[i * 13 + j] += sistd[i] * sQq[i * 13 + j];
        float a = 0.f;
        #pragma unroll
        for (int k = 0; k < 12; ++k) a = fmaf(sNn[i * 13 + k], sW[j * 13 + k], a);
        sPp[i * 13 + j] = a;
      }
      if (tid >= 144 && tid < 156) {
        int i = tid - 144;
        sdd12[i] = sdd12[i] + sistd[i] * swd[i] + scc[i];
      }
      __syncthreads();
      if (tid < 144) {
        int i = tid / 12, j = tid % 12;
        sMm[i * 13 + j] = sNn[i * 13 + j] + sPp[i * 13 + j] * sistd[j]
                        + sfb[i] * scc[j] + scc[i] * sfb[j] - scc[i] * scc[j];
      }
      __syncthreads();
    }

    // ---- phase 3: output ----
    if (tid < 12) {
      float a = 0.f;
      #pragma unroll
      for (int s = 0; s < 12; ++s) a = fmaf(smrg[s], sTt[s * 13 + tid], a);
      sVv[tid] = a;
    }
    if (tid == 200) {
      float a = 0.f;
      for (int s = 0; s < 12; ++s) a = fmaf(smrg[s], sdd12[s], a);
      misc[0] = a;
    }
    __syncthreads();
    if (tid < 66) {
      float a = 0.f;
      #pragma unroll
      for (int w = 0; w < 9; ++w) a = fmaf(sVv[1 + w], l_all[w][tid], a);
      a = fmaf(sVv[10], l_all[9][tid], a);
      lmix[tid] = a;
    }
    __syncthreads();
    if (tid < 66) {
      int c = tid;
      float vsr = 0.f, smw = 0.f;
      #pragma unroll
      for (int k = 1; k <= 10; ++k) vsr += sVv[k];
      #pragma unroll
      for (int s = 0; s < 12; ++s) smw += smrg[s];
      float lastv = l_all[9][c];
      float acc = sVv[0] * G_whp[(size_t)b * 66 + c]
                + vsr * tb_g0[c]
                + sVv[11] * gd[c]
                + misc[0] * tb_R[c]
                + smw * outb[c] + mrgb[0] + lastv;
      const float* krow = K2T + c * 66;
      for (int c2 = 0; c2 < 66; ++c2) acc = fmaf(lmix[c2], krow[c2], acc);
      outp[(size_t)b * XROW + c] = acc;
      last[(size_t)b * 66 + c] = acc;
      l_ring[((size_t)b * 10 + slot9) * 66 + c] = lastv;
      unsigned short hi = f2bf(acc);
      float lo = acc - bf2f(hi);
      int cb = (((c >> 3) & 3) ^ (b & 3)) & 3;
      size_t dst = (size_t)b * 96 + (size_t)(c & ~31) + cb * 8 + (c & 7);
      lpH[dst] = hi;
      lpL[dst] = f2bf(lo);
    }
    return;
  }

  // ================= generic fallback (round-4 mlp, exact) =================
  __shared__ float red[4][24];
  __shared__ f2 mustd2[SS];
  __shared__ float g_lds[HH];
  __shared__ float nc[CC];

  const int h0 = tid;
  const int h1 = tid + 512;
  const float* lrow = last + (size_t)b * CC;
  f2 wnew[2];
  {
    f2 a0 = { encb[h0], encb[h0 + 256] };
    f2 a1 = { encb[h1], encb[h1 + 256] };
    #pragma unroll 11
    for (int k = 0; k < CC; ++k) {
      float lv = lrow[k];
      f2 lv2 = { lv, lv };
      f2 w0 = { encWT[(size_t)k * HH + h0], encWT[(size_t)k * HH + h0 + 256] };
      f2 w1 = { encWT[(size_t)k * HH + h1], encWT[(size_t)k * HH + h1 + 256] };
      a0 = __builtin_elementwise_fma(lv2, w0, a0);
      a1 = __builtin_elementwise_fma(lv2, w1, a1);
    }
    wnew[0] = a0; wnew[1] = a1;
    float* wd = wst + ((size_t)b * 10 + slot9) * HH;
    wd[h0] = a0.x; wd[h0 + 256] = a0.y;
    wd[h1] = a1.x; wd[h1 + 256] = a1.y;
  }

  f2 fr[2][SS];
  {
    const float* whb = whp + (size_t)b * HH;
    const float* hb  = hdec + (size_t)b * HH;
    fr[0][0]  = { whb[h0], whb[h0 + 256] };
    fr[1][0]  = { whb[h1], whb[h1 + 256] };
    fr[0][11] = { hb[h0], hb[h0 + 256] };
    fr[1][11] = { hb[h1], hb[h1 + 256] };
    #pragma unroll
    for (int w = 0; w < 9; ++w) {
      int slot = ring0 + w; if (slot >= 10) slot -= 10;
      const float* ws_ = wst + ((size_t)b * 10 + slot) * HH;
      fr[0][1 + w] = { ws_[h0], ws_[h0 + 256] };
      fr[1][1 + w] = { ws_[h1], ws_[h1 + 256] };
    }
    fr[0][10] = wnew[0];
    fr[1][10] = wnew[1];
  }

  #pragma unroll 1
  for (int l = 0; l < LL; ++l) {
    const float* W  = seqW + (size_t)l * SS * SS;
    const float* Bv = seqb + (size_t)l * SS;
    const float* lA = lnA + (size_t)l * HH;
    const float* lB = lnB + (size_t)l * HH;
    f2 al[2], be[2];
    al[0] = { lA[h0], lA[h0 + 256] };  al[1] = { lA[h1], lA[h1 + 256] };
    be[0] = { lB[h0], lB[h0 + 256] };  be[1] = { lB[h1], lB[h1 + 256] };

    f2 y[2][SS];
    #pragma unroll
    for (int s = 0; s < SS; ++s) {
      float bv = Bv[s];
      f2 a0 = { bv, bv }, a1 = { bv, bv };
      #pragma unroll
      for (int k = 0; k < SS; ++k) {
        float wv = W[s * SS + k];
        f2 wv2 = { wv, wv };
        a0 = __builtin_elementwise_fma(fr[0][k], wv2, a0);
        a1 = __builtin_elementwise_fma(fr[1][k], wv2, a1);
      }
      y[0][s] = a0; y[1][s] = a1;
      f2 pp = a0 + a1;
      float ps = wave_sum63(pp.x + pp.y);
      f2 qq = __builtin_elementwise_fma(a0, a0, a1 * a1);
      float pq = wave_sum63(qq.x + qq.y);
      if (lane == 63) { red[wid][s] = ps; red[wid][12 + s] = pq; }
    }
    __syncthreads();
    if (tid < SS) {
      float S = red[0][tid] + red[1][tid] + red[2][tid] + red[3][tid];
      float Q = red[0][12 + tid] + red[1][12 + tid] + red[2][12 + tid] + red[3][12 + tid];
      float mu = S * (1.f / HH);
      float var = Q * (1.f / HH) - mu * mu;
      mustd2[tid] = { mu, 1.f / sqrtf(var + 1e-5f) };
    }
    __syncthreads();
    #pragma unroll
    for (int s = 0; s < SS; ++s) {
      f2 mi = mustd2[s];
      f2 mus = { mi.x, mi.x };
      f2 isd = { mi.y, mi.y };
      #pragma unroll
      for (int p = 0; p < 2; ++p) {
        f2 t = (y[p][s] - mus) * isd;
        fr[p][s] = __builtin_elementwise_fma(t, al[p], fr[p][s]) + be[p];
      }
    }
    __syncthreads();
  }

  float smw = 0.f;
  f2 g[2] = { {0.f, 0.f}, {0.f, 0.f} };
  #pragma unroll
  for (int s = 0; s < SS; ++s) {
    float mv = mrgW[s];
    smw += mv;
    f2 mv2 = { mv, mv };
    g[0] = __builtin_elementwise_fma(mv2, fr[0][s], g[0]);
    g[1] = __builtin_elementwise_fma(mv2, fr[1][s], g[1]);
  }
  g_lds[h0] = g[0].x; g_lds[h0 + 256] = g[0].y;
  g_lds[h1] = g[1].x; g_lds[h1 + 256] = g[1].y;
  const float mbv = mrgb[0];
  __syncthreads();
  #pragma unroll 1
  for (int i = 0; i < 17; ++i) {
    int c = wid + 4 * i;
    if (c < CC) {
      const float* ow = outW + (size_t)c * HH;
      float acc = 0.f;
      #pragma unroll
      for (int q = 0; q < 16; ++q) acc = fmaf(g_lds[lane + q * 64], ow[lane + q * 64], acc);
      acc = wave_sum63(acc);
      if (lane == 63) nc[c] = acc + outb[c] * smw + mbv + lrow[c];
    }
  }
  __syncthreads();
  if (tid < CC) {
    float nv = nc[tid];
    outp[(size_t)b * XROW + tid] = nv;
    last[(size_t)b * CC + tid] = nv;
    unsigned short hi = f2bf(nv);
    float lo = nv - bf2f(hi);
    int cb = (((tid >> 3) & 3) ^ (b & 3)) & 3;
    size_t dst = (size_t)b * 96 + (size_t)(tid & ~31) + cb * 8 + (tid & 7);
    lpH[dst] = hi;
    lpL[dst] = f2bf(lo);
  }
}

// ---------------------------------------------------------------------------
extern "C" void kernel_launch(void* const* d_in, const int* in_sizes, int n_in,
                              void* d_out, int out_size, void* d_ws, size_t ws_size,
                              hipStream_t stream) {
  const float* x    = (const float*)d_in[0];
  const float* gWi  = (const float*)d_in[1];
  const float* gWh  = (const float*)d_in[2];
  const float* gbi  = (const float*)d_in[3];
  const float* gbh  = (const float*)d_in[4];
  const float* encW = (const float*)d_in[5];
  const float* encb = (const float*)d_in[6];
  const float* seqW = (const float*)d_in[7];
  const float* seqb = (const float*)d_in[8];
  const float* lnA  = (const float*)d_in[9];
  const float* lnB  = (const float*)d_in[10];
  const float* outW = (const float*)d_in[11];
  const float* outb = (const float*)d_in[12];
  const float* mrgW = (const float*)d_in[13];
  const float* mrgb = (const float*)d_in[14];
  float* out = (float*)d_out;

  char* p = (char*)d_ws;
  auto alloc = [&](size_t bytes) { char* r = p; p += (bytes + 255) & ~(size_t)255; return r; };
  float* encWT = (float*)alloc((size_t)CC * HH * 4);
  float* last  = (float*)alloc((size_t)BB * CC * 4);
  float* wst   = (float*)alloc((size_t)BB * 10 * HH * 4);   // generic ring / fast overlay
  float* hf[3];
  for (int i = 0; i < 3; ++i) hf[i] = (float*)alloc((size_t)BB * HH * 4);
  unsigned short* WgH = (unsigned short*)alloc((size_t)4096 * 1120 * 2);
  unsigned short* WgL = (unsigned short*)alloc((size_t)4096 * 1120 * 2);
  unsigned short* XaH = (unsigned short*)alloc((size_t)TT * BB * 96 * 2);
  unsigned short* XaL = (unsigned short*)alloc((size_t)TT * BB * 96 * 2);
  unsigned short* hhi[3]; unsigned short* hlo[3];
  for (int i = 0; i < 3; ++i) {
    hhi[i] = (unsigned short*)alloc((size_t)BB * HH * 2);
    hlo[i] = (unsigned short*)alloc((size_t)BB * HH * 2);
  }
  unsigned short* lpH = (unsigned short*)alloc((size_t)BB * 96 * 2);
  unsigned short* lpL = (unsigned short*)alloc((size_t)BB * 96 * 2);
  int* flag = (int*)alloc(256);
  if ((size_t)(p - (char*)d_ws) > ws_size) return;  // insufficient workspace

  // fast-path overlay inside the wst region (mutually exclusive by flag)
  char* ov = (char*)wst;
  float* B144  = (float*)ov;                 ov += (size_t)1024 * 144 * 4;
  float* dp    = (float*)ov;                 ov += (size_t)KSEG * 1024 * 144 * 4;
  float* l_ring= (float*)ov;                 ov += (size_t)1024 * 10 * 66 * 4;
  float* q_ring= (float*)ov;                 ov += (size_t)1024 * 10 * 66 * 4;
  float* u_whp = (float*)ov;                 ov += (size_t)1024 * 66 * 4;
  float* G_whp = (float*)ov;                 ov += (size_t)1024 * 66 * 4;
  float* e_whp = (float*)ov;                 ov += 4096;
  float* s_whp = (float*)ov;                 ov += 4096;
  float* tabs  = (float*)ov;                 ov += 9216 * 4;

  // ---- one-time prep ----
  hipMemsetAsync(flag, 0xFF, 4, stream);
  flag_kernel<<<dim3(96), 256, 0, stream>>>(lnA, lnB, flag);
  prep_wgc<<<dim3((4096u * 1120u) / 256u), 256, 0, stream>>>(gWh, gWi, WgH, WgL);
  prep_xall<<<dim3(((unsigned)TT * BB * 96) / 256u), 256, 0, stream>>>(x, XaH, XaL);
  transpose_encW<<<dim3(CC, HH/256), 256, 0, stream>>>(encW, encWT);
  copy_last_kernel<<<dim3((BB*CC + 255)/256), 256, 0, stream>>>(x, last);
  prep_b144<<<dim3(576), 256, 0, stream>>>(encW, outW, encb, B144);
  prep_tabs<<<dim3(36), 256, 0, stream>>>(encW, encb, outW, tabs);
  linit_kernel<<<dim3((1024*9*66)/256), 256, 0, stream>>>(x, l_ring, flag);
  for (int w = 0; w < 9; ++w)
    qnew_kernel<<<dim3(128), 256, 0, stream>>>(x + (size_t)(54 + w) * CC, XROW,
                                               tabs, q_ring, w, flag);
  hipMemsetAsync(hf[0], 0, (size_t)BB * HH * 4, stream);
  hipMemsetAsync(hhi[0], 0, (size_t)BB * HH * 2, stream);
  hipMemsetAsync(hlo[0], 0, (size_t)BB * HH * 2, stream);

  const dim3 ggrid(512);

  // ---- encoder: 63 GRU steps ----
  int cur = 0;
  for (int t = 0; t < 63; ++t) {
    int nxt = 1 - cur;
    gru_mfma<<<ggrid, 256, 0, stream>>>(
        hhi[cur], hlo[cur], hf[cur],
        XaH + (size_t)t * BB * 96, XaL + (size_t)t * BB * 96,
        WgH, WgL, gbi, gbh, hf[nxt], hhi[nxt], hlo[nxt]);
    cur = nxt;
  }
  gru_mfma<<<ggrid, 256, 0, stream>>>(
      hhi[cur], hlo[cur], hf[cur],
      XaH + (size_t)63 * BB * 96, XaL + (size_t)63 * BB * 96,
      WgH, WgL, gbi, gbh, hf[2], hhi[2], hlo[2]);

  // whp-derived persistent fast-path arrays
  dec_gemm<<<dim3(16, KSEG), 256, 0, stream>>>(hf[2], B144, dp, flag);
  fast_combine<<<dim3(576), 256, 0, stream>>>(dp, u_whp, G_whp, e_whp, s_whp, flag);

  // generic-path wst init (skipped when fast)
  for (int w = 0; w < 9; ++w)
    wst_row_kernel<<<dim3(HH/256, BB), 256, 0, stream>>>(
        x + (size_t)(54 + w) * CC, XROW, encWT, encb, wst + (size_t)w * HH, flag);

  // ---- decoder: 64 steps ----
  int hc = 2;
  for (int t = 0; t < 64; ++t) {
    if (t > 0) {
      int hn = (t - 1) & 1;
      gru_mfma<<<ggrid, 256, 0, stream>>>(
          hhi[hc], hlo[hc], hf[hc], lpH, lpL,
          WgH, WgL, gbi, gbh, hf[hn], hhi[hn], hlo[hn]);
      hc = hn;
    }
    dec_gemm<<<dim3(16, KSEG), 256, 0, stream>>>(hf[hc], B144, dp, flag);
    tail_kernel<<<dim3(BB), 256, 0, stream>>>(
        hf[hc], hf[2], last, l_ring, q_ring, dp,
        u_whp, G_whp, e_whp, s_whp, tabs,
        wst, encWT, encb, seqW, seqb, lnA, lnB, outW, outb, mrgW, mrgb,
        t % 10, out + (size_t)t * CC, lpH, lpL, flag);
  }
}

// Round 7
// 7996.930 us; speedup vs baseline: 1.8918x; 1.1007x over previous
//
#include <hip/hip_runtime.h>
#include <hip/hip_bf16.h>
#include <cstddef>
#include <cstdint>

#define BB 1024
#define TT 64
#define CC 66
#define HH 1024
#define SS 12
#define LL 12
#define XROW (TT*CC)   // 4224 floats per batch row of x
#define DPSEG 32       // dp segments (one per jb)

typedef __attribute__((ext_vector_type(8))) __bf16 bfrag;
typedef __attribute__((ext_vector_type(4))) float f32x4;
typedef __attribute__((ext_vector_type(8))) short s8v;
typedef __attribute__((ext_vector_type(2))) float f2;

__device__ __forceinline__ unsigned short f2bf(float f) {
  unsigned int u = __builtin_bit_cast(unsigned int, f);
  unsigned int r = u + 0x7FFFu + ((u >> 16) & 1u);
  return (unsigned short)(r >> 16);
}
__device__ __forceinline__ float bf2f(unsigned short h) {
  unsigned int u = ((unsigned int)h) << 16;
  return __builtin_bit_cast(float, u);
}

__device__ __forceinline__ void gload16(const void* g, void* l) {
  __builtin_amdgcn_global_load_lds(
      (const __attribute__((address_space(1))) unsigned int*)g,
      (__attribute__((address_space(3))) unsigned int*)l, 16, 0, 0);
}

// DPP-based wave64 sum: result lands in lane 63. VALU-only (no LDS pipe).
template<int CTRL, int RM>
__device__ __forceinline__ float dppadd(float v) {
  int x = __builtin_amdgcn_update_dpp(0, __builtin_bit_cast(int, v),
                                      CTRL, RM, 0xF, true);
  return v + __builtin_bit_cast(float, x);
}
__device__ __forceinline__ float wave_sum63(float v) {
  v = dppadd<0x111, 0xF>(v);   // row_shr:1
  v = dppadd<0x112, 0xF>(v);   // row_shr:2
  v = dppadd<0x114, 0xF>(v);   // row_shr:4
  v = dppadd<0x118, 0xF>(v);   // row_shr:8
  v = dppadd<0x142, 0xa>(v);   // row_bcast:15
  v = dppadd<0x143, 0xc>(v);   // row_bcast:31 -> lane 63 = full sum
  return v;
}

// ---------------------------------------------------------------------------
// Split-bf16 MFMA GRU step, v4: 3-buffer counted-vmcnt pipeline (round 6)
// + fused dp partial GEMM in the epilogue (dp32[jb][b][144] = h_tile @ B144),
// guarded by do_dp && *flagp. Staging LDS is reused for the h tile.
// ---------------------------------------------------------------------------
__global__ __launch_bounds__(256) void gru_mfma(
    const unsigned short* __restrict__ Ahi, const unsigned short* __restrict__ Alo,
    const float* __restrict__ hprev,
    const unsigned short* __restrict__ Xhi, const unsigned short* __restrict__ Xlo,
    const unsigned short* __restrict__ Whi, const unsigned short* __restrict__ Wlo,
    const float* __restrict__ bi, const float* __restrict__ bh,
    float* __restrict__ hout_f32,
    unsigned short* __restrict__ hout_hi, unsigned short* __restrict__ hout_lo,
    const float* __restrict__ B144, float* __restrict__ dp32,
    const int* __restrict__ flagp, int do_dp)
{
  __shared__ __align__(16) unsigned short AsH[3][64*32];
  __shared__ __align__(16) unsigned short AsL[3][64*32];
  __shared__ __align__(16) unsigned short BsH[3][128*32];
  __shared__ __align__(16) unsigned short BsL[3][128*32];

  const int tid = threadIdx.x, lane = tid & 63, wid = tid >> 6;
  const int bid = blockIdx.x;
  const int idx = bid >> 3;
  const int jb = (bid & 7) * 4 + (idx & 3);
  const int b0 = (idx >> 2) * 64;
  const int wm = wid >> 1, wn = wid & 1;
  const int aR = lane >> 2, aC = lane & 3;

  auto stage = [&](int bs, int kc) {
    const unsigned short *shi, *slo; size_t go;
    int row = wid * 16 + aR;
    if (kc < 32) {
      go = (size_t)(b0 + row) * 1024 + (size_t)kc * 32 + aC * 8;
      shi = Ahi; slo = Alo;
    } else {
      go = (size_t)(b0 + row) * 96 + (size_t)(kc - 32) * 32 + aC * 8;
      shi = Xhi; slo = Xlo;
    }
    gload16(shi + go, &AsH[bs][wid * 512]);
    gload16(slo + go, &AsL[bs][wid * 512]);
    size_t base = ((size_t)jb * 35 + kc) * 4096;
    size_t go0 = base + (size_t)(wid * 32 + aR) * 32 + aC * 8;
    gload16(Whi + go0,       &BsH[bs][wid * 1024]);
    gload16(Whi + go0 + 512, &BsH[bs][wid * 1024 + 512]);
    gload16(Wlo + go0,       &BsL[bs][wid * 1024]);
    gload16(Wlo + go0 + 512, &BsL[bs][wid * 1024 + 512]);
  };

  int offA[2], offB[4];
  #pragma unroll
  for (int mh = 0; mh < 2; ++mh) {
    int r = wm * 32 + mh * 16 + (lane & 15);
    int cb = (lane >> 4) ^ (r & 3);
    offA[mh] = r * 32 + cb * 8;
  }
  #pragma unroll
  for (int g = 0; g < 4; ++g) {
    int r = wn * 64 + g * 16 + (lane & 15);
    int cb = (lane >> 4) ^ (r & 3);
    offB[g] = r * 32 + cb * 8;
  }

  f32x4 acc[2][4] = {};

  stage(0, 0);
  stage(1, 1);

  int cur = 0;
  for (int kc = 0; kc < 34; ++kc) {
    asm volatile("s_waitcnt vmcnt(6)" ::: "memory");
    __builtin_amdgcn_s_barrier();
    asm volatile("" ::: "memory");

    bfrag ah[2], al[2], bhf[4], blf[4];
    #pragma unroll
    for (int mh = 0; mh < 2; ++mh) {
      ah[mh] = __builtin_bit_cast(bfrag, *(const s8v*)(&AsH[cur][offA[mh]]));
      al[mh] = __builtin_bit_cast(bfrag, *(const s8v*)(&AsL[cur][offA[mh]]));
    }
    #pragma unroll
    for (int g = 0; g < 4; ++g) {
      bhf[g] = __builtin_bit_cast(bfrag, *(const s8v*)(&BsH[cur][offB[g]]));
      blf[g] = __builtin_bit_cast(bfrag, *(const s8v*)(&BsL[cur][offB[g]]));
    }
    if (kc < 33) {
      int st = (cur >= 1) ? cur - 1 : 2;   // (cur+2)%3
      stage(st, kc + 2);
    }
    #pragma unroll
    for (int mh = 0; mh < 2; ++mh)
      #pragma unroll
      for (int g = 0; g < 4; ++g) {
        acc[mh][g] = __builtin_amdgcn_mfma_f32_16x16x32_bf16(ah[mh], bhf[g], acc[mh][g], 0, 0, 0);
        acc[mh][g] = __builtin_amdgcn_mfma_f32_16x16x32_bf16(ah[mh], blf[g], acc[mh][g], 0, 0, 0);
        acc[mh][g] = __builtin_amdgcn_mfma_f32_16x16x32_bf16(al[mh], bhf[g], acc[mh][g], 0, 0, 0);
      }
    cur = (cur < 2) ? cur + 1 : 0;
  }
  // peeled kc = 34 (cur == 1)
  {
    asm volatile("s_waitcnt vmcnt(0)" ::: "memory");
    __builtin_amdgcn_s_barrier();
    asm volatile("" ::: "memory");
    bfrag ah[2], al[2], bhf[4], blf[4];
    #pragma unroll
    for (int mh = 0; mh < 2; ++mh) {
      ah[mh] = __builtin_bit_cast(bfrag, *(const s8v*)(&AsH[1][offA[mh]]));
      al[mh] = __builtin_bit_cast(bfrag, *(const s8v*)(&AsL[1][offA[mh]]));
    }
    #pragma unroll
    for (int g = 0; g < 4; ++g) {
      bhf[g] = __builtin_bit_cast(bfrag, *(const s8v*)(&BsH[1][offB[g]]));
      blf[g] = __builtin_bit_cast(bfrag, *(const s8v*)(&BsL[1][offB[g]]));
    }
    #pragma unroll
    for (int mh = 0; mh < 2; ++mh)
      #pragma unroll
      for (int g = 0; g < 4; ++g) {
        acc[mh][g] = __builtin_amdgcn_mfma_f32_16x16x32_bf16(ah[mh], bhf[g], acc[mh][g], 0, 0, 0);
        acc[mh][g] = __builtin_amdgcn_mfma_f32_16x16x32_bf16(ah[mh], blf[g], acc[mh][g], 0, 0, 0);
        acc[mh][g] = __builtin_amdgcn_mfma_f32_16x16x32_bf16(al[mh], bhf[g], acc[mh][g], 0, 0, 0);
      }
  }

  // ---- gates epilogue (register-local); keep h values for fused dp ----
  const int j = jb * 32 + wn * 16 + (lane & 15);
  const float b_r  = bi[j] + bh[j];
  const float b_z  = bi[HH + j] + bh[HH + j];
  const float b_nh = bh[2 * HH + j];
  const float b_nx = bi[2 * HH + j];
  float hvv[2][4];
  #pragma unroll
  for (int mh = 0; mh < 2; ++mh)
    #pragma unroll
    for (int q = 0; q < 4; ++q) {
      int m = b0 + wm * 32 + mh * 16 + (lane >> 4) * 4 + q;
      float hpv = hprev[(size_t)m * HH + j];
      float rr = acc[mh][0][q] + b_r;
      float zz = acc[mh][1][q] + b_z;
      float nh = acc[mh][2][q] + b_nh;
      float nx = acc[mh][3][q] + b_nx;
      float r = 1.f / (1.f + __expf(-rr));
      float z = 1.f / (1.f + __expf(-zz));
      float n = tanhf(nx + r * nh);
      float hv = (1.f - z) * n + z * hpv;
      hvv[mh][q] = hv;
      hout_f32[(size_t)m * HH + j] = hv;
      unsigned short hi = f2bf(hv);
      float lo = hv - bf2f(hi);
      int cb = ((j >> 3) & 3) ^ (m & 3);
      size_t dst = (size_t)m * 1024 + (size_t)(j & ~31) + cb * 8 + (j & 7);
      hout_hi[dst] = hi;
      hout_lo[dst] = f2bf(lo);
    }

  // ---- fused dp partial: dp32[jb][b][144] = h_tile(64x32) @ B144-rows ----
  if (do_dp && *flagp) {
    float* hsf = reinterpret_cast<float*>(&AsH[0][0]);   // 64x33 floats (8448B)
    __syncthreads();   // all LDS frag reads done -> safe to overwrite staging
    #pragma unroll
    for (int mh = 0; mh < 2; ++mh)
      #pragma unroll
      for (int q = 0; q < 4; ++q) {
        int mloc = wm * 32 + mh * 16 + (lane >> 4) * 4 + q;
        int jloc = wn * 16 + (lane & 15);
        hsf[mloc * 33 + jloc] = hvv[mh][q];
      }
    __syncthreads();
    const int b_sub = tid & 63;
    const int cg = __builtin_amdgcn_readfirstlane(tid >> 6);
    const int base_c = cg * 36;
    float acc36[36];
    #pragma unroll
    for (int i = 0; i < 36; ++i) acc36[i] = 0.f;
    for (int kk = 0; kk < 32; ++kk) {
      float av = hsf[b_sub * 33 + kk];
      const float* brow = B144 + (size_t)(jb * 32 + kk) * 144 + base_c;  // uniform
      #pragma unroll
      for (int qq = 0; qq < 9; ++qq) {
        f32x4 b4 = *(const f32x4*)(brow + qq * 4);
        acc36[qq*4+0] = fmaf(av, b4[0], acc36[qq*4+0]);
        acc36[qq*4+1] = fmaf(av, b4[1], acc36[qq*4+1]);
        acc36[qq*4+2] = fmaf(av, b4[2], acc36[qq*4+2]);
        acc36[qq*4+3] = fmaf(av, b4[3], acc36[qq*4+3]);
      }
    }
    float* drow = dp32 + ((size_t)jb * 1024 + b0 + b_sub) * 144 + base_c;
    #pragma unroll
    for (int qq = 0; qq < 9; ++qq)
      *(f32x4*)(drow + qq * 4) = { acc36[qq*4+0], acc36[qq*4+1], acc36[qq*4+2], acc36[qq*4+3] };
  }
}

// ---------------------------------------------------------------------------
// Prep kernels (unchanged).
// ---------------------------------------------------------------------------
__global__ __launch_bounds__(256) void prep_wgc(
    const float* __restrict__ Wh, const float* __restrict__ Wi,
    unsigned short* __restrict__ Whi, unsigned short* __restrict__ Wlo)
{
  size_t idx = (size_t)blockIdx.x * 256 + threadIdx.x;
  if (idx >= (size_t)4096 * 1120) return;
  int k = (int)(idx % 1120);
  int rg = (int)(idx / 1120);
  int jbv = rg >> 7, r = rg & 127;
  int jhi = r >> 6, rem = r & 63, g = rem >> 4, jlo = rem & 15;
  int j = jbv * 32 + jhi * 16 + jlo;
  float v = 0.f;
  if (g == 0)      v = (k < 1024) ? Wh[(size_t)j * HH + k]            : ((k < 1090) ? Wi[(size_t)j * CC + (k - 1024)] : 0.f);
  else if (g == 1) v = (k < 1024) ? Wh[(size_t)(HH + j) * HH + k]     : ((k < 1090) ? Wi[(size_t)(HH + j) * CC + (k - 1024)] : 0.f);
  else if (g == 2) v = (k < 1024) ? Wh[(size_t)(2 * HH + j) * HH + k] : 0.f;
  else             v = (k >= 1024 && k < 1090) ? Wi[(size_t)(2 * HH + j) * CC + (k - 1024)] : 0.f;
  unsigned short hi = f2bf(v);
  float lo = v - bf2f(hi);
  int kc = k >> 5, kk = k & 31;
  int cb = ((kk >> 3) ^ (r & 3)) & 3;
  size_t dst = (((size_t)jbv * 35 + kc) * 128 + r) * 32 + cb * 8 + (kk & 7);
  Whi[dst] = hi;
  Wlo[dst] = f2bf(lo);
}

__global__ __launch_bounds__(256) void prep_xall(
    const float* __restrict__ x,
    unsigned short* __restrict__ Xhi, unsigned short* __restrict__ Xlo)
{
  size_t idx = (size_t)blockIdx.x * 256 + threadIdx.x;
  if (idx >= (size_t)TT * BB * 96) return;
  int kx = (int)(idx % 96);
  size_t rem = idx / 96;
  int b = (int)(rem % BB);
  int t = (int)(rem / BB);
  float v = (kx < CC) ? x[(size_t)b * XROW + (size_t)t * CC + kx] : 0.f;
  unsigned short hi = f2bf(v);
  float lo = v - bf2f(hi);
  int cb = (((kx >> 3) & 3) ^ (b & 3)) & 3;
  size_t dst = ((size_t)t * BB + b) * 96 + (size_t)(kx & ~31) + cb * 8 + (kx & 7);
  Xhi[dst] = hi;
  Xlo[dst] = f2bf(lo);
}

__global__ __launch_bounds__(256) void wst_row_kernel(
    const float* __restrict__ src, int src_stride,
    const float* __restrict__ encWT, const float* __restrict__ encb,
    float* __restrict__ dst, const int* __restrict__ flagp)
{
  if (*flagp) return;   // fast path active: wst not used (region overlaid)
  __shared__ float s[CC];
  int b = blockIdx.y;
  int h = blockIdx.x * 256 + threadIdx.x;
  if (threadIdx.x < CC) s[threadIdx.x] = src[(size_t)b * src_stride + threadIdx.x];
  __syncthreads();
  float acc = encb[h];
  #pragma unroll
  for (int k = 0; k < CC; ++k) acc = fmaf(s[k], encWT[(size_t)k * HH + h], acc);
  dst[(size_t)b * (10 * HH) + h] = acc;
}

__global__ __launch_bounds__(256) void transpose_encW(
    const float* __restrict__ W, float* __restrict__ WT)
{
  int k = blockIdx.x;
  int h = blockIdx.y * 256 + threadIdx.x;
  WT[(size_t)k * HH + h] = W[(size_t)h * CC + k];
}

__global__ __launch_bounds__(256) void copy_last_kernel(
    const float* __restrict__ x, float* __restrict__ last)
{
  int idx = blockIdx.x * 256 + threadIdx.x;
  if (idx < BB * CC) {
    int b = idx / CC, c = idx - b * CC;
    last[idx] = x[(size_t)b * XROW + 63 * CC + c];
  }
}

__global__ __launch_bounds__(256) void flag_kernel(
    const float* __restrict__ lnA, const float* __restrict__ lnB, int* flagp)
{
  int idx = blockIdx.x * 256 + threadIdx.x;
  bool ok;
  if (idx < LL * HH) ok = (lnA[idx] == 1.0f);
  else ok = (lnB[idx - LL * HH] == 0.0f);
  if (!ok) atomicAnd(flagp, 0);
}

// ---------------------------------------------------------------------------
// Fast-path preps. tabs layout: K3[4356] | K2T[4356] | e1[66] | csE[66] |
// g0[66] | R[66] | be | sum_encb  (8978 floats)
// ---------------------------------------------------------------------------
__global__ __launch_bounds__(256) void prep_tabs(
    const float* __restrict__ encW, const float* __restrict__ encb,
    const float* __restrict__ outW, float* __restrict__ tabs)
{
  int idx = blockIdx.x * 256 + threadIdx.x;
  if (idx >= 8978) return;
  float a = 0.f;
  if (idx < 4356) {
    int c1 = idx / 66, c2 = idx % 66;
    for (int h = 0; h < HH; ++h) a = fmaf(encW[h * CC + c1], encW[h * CC + c2], a);
  } else if (idx < 8712) {
    int p = idx - 4356; int c = p / 66, c1 = p % 66;
    for (int h = 0; h < HH; ++h) a = fmaf(encW[h * CC + c1], outW[(size_t)c * HH + h], a);
  } else if (idx < 8778) {
    int c1 = idx - 8712;
    for (int h = 0; h < HH; ++h) a = fmaf(encW[h * CC + c1], encb[h], a);
  } else if (idx < 8844) {
    int c1 = idx - 8778;
    for (int h = 0; h < HH; ++h) a += encW[h * CC + c1];
  } else if (idx < 8910) {
    int c = idx - 8844;
    for (int h = 0; h < HH; ++h) a = fmaf(encb[h], outW[(size_t)c * HH + h], a);
  } else if (idx < 8976) {
    int c = idx - 8910;
    for (int h = 0; h < HH; ++h) a += outW[(size_t)c * HH + h];
  } else if (idx == 8976) {
    for (int h = 0; h < HH; ++h) a = fmaf(encb[h], encb[h], a);
  } else {
    for (int h = 0; h < HH; ++h) a += encb[h];
  }
  tabs[idx] = a;
}

__global__ __launch_bounds__(256) void prep_b144(
    const float* __restrict__ encW, const float* __restrict__ outW,
    const float* __restrict__ encb, float* __restrict__ B144)
{
  int idx = blockIdx.x * 256 + threadIdx.x;
  if (idx >= 1024 * 144) return;
  int k = idx / 144, n = idx % 144;
  float v;
  if (n < 66) v = encW[k * CC + n];
  else if (n < 132) v = outW[(size_t)(n - 66) * HH + k];
  else if (n == 132) v = encb[k];
  else if (n == 133) v = 1.f;
  else v = 0.f;
  B144[idx] = v;
}

__global__ __launch_bounds__(256) void linit_kernel(
    const float* __restrict__ x, float* __restrict__ l_ring,
    const int* __restrict__ flagp)
{
  if (!*flagp) return;
  int idx = blockIdx.x * 256 + threadIdx.x;
  if (idx >= 1024 * 9 * 66) return;
  int c = idx % 66; int r = idx / 66; int w = r % 9; int b = r / 9;
  l_ring[((size_t)b * 10 + w) * 66 + c] = x[(size_t)b * XROW + (54 + w) * CC + c];
}

// init-only: q = K3 @ frame into ring slot (w = 0..9 covers x54..x63)
__global__ __launch_bounds__(256) void qnew_kernel(
    const float* __restrict__ src, int sstride, const float* __restrict__ K3,
    float* __restrict__ q_ring, int slot, const int* __restrict__ flagp)
{
  if (!*flagp) return;
  __shared__ float Ks[4356];
  __shared__ float ls[8][66];
  int tid = threadIdx.x, b0 = blockIdx.x * 8;
  for (int i = tid; i < 4356; i += 256) Ks[i] = K3[i];
  for (int i = tid; i < 8 * 66; i += 256)
    ls[i / 66][i % 66] = src[(size_t)(b0 + i / 66) * sstride + (i % 66)];
  __syncthreads();
  for (int o = tid; o < 528; o += 256) {
    int bi = o / 66, c1 = o % 66;
    float a = 0.f;
    for (int c2 = 0; c2 < 66; ++c2) a = fmaf(Ks[c1 * 66 + c2], ls[bi][c2], a);
    q_ring[((size_t)(b0 + bi) * 10 + slot) * 66 + c1] = a;
  }
}

__global__ __launch_bounds__(256) void fast_combine(
    const float* __restrict__ dp, float* __restrict__ u, float* __restrict__ G,
    float* __restrict__ e, float* __restrict__ s, const int* __restrict__ flagp)
{
  if (!*flagp) return;
  int o = blockIdx.x * 256 + threadIdx.x;
  if (o >= 1024 * 144) return;
  int b = o / 144, c = o % 144;
  float a = 0.f;
  #pragma unroll
  for (int g = 0; g < DPSEG; ++g) a += dp[((size_t)g * 1024 + b) * 144 + c];
  if (c < 66) u[b * 66 + c] = a;
  else if (c < 132) G[b * 66 + (c - 66)] = a;
  else if (c == 132) e[b] = a;
  else if (c == 133) s[b] = a;
}

// ---------------------------------------------------------------------------
// tail_kernel: fast path = Gram (frame space) + 12-layer affine-LN recursion
// + output + q(new frame) for the next step. Generic path = round-4 mlp.
// ---------------------------------------------------------------------------
__global__ __launch_bounds__(256) void tail_kernel(
    const float* __restrict__ hdec, const float* __restrict__ whp,
    float* __restrict__ last, float* __restrict__ l_ring,
    float* __restrict__ q_ring, const float* __restrict__ dp,
    const float* __restrict__ u_whp, const float* __restrict__ G_whp,
    const float* __restrict__ e_whp, const float* __restrict__ s_whp,
    const float* __restrict__ tabs,
    float* __restrict__ wst, const float* __restrict__ encWT,
    const float* __restrict__ encb,
    const float* __restrict__ seqW, const float* __restrict__ seqb,
    const float* __restrict__ lnA, const float* __restrict__ lnB,
    const float* __restrict__ outW, const float* __restrict__ outb,
    const float* __restrict__ mrgW, const float* __restrict__ mrgb,
    int ring0, float* __restrict__ outp,
    unsigned short* __restrict__ lpH, unsigned short* __restrict__ lpL,
    const int* __restrict__ flagp)
{
  const int b = blockIdx.x, tid = threadIdx.x;
  const int lane = tid & 63, wid = tid >> 6;
  const int slot9 = (ring0 == 0) ? 9 : ring0 - 1;   // == (ring0+9)%10

  if (*flagp) {
    // ================= fast path =================
    __shared__ float l_all[10][66], Qv[10][66];
    __shared__ float yd[66], gd[66], uw[66], se1[66], scs[66], lmix[66], newf[66];
    __shared__ float sW[156], sMm[156], sTt[156], sPp[156], sNn[156], sQq[156];
    __shared__ float sb12[12], sistd[12], scc[12], sfb[12], sdd12[12], swd[12], sVv[12], smrg[12];
    __shared__ float sred[12], misc[8];

    const float* K2T   = tabs + 4356;
    const float* tb_e1 = tabs + 8712;
    const float* tb_cs = tabs + 8778;
    const float* tb_g0 = tabs + 8844;
    const float* tb_R  = tabs + 8910;

    // ---- phase 0: staging + reductions ----
    for (int i = tid; i < 660; i += 256) {
      int w = i / 66, c = i % 66;
      int slot = ring0 + w; if (slot >= 10) slot -= 10;
      Qv[w][c] = q_ring[((size_t)b * 10 + slot) * 66 + c];
      if (w < 9) l_all[w][c] = l_ring[((size_t)b * 10 + slot) * 66 + c];
      else       l_all[9][c] = last[(size_t)b * 66 + c];
    }
    for (int i = tid; i < 66; i += 256) {
      uw[i]  = u_whp[(size_t)b * 66 + i];
      se1[i] = tb_e1[i];
      scs[i] = tb_cs[i];
    }
    if (tid < 134) {
      float a = 0.f;
      #pragma unroll
      for (int g = 0; g < DPSEG; ++g) a += dp[((size_t)g * 1024 + b) * 144 + tid];
      if (tid < 66) yd[tid] = a;
      else if (tid < 132) gd[tid - 66] = a;
      else if (tid == 132) misc[1] = a;   // <hdec, encb>
      else misc[2] = a;                   // sum_h hdec
    }
    if (tid >= 160 && tid < 172) smrg[tid - 160] = mrgW[tid - 160];
    {
      f32x4 hv = *(const f32x4*)&hdec[(size_t)b * 1024 + tid * 4];
      f32x4 wv = *(const f32x4*)&whp[(size_t)b * 1024 + tid * 4];
      float d2 = hv[0]*hv[0] + hv[1]*hv[1] + hv[2]*hv[2] + hv[3]*hv[3];
      float dw = hv[0]*wv[0] + hv[1]*wv[1] + hv[2]*wv[2] + hv[3]*wv[3];
      float w2 = wv[0]*wv[0] + wv[1]*wv[1] + wv[2]*wv[2] + wv[3]*wv[3];
      d2 = wave_sum63(d2); dw = wave_sum63(dw); w2 = wave_sum63(w2);
      if (lane == 63) { sred[wid*3] = d2; sred[wid*3+1] = dw; sred[wid*3+2] = w2; }
    }
    __syncthreads();
    if (tid >= 128 && tid < 131) {
      int i = tid - 128;
      misc[3 + i] = sred[i] + sred[3 + i] + sred[6 + i] + sred[9 + i];
    }
    if (tid == 132) misc[6] = tabs[8976];   // be
    if (tid == 133) misc[7] = tabs[8977];   // sum_encb
    __syncthreads();

    // ---- phase 1: Gram + fbar + init ----
    if (tid < 144) {
      int i = tid / 12, j = tid % 12;
      float gv;
      if (i == 0 && j == 0) gv = misc[5];
      else if (i == 11 && j == 11) gv = misc[3];
      else if ((i == 0 && j == 11) || (i == 11 && j == 0)) gv = misc[4];
      else if (i == 0 || j == 0) {
        int w = (i == 0 ? j : i) - 1;
        float a = e_whp[b];
        for (int c = 0; c < 66; ++c) a = fmaf(uw[c], l_all[w][c], a);
        gv = a;
      } else if (i == 11 || j == 11) {
        int w = (i == 11 ? j : i) - 1;
        float a = misc[1];
        for (int c = 0; c < 66; ++c) a = fmaf(yd[c], l_all[w][c], a);
        gv = a;
      } else {
        int wi = i - 1, wj = j - 1;
        float a = misc[6];
        for (int c = 0; c < 66; ++c) a = fmaf(se1[c], l_all[wi][c] + l_all[wj][c], a);
        for (int c = 0; c < 66; ++c) a = fmaf(l_all[wi][c], Qv[wj][c], a);
        gv = a;
      }
      sMm[i * 13 + j] = gv * (1.f / 1024.f);
      sTt[i * 13 + j] = (i == j) ? 1.f : 0.f;
    }
    if (tid >= 144 && tid < 156) {
      int k = tid - 144;
      float fb;
      if (k == 0) fb = s_whp[b] * (1.f / 1024.f);
      else if (k == 11) fb = misc[2] * (1.f / 1024.f);
      else {
        float a = misc[7];
        for (int c = 0; c < 66; ++c) a = fmaf(scs[c], l_all[k - 1][c], a);
        fb = a * (1.f / 1024.f);
      }
      sfb[k] = fb;
      sdd12[k] = 0.f;
    }
    __syncthreads();

    // ---- phase 2: 12-layer recursion ----
    for (int l = 0; l < LL; ++l) {
      if (tid < 144) sW[(tid / 12) * 13 + (tid % 12)] = seqW[l * 144 + tid];
      if (tid >= 160 && tid < 172) sb12[tid - 160] = seqb[l * 12 + (tid - 160)];
      __syncthreads();
      if (tid < 144) {
        int s = tid / 12, k = tid % 12;
        float a = 0.f;
        #pragma unroll
        for (int k2 = 0; k2 < 12; ++k2) a = fmaf(sW[s * 13 + k2], sMm[k2 * 13 + k], a);
        sPp[s * 13 + k] = a;
      }
      __syncthreads();
      if (tid < 12) {
        int s = tid;
        float mu = sb12[s];
        #pragma unroll
        for (int k = 0; k < 12; ++k) mu = fmaf(sW[s * 13 + k], sfb[k], mu);
        float e2 = 0.f;
        #pragma unroll
        for (int k = 0; k < 12; ++k) e2 = fmaf(sPp[s * 13 + k], sW[s * 13 + k], e2);
        float wf = mu - sb12[s];
        float var = fmaxf(e2 - wf * wf, 0.f);
        float is = 1.f / sqrtf(var + 1e-5f);
        sistd[s] = is;
        scc[s] = is * (sb12[s] - mu);
      }
      __syncthreads();
      if (tid < 144) {
        int i = tid / 12, j = tid % 12;
        float a = 0.f;
        #pragma unroll
        for (int k = 0; k < 12; ++k) a = fmaf(sW[i * 13 + k], sTt[k * 13 + j], a);
        sQq[i * 13 + j] = a;
        sNn[i * 13 + j] = sMm[i * 13 + j] + sistd[i] * sPp[i * 13 + j];
      }
      if (tid >= 144 && tid < 156) {
        int i = tid - 144;
        float a = 0.f;
        #pragma unroll
        for (int k = 0; k < 12; ++k) a = fmaf(sW[i * 13 + k], sdd12[k], a);
        swd[i] = a;
      }
      __syncthreads();
      if (tid < 144) {
        int i = tid / 12, j = tid % 12;
        sTt[i * 13 + j] += sistd[i] * sQq[i * 13 + j];
        float a = 0.f;
        #pragma unroll
        for (int k = 0; k < 12; ++k) a = fmaf(sNn[i * 13 + k], sW[j * 13 + k], a);
        sPp[i * 13 + j] = a;
      }
      if (tid >= 144 && tid < 156) {
        int i = tid - 144;
        sdd12[i] = sdd12[i] + sistd[i] * swd[i] + scc[i];
      }
      __syncthreads();
      if (tid < 144) {
        int i = tid / 12, j = tid % 12;
        sMm[i * 13 + j] = sNn[i * 13 + j] + sPp[i * 13 + j] * sistd[j]
                        + sfb[i] * scc[j] + scc[i] * sfb[j] - scc[i] * scc[j];
      }
      __syncthreads();
    }

    // ---- phase 3: output + q(new frame) ----
    if (tid < 12) {
      float a = 0.f;
      #pragma unroll
      for (int s = 0; s < 12; ++s) a = fmaf(smrg[s], sTt[s * 13 + tid], a);
      sVv[tid] = a;
    }
    if (tid == 200) {
      float a = 0.f;
      for (int s = 0; s < 12; ++s) a = fmaf(smrg[s], sdd12[s], a);
      misc[0] = a;
    }
    __syncthreads();
    if (tid < 66) {
      float a = 0.f;
      #pragma unroll
      for (int w = 0; w < 9; ++w) a = fmaf(sVv[1 + w], l_all[w][tid], a);
      a = fmaf(sVv[10], l_all[9][tid], a);
      lmix[tid] = a;
    }
    __syncthreads();
    if (tid < 66) {
      int c = tid;
      float vsr = 0.f, smw = 0.f;
      #pragma unroll
      for (int k = 1; k <= 10; ++k) vsr += sVv[k];
      #pragma unroll
      for (int s = 0; s < 12; ++s) smw += smrg[s];
      float lastv = l_all[9][c];
      float acc = sVv[0] * G_whp[(size_t)b * 66 + c]
                + vsr * tb_g0[c]
                + sVv[11] * gd[c]
                + misc[0] * tb_R[c]
                + smw * outb[c] + mrgb[0] + lastv;
      const float* krow = K2T + c * 66;
      for (int c2 = 0; c2 < 66; ++c2) acc = fmaf(lmix[c2], krow[c2], acc);
      outp[(size_t)b * XROW + c] = acc;
      last[(size_t)b * 66 + c] = acc;
      l_ring[((size_t)b * 10 + slot9) * 66 + c] = lastv;
      newf[c] = acc;
      unsigned short hi = f2bf(acc);
      float lo = acc - bf2f(hi);
      int cb = (((c >> 3) & 3) ^ (b & 3)) & 3;
      size_t dst = (size_t)b * 96 + (size_t)(c & ~31) + cb * 8 + (c & 7);
      lpH[dst] = hi;
      lpL[dst] = f2bf(lo);
    }
    __syncthreads();
    if (tid < 66) {
      // q(new frame) for the next step, ring slot = ring0
      float a = 0.f;
      const float* k3r = tabs + tid * 66;
      for (int c2 = 0; c2 < 66; ++c2) a = fmaf(k3r[c2], newf[c2], a);
      q_ring[((size_t)b * 10 + ring0) * 66 + tid] = a;
    }
    return;
  }

  // ================= generic fallback (round-4 mlp, exact) =================
  __shared__ float red[4][24];
  __shared__ f2 mustd2[SS];
  __shared__ float g_lds[HH];
  __shared__ float nc[CC];

  const int h0 = tid;
  const int h1 = tid + 512;
  const float* lrow = last + (size_t)b * CC;
  f2 wnew[2];
  {
    f2 a0 = { encb[h0], encb[h0 + 256] };
    f2 a1 = { encb[h1], encb[h1 + 256] };
    #pragma unroll 11
    for (int k = 0; k < CC; ++k) {
      float lv = lrow[k];
      f2 lv2 = { lv, lv };
      f2 w0 = { encWT[(size_t)k * HH + h0], encWT[(size_t)k * HH + h0 + 256] };
      f2 w1 = { encWT[(size_t)k * HH + h1], encWT[(size_t)k * HH + h1 + 256] };
      a0 = __builtin_elementwise_fma(lv2, w0, a0);
      a1 = __builtin_elementwise_fma(lv2, w1, a1);
    }
    wnew[0] = a0; wnew[1] = a1;
    float* wd = wst + ((size_t)b * 10 + slot9) * HH;
    wd[h0] = a0.x; wd[h0 + 256] = a0.y;
    wd[h1] = a1.x; wd[h1 + 256] = a1.y;
  }

  f2 fr[2][SS];
  {
    const float* whb = whp + (size_t)b * HH;
    const float* hb  = hdec + (size_t)b * HH;
    fr[0][0]  = { whb[h0], whb[h0 + 256] };
    fr[1][0]  = { whb[h1], whb[h1 + 256] };
    fr[0][11] = { hb[h0], hb[h0 + 256] };
    fr[1][11] = { hb[h1], hb[h1 + 256] };
    #pragma unroll
    for (int w = 0; w < 9; ++w) {
      int slot = ring0 + w; if (slot >= 10) slot -= 10;
      const float* ws_ = wst + ((size_t)b * 10 + slot) * HH;
      fr[0][1 + w] = { ws_[h0], ws_[h0 + 256] };
      fr[1][1 + w] = { ws_[h1], ws_[h1 + 256] };
    }
    fr[0][10] = wnew[0];
    fr[1][10] = wnew[1];
  }

  #pragma unroll 1
  for (int l = 0; l < LL; ++l) {
    const float* W  = seqW + (size_t)l * SS * SS;
    const float* Bv = seqb + (size_t)l * SS;
    const float* lA = lnA + (size_t)l * HH;
    const float* lB = lnB + (size_t)l * HH;
    f2 al[2], be[2];
    al[0] = { lA[h0], lA[h0 + 256] };  al[1] = { lA[h1], lA[h1 + 256] };
    be[0] = { lB[h0], lB[h0 + 256] };  be[1] = { lB[h1], lB[h1 + 256] };

    f2 y[2][SS];
    #pragma unroll
    for (int s = 0; s < SS; ++s) {
      float bv = Bv[s];
      f2 a0 = { bv, bv }, a1 = { bv, bv };
      #pragma unroll
      for (int k = 0; k < SS; ++k) {
        float wv = W[s * SS + k];
        f2 wv2 = { wv, wv };
        a0 = __builtin_elementwise_fma(fr[0][k], wv2, a0);
        a1 = __builtin_elementwise_fma(fr[1][k], wv2, a1);
      }
      y[0][s] = a0; y[1][s] = a1;
      f2 pp = a0 + a1;
      float ps = wave_sum63(pp.x + pp.y);
      f2 qq = __builtin_elementwise_fma(a0, a0, a1 * a1);
      float pq = wave_sum63(qq.x + qq.y);
      if (lane == 63) { red[wid][s] = ps; red[wid][12 + s] = pq; }
    }
    __syncthreads();
    if (tid < SS) {
      float S = red[0][tid] + red[1][tid] + red[2][tid] + red[3][tid];
      float Q = red[0][12 + tid] + red[1][12 + tid] + red[2][12 + tid] + red[3][12 + tid];
      float mu = S * (1.f / HH);
      float var = Q * (1.f / HH) - mu * mu;
      mustd2[tid] = { mu, 1.f / sqrtf(var + 1e-5f) };
    }
    __syncthreads();
    #pragma unroll
    for (int s = 0; s < SS; ++s) {
      f2 mi = mustd2[s];
      f2 mus = { mi.x, mi.x };
      f2 isd = { mi.y, mi.y };
      #pragma unroll
      for (int p = 0; p < 2; ++p) {
        f2 t = (y[p][s] - mus) * isd;
        fr[p][s] = __builtin_elementwise_fma(t, al[p], fr[p][s]) + be[p];
      }
    }
    __syncthreads();
  }

  float smw = 0.f;
  f2 g[2] = { {0.f, 0.f}, {0.f, 0.f} };
  #pragma unroll
  for (int s = 0; s < SS; ++s) {
    float mv = mrgW[s];
    smw += mv;
    f2 mv2 = { mv, mv };
    g[0] = __builtin_elementwise_fma(mv2, fr[0][s], g[0]);
    g[1] = __builtin_elementwise_fma(mv2, fr[1][s], g[1]);
  }
  g_lds[h0] = g[0].x; g_lds[h0 + 256] = g[0].y;
  g_lds[h1] = g[1].x; g_lds[h1 + 256] = g[1].y;
  const float mbv = mrgb[0];
  __syncthreads();
  #pragma unroll 1
  for (int i = 0; i < 17; ++i) {
    int c = wid + 4 * i;
    if (c < CC) {
      const float* ow = outW + (size_t)c * HH;
      float acc = 0.f;
      #pragma unroll
      for (int q = 0; q < 16; ++q) acc = fmaf(g_lds[lane + q * 64], ow[lane + q * 64], acc);
      acc = wave_sum63(acc);
      if (lane == 63) nc[c] = acc + outb[c] * smw + mbv + lrow[c];
    }
  }
  __syncthreads();
  if (tid < CC) {
    float nv = nc[tid];
    outp[(size_t)b * XROW + tid] = nv;
    last[(size_t)b * CC + tid] = nv;
    unsigned short hi = f2bf(nv);
    float lo = nv - bf2f(hi);
    int cb = (((tid >> 3) & 3) ^ (b & 3)) & 3;
    size_t dst = (size_t)b * 96 + (size_t)(tid & ~31) + cb * 8 + (tid & 7);
    lpH[dst] = hi;
    lpL[dst] = f2bf(lo);
  }
}

// ---------------------------------------------------------------------------
extern "C" void kernel_launch(void* const* d_in, const int* in_sizes, int n_in,
                              void* d_out, int out_size, void* d_ws, size_t ws_size,
                              hipStream_t stream) {
  const float* x    = (const float*)d_in[0];
  const float* gWi  = (const float*)d_in[1];
  const float* gWh  = (const float*)d_in[2];
  const float* gbi  = (const float*)d_in[3];
  const float* gbh  = (const float*)d_in[4];
  const float* encW = (const float*)d_in[5];
  const float* encb = (const float*)d_in[6];
  const float* seqW = (const float*)d_in[7];
  const float* seqb = (const float*)d_in[8];
  const float* lnA  = (const float*)d_in[9];
  const float* lnB  = (const float*)d_in[10];
  const float* outW = (const float*)d_in[11];
  const float* outb = (const float*)d_in[12];
  const float* mrgW = (const float*)d_in[13];
  const float* mrgb = (const float*)d_in[14];
  float* out = (float*)d_out;

  char* p = (char*)d_ws;
  auto alloc = [&](size_t bytes) { char* r = p; p += (bytes + 255) & ~(size_t)255; return r; };
  float* encWT = (float*)alloc((size_t)CC * HH * 4);
  float* last  = (float*)alloc((size_t)BB * CC * 4);
  float* wst   = (float*)alloc((size_t)BB * 10 * HH * 4);   // generic ring / fast overlay
  float* hf[3];
  for (int i = 0; i < 3; ++i) hf[i] = (float*)alloc((size_t)BB * HH * 4);
  unsigned short* WgH = (unsigned short*)alloc((size_t)4096 * 1120 * 2);
  unsigned short* WgL = (unsigned short*)alloc((size_t)4096 * 1120 * 2);
  unsigned short* XaH = (unsigned short*)alloc((size_t)TT * BB * 96 * 2);
  unsigned short* XaL = (unsigned short*)alloc((size_t)TT * BB * 96 * 2);
  unsigned short* hhi[3]; unsigned short* hlo[3];
  for (int i = 0; i < 3; ++i) {
    hhi[i] = (unsigned short*)alloc((size_t)BB * HH * 2);
    hlo[i] = (unsigned short*)alloc((size_t)BB * HH * 2);
  }
  unsigned short* lpH = (unsigned short*)alloc((size_t)BB * 96 * 2);
  unsigned short* lpL = (unsigned short*)alloc((size_t)BB * 96 * 2);
  int* flag = (int*)alloc(256);
  if ((size_t)(p - (char*)d_ws) > ws_size) return;  // insufficient workspace

  // fast-path overlay inside the wst region (mutually exclusive by flag)
  char* ov = (char*)wst;
  float* B144  = (float*)ov;                 ov += (size_t)1024 * 144 * 4;
  float* dp32  = (float*)ov;                 ov += (size_t)DPSEG * 1024 * 144 * 4;  // 18.9 MB
  float* l_ring= (float*)ov;                 ov += (size_t)1024 * 10 * 66 * 4;
  float* q_ring= (float*)ov;                 ov += (size_t)1024 * 10 * 66 * 4;
  float* u_whp = (float*)ov;                 ov += (size_t)1024 * 66 * 4;
  float* G_whp = (float*)ov;                 ov += (size_t)1024 * 66 * 4;
  float* e_whp = (float*)ov;                 ov += 4096;
  float* s_whp = (float*)ov;                 ov += 4096;
  float* tabs  = (float*)ov;                 ov += 9216 * 4;

  // ---- one-time prep ----
  hipMemsetAsync(flag, 0xFF, 4, stream);
  flag_kernel<<<dim3(96), 256, 0, stream>>>(lnA, lnB, flag);
  prep_wgc<<<dim3((4096u * 1120u) / 256u), 256, 0, stream>>>(gWh, gWi, WgH, WgL);
  prep_xall<<<dim3(((unsigned)TT * BB * 96) / 256u), 256, 0, stream>>>(x, XaH, XaL);
  transpose_encW<<<dim3(CC, HH/256), 256, 0, stream>>>(encW, encWT);
  copy_last_kernel<<<dim3((BB*CC + 255)/256), 256, 0, stream>>>(x, last);
  prep_b144<<<dim3(576), 256, 0, stream>>>(encW, outW, encb, B144);
  prep_tabs<<<dim3(36), 256, 0, stream>>>(encW, encb, outW, tabs);
  linit_kernel<<<dim3((1024*9*66)/256), 256, 0, stream>>>(x, l_ring, flag);
  for (int w = 0; w < 10; ++w)   // slots 0..9 = q(x[54..63])
    qnew_kernel<<<dim3(128), 256, 0, stream>>>(x + (size_t)(54 + w) * CC, XROW,
                                               tabs, q_ring, w, flag);
  hipMemsetAsync(hf[0], 0, (size_t)BB * HH * 4, stream);
  hipMemsetAsync(hhi[0], 0, (size_t)BB * HH * 2, stream);
  hipMemsetAsync(hlo[0], 0, (size_t)BB * HH * 2, stream);

  const dim3 ggrid(512);

  // ---- encoder: 63 GRU steps (no dp) ----
  int cur = 0;
  for (int t = 0; t < 63; ++t) {
    int nxt = 1 - cur;
    gru_mfma<<<ggrid, 256, 0, stream>>>(
        hhi[cur], hlo[cur], hf[cur],
        XaH + (size_t)t * BB * 96, XaL + (size_t)t * BB * 96,
        WgH, WgL, gbi, gbh, hf[nxt], hhi[nxt], hlo[nxt],
        B144, dp32, flag, 0);
    cur = nxt;
  }
  // window_history GRU -> hf[2], with fused dp (whp's dp feeds fast_combine + t=0 tail)
  gru_mfma<<<ggrid, 256, 0, stream>>>(
      hhi[cur], hlo[cur], hf[cur],
      XaH + (size_t)63 * BB * 96, XaL + (size_t)63 * BB * 96,
      WgH, WgL, gbi, gbh, hf[2], hhi[2], hlo[2],
      B144, dp32, flag, 1);

  // whp-derived persistent fast-path arrays
  fast_combine<<<dim3(576), 256, 0, stream>>>(dp32, u_whp, G_whp, e_whp, s_whp, flag);

  // generic-path wst init (skipped when fast)
  for (int w = 0; w < 9; ++w)
    wst_row_kernel<<<dim3(HH/256, BB), 256, 0, stream>>>(
        x + (size_t)(54 + w) * CC, XROW, encWT, encb, wst + (size_t)w * HH, flag);

  // ---- decoder: 64 steps, 2 launches each ----
  int hc = 2;
  for (int t = 0; t < 64; ++t) {
    if (t > 0) {
      int hn = (t - 1) & 1;
      gru_mfma<<<ggrid, 256, 0, stream>>>(
          hhi[hc], hlo[hc], hf[hc], lpH, lpL,
          WgH, WgL, gbi, gbh, hf[hn], hhi[hn], hlo[hn],
          B144, dp32, flag, 1);
      hc = hn;
    }
    tail_kernel<<<dim3(BB), 256, 0, stream>>>(
        hf[hc], hf[2], last, l_ring, q_ring, dp32,
        u_whp, G_whp, e_whp, s_whp, tabs,
        wst, encWT, encb, seqW, seqb, lnA, lnB, outW, outb, mrgW, mrgb,
        t % 10, out + (size_t)t * CC, lpH, lpL, flag);
  }
}

// Round 8
// 7952.826 us; speedup vs baseline: 1.9023x; 1.0055x over previous
//
#include <hip/hip_runtime.h>
#include <hip/hip_bf16.h>
#include <cstddef>
#include <cstdint>

#define BB 1024
#define TT 64
#define CC 66
#define HH 1024
#define SS 12
#define LL 12
#define XROW (TT*CC)   // 4224 floats per batch row of x
#define DPSEG 32       // dp segments (one per jb)

typedef __attribute__((ext_vector_type(8))) __bf16 bfrag;
typedef __attribute__((ext_vector_type(4))) float f32x4;
typedef __attribute__((ext_vector_type(8))) short s8v;
typedef __attribute__((ext_vector_type(2))) float f2;

// Bank swizzle for 16B units within a 32-short row chunk, baked into global
// layouts. SW(row) spreads ds_read_b128 slots: s=(4r+cb)%8 hits all 8 slots
// exactly 2x (hardware floor). Old (r&3) bake was 4-way on half the slots.
#define SWROW(r) (((r) >> 1) & 3)

__device__ __forceinline__ unsigned short f2bf(float f) {
  unsigned int u = __builtin_bit_cast(unsigned int, f);
  unsigned int r = u + 0x7FFFu + ((u >> 16) & 1u);
  return (unsigned short)(r >> 16);
}
__device__ __forceinline__ float bf2f(unsigned short h) {
  unsigned int u = ((unsigned int)h) << 16;
  return __builtin_bit_cast(float, u);
}

__device__ __forceinline__ void gload16(const void* g, void* l) {
  __builtin_amdgcn_global_load_lds(
      (const __attribute__((address_space(1))) unsigned int*)g,
      (__attribute__((address_space(3))) unsigned int*)l, 16, 0, 0);
}

// DPP-based wave64 sum: result lands in lane 63. VALU-only (no LDS pipe).
template<int CTRL, int RM>
__device__ __forceinline__ float dppadd(float v) {
  int x = __builtin_amdgcn_update_dpp(0, __builtin_bit_cast(int, v),
                                      CTRL, RM, 0xF, true);
  return v + __builtin_bit_cast(float, x);
}
__device__ __forceinline__ float wave_sum63(float v) {
  v = dppadd<0x111, 0xF>(v);   // row_shr:1
  v = dppadd<0x112, 0xF>(v);   // row_shr:2
  v = dppadd<0x114, 0xF>(v);   // row_shr:4
  v = dppadd<0x118, 0xF>(v);   // row_shr:8
  v = dppadd<0x142, 0xa>(v);   // row_bcast:15
  v = dppadd<0x143, 0xc>(v);   // row_bcast:31 -> lane 63 = full sum
  return v;
}

// ---------------------------------------------------------------------------
// Split-bf16 MFMA GRU step, v5: 3-buffer counted-vmcnt pipeline + fused dp
// partial GEMM, with the conflict-free SWROW bank swizzle baked everywhere.
// ---------------------------------------------------------------------------
__global__ __launch_bounds__(256) void gru_mfma(
    const unsigned short* __restrict__ Ahi, const unsigned short* __restrict__ Alo,
    const float* __restrict__ hprev,
    const unsigned short* __restrict__ Xhi, const unsigned short* __restrict__ Xlo,
    const unsigned short* __restrict__ Whi, const unsigned short* __restrict__ Wlo,
    const float* __restrict__ bi, const float* __restrict__ bh,
    float* __restrict__ hout_f32,
    unsigned short* __restrict__ hout_hi, unsigned short* __restrict__ hout_lo,
    const float* __restrict__ B144, float* __restrict__ dp32,
    const int* __restrict__ flagp, int do_dp)
{
  __shared__ __align__(16) unsigned short AsH[3][64*32];
  __shared__ __align__(16) unsigned short AsL[3][64*32];
  __shared__ __align__(16) unsigned short BsH[3][128*32];
  __shared__ __align__(16) unsigned short BsL[3][128*32];

  const int tid = threadIdx.x, lane = tid & 63, wid = tid >> 6;
  const int bid = blockIdx.x;
  const int idx = bid >> 3;
  const int jb = (bid & 7) * 4 + (idx & 3);
  const int b0 = (idx >> 2) * 64;
  const int wm = wid >> 1, wn = wid & 1;
  const int aR = lane >> 2, aC = lane & 3;

  auto stage = [&](int bs, int kc) {
    const unsigned short *shi, *slo; size_t go;
    int row = wid * 16 + aR;
    if (kc < 32) {
      go = (size_t)(b0 + row) * 1024 + (size_t)kc * 32 + aC * 8;
      shi = Ahi; slo = Alo;
    } else {
      go = (size_t)(b0 + row) * 96 + (size_t)(kc - 32) * 32 + aC * 8;
      shi = Xhi; slo = Xlo;
    }
    gload16(shi + go, &AsH[bs][wid * 512]);
    gload16(slo + go, &AsL[bs][wid * 512]);
    size_t base = ((size_t)jb * 35 + kc) * 4096;
    size_t go0 = base + (size_t)(wid * 32 + aR) * 32 + aC * 8;
    gload16(Whi + go0,       &BsH[bs][wid * 1024]);
    gload16(Whi + go0 + 512, &BsH[bs][wid * 1024 + 512]);
    gload16(Wlo + go0,       &BsL[bs][wid * 1024]);
    gload16(Wlo + go0 + 512, &BsL[bs][wid * 1024 + 512]);
  };

  int offA[2], offB[4];
  #pragma unroll
  for (int mh = 0; mh < 2; ++mh) {
    int r = wm * 32 + mh * 16 + (lane & 15);
    int cb = (lane >> 4) ^ SWROW(r);
    offA[mh] = r * 32 + cb * 8;
  }
  #pragma unroll
  for (int g = 0; g < 4; ++g) {
    int r = wn * 64 + g * 16 + (lane & 15);
    int cb = (lane >> 4) ^ SWROW(r);
    offB[g] = r * 32 + cb * 8;
  }

  f32x4 acc[2][4] = {};

  stage(0, 0);
  stage(1, 1);

  int cur = 0;
  for (int kc = 0; kc < 34; ++kc) {
    asm volatile("s_waitcnt vmcnt(6)" ::: "memory");
    __builtin_amdgcn_s_barrier();
    asm volatile("" ::: "memory");

    bfrag ah[2], al[2], bhf[4], blf[4];
    #pragma unroll
    for (int mh = 0; mh < 2; ++mh) {
      ah[mh] = __builtin_bit_cast(bfrag, *(const s8v*)(&AsH[cur][offA[mh]]));
      al[mh] = __builtin_bit_cast(bfrag, *(const s8v*)(&AsL[cur][offA[mh]]));
    }
    #pragma unroll
    for (int g = 0; g < 4; ++g) {
      bhf[g] = __builtin_bit_cast(bfrag, *(const s8v*)(&BsH[cur][offB[g]]));
      blf[g] = __builtin_bit_cast(bfrag, *(const s8v*)(&BsL[cur][offB[g]]));
    }
    if (kc < 33) {
      int st = (cur >= 1) ? cur - 1 : 2;   // (cur+2)%3
      stage(st, kc + 2);
    }
    #pragma unroll
    for (int mh = 0; mh < 2; ++mh)
      #pragma unroll
      for (int g = 0; g < 4; ++g) {
        acc[mh][g] = __builtin_amdgcn_mfma_f32_16x16x32_bf16(ah[mh], bhf[g], acc[mh][g], 0, 0, 0);
        acc[mh][g] = __builtin_amdgcn_mfma_f32_16x16x32_bf16(ah[mh], blf[g], acc[mh][g], 0, 0, 0);
        acc[mh][g] = __builtin_amdgcn_mfma_f32_16x16x32_bf16(al[mh], bhf[g], acc[mh][g], 0, 0, 0);
      }
    cur = (cur < 2) ? cur + 1 : 0;
  }
  // peeled kc = 34 (cur == 1)
  {
    asm volatile("s_waitcnt vmcnt(0)" ::: "memory");
    __builtin_amdgcn_s_barrier();
    asm volatile("" ::: "memory");
    bfrag ah[2], al[2], bhf[4], blf[4];
    #pragma unroll
    for (int mh = 0; mh < 2; ++mh) {
      ah[mh] = __builtin_bit_cast(bfrag, *(const s8v*)(&AsH[1][offA[mh]]));
      al[mh] = __builtin_bit_cast(bfrag, *(const s8v*)(&AsL[1][offA[mh]]));
    }
    #pragma unroll
    for (int g = 0; g < 4; ++g) {
      bhf[g] = __builtin_bit_cast(bfrag, *(const s8v*)(&BsH[1][offB[g]]));
      blf[g] = __builtin_bit_cast(bfrag, *(const s8v*)(&BsL[1][offB[g]]));
    }
    #pragma unroll
    for (int mh = 0; mh < 2; ++mh)
      #pragma unroll
      for (int g = 0; g < 4; ++g) {
        acc[mh][g] = __builtin_amdgcn_mfma_f32_16x16x32_bf16(ah[mh], bhf[g], acc[mh][g], 0, 0, 0);
        acc[mh][g] = __builtin_amdgcn_mfma_f32_16x16x32_bf16(ah[mh], blf[g], acc[mh][g], 0, 0, 0);
        acc[mh][g] = __builtin_amdgcn_mfma_f32_16x16x32_bf16(al[mh], bhf[g], acc[mh][g], 0, 0, 0);
      }
  }

  // ---- gates epilogue (register-local); keep h values for fused dp ----
  const int j = jb * 32 + wn * 16 + (lane & 15);
  const float b_r  = bi[j] + bh[j];
  const float b_z  = bi[HH + j] + bh[HH + j];
  const float b_nh = bh[2 * HH + j];
  const float b_nx = bi[2 * HH + j];
  float hvv[2][4];
  #pragma unroll
  for (int mh = 0; mh < 2; ++mh)
    #pragma unroll
    for (int q = 0; q < 4; ++q) {
      int m = b0 + wm * 32 + mh * 16 + (lane >> 4) * 4 + q;
      float hpv = hprev[(size_t)m * HH + j];
      float rr = acc[mh][0][q] + b_r;
      float zz = acc[mh][1][q] + b_z;
      float nh = acc[mh][2][q] + b_nh;
      float nx = acc[mh][3][q] + b_nx;
      float r = 1.f / (1.f + __expf(-rr));
      float z = 1.f / (1.f + __expf(-zz));
      float n = tanhf(nx + r * nh);
      float hv = (1.f - z) * n + z * hpv;
      hvv[mh][q] = hv;
      hout_f32[(size_t)m * HH + j] = hv;
      unsigned short hi = f2bf(hv);
      float lo = hv - bf2f(hi);
      int cb = ((j >> 3) & 3) ^ SWROW(m);
      size_t dst = (size_t)m * 1024 + (size_t)(j & ~31) + cb * 8 + (j & 7);
      hout_hi[dst] = hi;
      hout_lo[dst] = f2bf(lo);
    }

  // ---- fused dp partial: dp32[jb][b][144] = h_tile(64x32) @ B144-rows ----
  if (do_dp && *flagp) {
    float* hsf = reinterpret_cast<float*>(&AsH[0][0]);   // 64x33 floats (8448B)
    __syncthreads();   // all LDS frag reads done -> safe to overwrite staging
    #pragma unroll
    for (int mh = 0; mh < 2; ++mh)
      #pragma unroll
      for (int q = 0; q < 4; ++q) {
        int mloc = wm * 32 + mh * 16 + (lane >> 4) * 4 + q;
        int jloc = wn * 16 + (lane & 15);
        hsf[mloc * 33 + jloc] = hvv[mh][q];
      }
    __syncthreads();
    const int b_sub = tid & 63;
    const int cg = __builtin_amdgcn_readfirstlane(tid >> 6);
    const int base_c = cg * 36;
    float acc36[36];
    #pragma unroll
    for (int i = 0; i < 36; ++i) acc36[i] = 0.f;
    for (int kk = 0; kk < 32; ++kk) {
      float av = hsf[b_sub * 33 + kk];
      const float* brow = B144 + (size_t)(jb * 32 + kk) * 144 + base_c;  // uniform
      #pragma unroll
      for (int qq = 0; qq < 9; ++qq) {
        f32x4 b4 = *(const f32x4*)(brow + qq * 4);
        acc36[qq*4+0] = fmaf(av, b4[0], acc36[qq*4+0]);
        acc36[qq*4+1] = fmaf(av, b4[1], acc36[qq*4+1]);
        acc36[qq*4+2] = fmaf(av, b4[2], acc36[qq*4+2]);
        acc36[qq*4+3] = fmaf(av, b4[3], acc36[qq*4+3]);
      }
    }
    float* drow = dp32 + ((size_t)jb * 1024 + b0 + b_sub) * 144 + base_c;
    #pragma unroll
    for (int qq = 0; qq < 9; ++qq)
      *(f32x4*)(drow + qq * 4) = { acc36[qq*4+0], acc36[qq*4+1], acc36[qq*4+2], acc36[qq*4+3] };
  }
}

// ---------------------------------------------------------------------------
// Prep kernels.
// ---------------------------------------------------------------------------
__global__ __launch_bounds__(256) void prep_wgc(
    const float* __restrict__ Wh, const float* __restrict__ Wi,
    unsigned short* __restrict__ Whi, unsigned short* __restrict__ Wlo)
{
  size_t idx = (size_t)blockIdx.x * 256 + threadIdx.x;
  if (idx >= (size_t)4096 * 1120) return;
  int k = (int)(idx % 1120);
  int rg = (int)(idx / 1120);
  int jbv = rg >> 7, r = rg & 127;
  int jhi = r >> 6, rem = r & 63, g = rem >> 4, jlo = rem & 15;
  int j = jbv * 32 + jhi * 16 + jlo;
  float v = 0.f;
  if (g == 0)      v = (k < 1024) ? Wh[(size_t)j * HH + k]            : ((k < 1090) ? Wi[(size_t)j * CC + (k - 1024)] : 0.f);
  else if (g == 1) v = (k < 1024) ? Wh[(size_t)(HH + j) * HH + k]     : ((k < 1090) ? Wi[(size_t)(HH + j) * CC + (k - 1024)] : 0.f);
  else if (g == 2) v = (k < 1024) ? Wh[(size_t)(2 * HH + j) * HH + k] : 0.f;
  else             v = (k >= 1024 && k < 1090) ? Wi[(size_t)(2 * HH + j) * CC + (k - 1024)] : 0.f;
  unsigned short hi = f2bf(v);
  float lo = v - bf2f(hi);
  int kc = k >> 5, kk = k & 31;
  int cb = ((kk >> 3) ^ SWROW(r)) & 3;
  size_t dst = (((size_t)jbv * 35 + kc) * 128 + r) * 32 + cb * 8 + (kk & 7);
  Whi[dst] = hi;
  Wlo[dst] = f2bf(lo);
}

__global__ __launch_bounds__(256) void prep_xall(
    const float* __restrict__ x,
    unsigned short* __restrict__ Xhi, unsigned short* __restrict__ Xlo)
{
  size_t idx = (size_t)blockIdx.x * 256 + threadIdx.x;
  if (idx >= (size_t)TT * BB * 96) return;
  int kx = (int)(idx % 96);
  size_t rem = idx / 96;
  int b = (int)(rem % BB);
  int t = (int)(rem / BB);
  float v = (kx < CC) ? x[(size_t)b * XROW + (size_t)t * CC + kx] : 0.f;
  unsigned short hi = f2bf(v);
  float lo = v - bf2f(hi);
  int cb = (((kx >> 3) & 3) ^ SWROW(b)) & 3;
  size_t dst = ((size_t)t * BB + b) * 96 + (size_t)(kx & ~31) + cb * 8 + (kx & 7);
  Xhi[dst] = hi;
  Xlo[dst] = f2bf(lo);
}

__global__ __launch_bounds__(256) void wst_row_kernel(
    const float* __restrict__ src, int src_stride,
    const float* __restrict__ encWT, const float* __restrict__ encb,
    float* __restrict__ dst, const int* __restrict__ flagp)
{
  if (*flagp) return;   // fast path active: wst not used (region overlaid)
  __shared__ float s[CC];
  int b = blockIdx.y;
  int h = blockIdx.x * 256 + threadIdx.x;
  if (threadIdx.x < CC) s[threadIdx.x] = src[(size_t)b * src_stride + threadIdx.x];
  __syncthreads();
  float acc = encb[h];
  #pragma unroll
  for (int k = 0; k < CC; ++k) acc = fmaf(s[k], encWT[(size_t)k * HH + h], acc);
  dst[(size_t)b * (10 * HH) + h] = acc;
}

__global__ __launch_bounds__(256) void transpose_encW(
    const float* __restrict__ W, float* __restrict__ WT)
{
  int k = blockIdx.x;
  int h = blockIdx.y * 256 + threadIdx.x;
  WT[(size_t)k * HH + h] = W[(size_t)h * CC + k];
}

__global__ __launch_bounds__(256) void copy_last_kernel(
    const float* __restrict__ x, float* __restrict__ last)
{
  int idx = blockIdx.x * 256 + threadIdx.x;
  if (idx < BB * CC) {
    int b = idx / CC, c = idx - b * CC;
    last[idx] = x[(size_t)b * XROW + 63 * CC + c];
  }
}

__global__ __launch_bounds__(256) void flag_kernel(
    const float* __restrict__ lnA, const float* __restrict__ lnB, int* flagp)
{
  int idx = blockIdx.x * 256 + threadIdx.x;
  bool ok;
  if (idx < LL * HH) ok = (lnA[idx] == 1.0f);
  else ok = (lnB[idx - LL * HH] == 0.0f);
  if (!ok) atomicAnd(flagp, 0);
}

// ---------------------------------------------------------------------------
// Fast-path preps. tabs layout: K3[4356] | K2T[4356] | e1[66] | csE[66] |
// g0[66] | R[66] | be | sum_encb  (8978 floats). Wave-parallel: one wave
// per output, 64-lane reduction over h.
// ---------------------------------------------------------------------------
__global__ __launch_bounds__(256) void prep_tabs(
    const float* __restrict__ encW, const float* __restrict__ encb,
    const float* __restrict__ outW, float* __restrict__ tabs)
{
  const int lane = threadIdx.x & 63, wid = threadIdx.x >> 6;
  int idx = blockIdx.x * 4 + wid;
  if (idx >= 8978) return;
  float a = 0.f;
  if (idx < 4356) {
    int c1 = idx / 66, c2 = idx % 66;
    for (int h = lane; h < HH; h += 64) a = fmaf(encW[h * CC + c1], encW[h * CC + c2], a);
  } else if (idx < 8712) {
    int p = idx - 4356; int c = p / 66, c1 = p % 66;
    for (int h = lane; h < HH; h += 64) a = fmaf(encW[h * CC + c1], outW[(size_t)c * HH + h], a);
  } else if (idx < 8778) {
    int c1 = idx - 8712;
    for (int h = lane; h < HH; h += 64) a = fmaf(encW[h * CC + c1], encb[h], a);
  } else if (idx < 8844) {
    int c1 = idx - 8778;
    for (int h = lane; h < HH; h += 64) a += encW[h * CC + c1];
  } else if (idx < 8910) {
    int c = idx - 8844;
    for (int h = lane; h < HH; h += 64) a = fmaf(encb[h], outW[(size_t)c * HH + h], a);
  } else if (idx < 8976) {
    int c = idx - 8910;
    for (int h = lane; h < HH; h += 64) a += outW[(size_t)c * HH + h];
  } else if (idx == 8976) {
    for (int h = lane; h < HH; h += 64) a = fmaf(encb[h], encb[h], a);
  } else {
    for (int h = lane; h < HH; h += 64) a += encb[h];
  }
  a = wave_sum63(a);
  if (lane == 63) tabs[idx] = a;
}

__global__ __launch_bounds__(256) void prep_b144(
    const float* __restrict__ encW, const float* __restrict__ outW,
    const float* __restrict__ encb, float* __restrict__ B144)
{
  int idx = blockIdx.x * 256 + threadIdx.x;
  if (idx >= 1024 * 144) return;
  int k = idx / 144, n = idx % 144;
  float v;
  if (n < 66) v = encW[k * CC + n];
  else if (n < 132) v = outW[(size_t)(n - 66) * HH + k];
  else if (n == 132) v = encb[k];
  else if (n == 133) v = 1.f;
  else v = 0.f;
  B144[idx] = v;
}

__global__ __launch_bounds__(256) void linit_kernel(
    const float* __restrict__ x, float* __restrict__ l_ring,
    const int* __restrict__ flagp)
{
  if (!*flagp) return;
  int idx = blockIdx.x * 256 + threadIdx.x;
  if (idx >= 1024 * 9 * 66) return;
  int c = idx % 66; int r = idx / 66; int w = r % 9; int b = r / 9;
  l_ring[((size_t)b * 10 + w) * 66 + c] = x[(size_t)b * XROW + (54 + w) * CC + c];
}

// init-only: q = K3 @ frame into ring slot (w = 0..9 covers x54..x63)
__global__ __launch_bounds__(256) void qnew_kernel(
    const float* __restrict__ src, int sstride, const float* __restrict__ K3,
    float* __restrict__ q_ring, int slot, const int* __restrict__ flagp)
{
  if (!*flagp) return;
  __shared__ float Ks[4356];
  __shared__ float ls[8][66];
  int tid = threadIdx.x, b0 = blockIdx.x * 8;
  for (int i = tid; i < 4356; i += 256) Ks[i] = K3[i];
  for (int i = tid; i < 8 * 66; i += 256)
    ls[i / 66][i % 66] = src[(size_t)(b0 + i / 66) * sstride + (i % 66)];
  __syncthreads();
  for (int o = tid; o < 528; o += 256) {
    int bi = o / 66, c1 = o % 66;
    float a = 0.f;
    for (int c2 = 0; c2 < 66; ++c2) a = fmaf(Ks[c1 * 66 + c2], ls[bi][c2], a);
    q_ring[((size_t)(b0 + bi) * 10 + slot) * 66 + c1] = a;
  }
}

__global__ __launch_bounds__(256) void fast_combine(
    const float* __restrict__ dp, float* __restrict__ u, float* __restrict__ G,
    float* __restrict__ e, float* __restrict__ s, const int* __restrict__ flagp)
{
  if (!*flagp) return;
  int o = blockIdx.x * 256 + threadIdx.x;
  if (o >= 1024 * 144) return;
  int b = o / 144, c = o % 144;
  float a = 0.f;
  #pragma unroll
  for (int g = 0; g < DPSEG; ++g) a += dp[((size_t)g * 1024 + b) * 144 + c];
  if (c < 66) u[b * 66 + c] = a;
  else if (c < 132) G[b * 66 + (c - 66)] = a;
  else if (c == 132) e[b] = a;
  else if (c == 133) s[b] = a;
}

// ---------------------------------------------------------------------------
// tail_kernel: fast path = Gram (frame space) + 12-layer affine-LN recursion
// + output + q(new frame) for the next step. Generic path = round-4 mlp.
// ---------------------------------------------------------------------------
__global__ __launch_bounds__(256) void tail_kernel(
    const float* __restrict__ hdec, const float* __restrict__ whp,
    float* __restrict__ last, float* __restrict__ l_ring,
    float* __restrict__ q_ring, const float* __restrict__ dp,
    const float* __restrict__ u_whp, const float* __restrict__ G_whp,
    const float* __restrict__ e_whp, const float* __restrict__ s_whp,
    const float* __restrict__ tabs,
    float* __restrict__ wst, const float* __restrict__ encWT,
    const float* __restrict__ encb,
    const float* __restrict__ seqW, const float* __restrict__ seqb,
    const float* __restrict__ lnA, const float* __restrict__ lnB,
    const float* __restrict__ outW, const float* __restrict__ outb,
    const float* __restrict__ mrgW, const float* __restrict__ mrgb,
    int ring0, float* __restrict__ outp,
    unsigned short* __restrict__ lpH, unsigned short* __restrict__ lpL,
    const int* __restrict__ flagp)
{
  const int b = blockIdx.x, tid = threadIdx.x;
  const int lane = tid & 63, wid = tid >> 6;
  const int slot9 = (ring0 == 0) ? 9 : ring0 - 1;   // == (ring0+9)%10

  if (*flagp) {
    // ================= fast path =================
    __shared__ float l_all[10][66], Qv[10][66];
    __shared__ float yd[66], gd[66], uw[66], se1[66], scs[66], lmix[66], newf[66];
    __shared__ float sW[156], sMm[156], sTt[156], sPp[156], sNn[156], sQq[156];
    __shared__ float sb12[12], sistd[12], scc[12], sfb[12], sdd12[12], swd[12], sVv[12], smrg[12];
    __shared__ float sred[12], misc[8];

    const float* K2T   = tabs + 4356;
    const float* tb_e1 = tabs + 8712;
    const float* tb_cs = tabs + 8778;
    const float* tb_g0 = tabs + 8844;
    const float* tb_R  = tabs + 8910;

    // ---- phase 0: staging + reductions ----
    for (int i = tid; i < 660; i += 256) {
      int w = i / 66, c = i % 66;
      int slot = ring0 + w; if (slot >= 10) slot -= 10;
      Qv[w][c] = q_ring[((size_t)b * 10 + slot) * 66 + c];
      if (w < 9) l_all[w][c] = l_ring[((size_t)b * 10 + slot) * 66 + c];
      else       l_all[9][c] = last[(size_t)b * 66 + c];
    }
    for (int i = tid; i < 66; i += 256) {
      uw[i]  = u_whp[(size_t)b * 66 + i];
      se1[i] = tb_e1[i];
      scs[i] = tb_cs[i];
    }
    if (tid < 134) {
      float a = 0.f;
      #pragma unroll
      for (int g = 0; g < DPSEG; ++g) a += dp[((size_t)g * 1024 + b) * 144 + tid];
      if (tid < 66) yd[tid] = a;
      else if (tid < 132) gd[tid - 66] = a;
      else if (tid == 132) misc[1] = a;   // <hdec, encb>
      else misc[2] = a;                   // sum_h hdec
    }
    if (tid >= 160 && tid < 172) smrg[tid - 160] = mrgW[tid - 160];
    {
      f32x4 hv = *(const f32x4*)&hdec[(size_t)b * 1024 + tid * 4];
      f32x4 wv = *(const f32x4*)&whp[(size_t)b * 1024 + tid * 4];
      float d2 = hv[0]*hv[0] + hv[1]*hv[1] + hv[2]*hv[2] + hv[3]*hv[3];
      float dw = hv[0]*wv[0] + hv[1]*wv[1] + hv[2]*wv[2] + hv[3]*wv[3];
      float w2 = wv[0]*wv[0] + wv[1]*wv[1] + wv[2]*wv[2] + wv[3]*wv[3];
      d2 = wave_sum63(d2); dw = wave_sum63(dw); w2 = wave_sum63(w2);
      if (lane == 63) { sred[wid*3] = d2; sred[wid*3+1] = dw; sred[wid*3+2] = w2; }
    }
    __syncthreads();
    if (tid >= 128 && tid < 131) {
      int i = tid - 128;
      misc[3 + i] = sred[i] + sred[3 + i] + sred[6 + i] + sred[9 + i];
    }
    if (tid == 132) misc[6] = tabs[8976];   // be
    if (tid == 133) misc[7] = tabs[8977];   // sum_encb
    __syncthreads();

    // ---- phase 1: Gram + fbar + init ----
    if (tid < 144) {
      int i = tid / 12, j = tid % 12;
      float gv;
      if (i == 0 && j == 0) gv = misc[5];
      else if (i == 11 && j == 11) gv = misc[3];
      else if ((i == 0 && j == 11) || (i == 11 && j == 0)) gv = misc[4];
      else if (i == 0 || j == 0) {
        int w = (i == 0 ? j : i) - 1;
        float a = e_whp[b];
        for (int c = 0; c < 66; ++c) a = fmaf(uw[c], l_all[w][c], a);
        gv = a;
      } else if (i == 11 || j == 11) {
        int w = (i == 11 ? j : i) - 1;
        float a = misc[1];
        for (int c = 0; c < 66; ++c) a = fmaf(yd[c], l_all[w][c], a);
        gv = a;
      } else {
        int wi = i - 1, wj = j - 1;
        float a = misc[6];
        for (int c = 0; c < 66; ++c) a = fmaf(se1[c], l_all[wi][c] + l_all[wj][c], a);
        for (int c = 0; c < 66; ++c) a = fmaf(l_all[wi][c], Qv[wj][c], a);
        gv = a;
      }
      sMm[i * 13 + j] = gv * (1.f / 1024.f);
      sTt[i * 13 + j] = (i == j) ? 1.f : 0.f;
    }
    if (tid >= 144 && tid < 156) {
      int k = tid - 144;
      float fb;
      if (k == 0) fb = s_whp[b] * (1.f / 1024.f);
      else if (k == 11) fb = misc[2] * (1.f / 1024.f);
      else {
        float a = misc[7];
        for (int c = 0; c < 66; ++c) a = fmaf(scs[c], l_all[k - 1][c], a);
        fb = a * (1.f / 1024.f);
      }
      sfb[k] = fb;
      sdd12[k] = 0.f;
    }
    __syncthreads();

    // ---- phase 2: 12-layer recursion ----
    for (int l = 0; l < LL; ++l) {
      if (tid < 144) sW[(tid / 12) * 13 + (tid % 12)] = seqW[l * 144 + tid];
      if (tid >= 160 && tid < 172) sb12[tid - 160] = seqb[l * 12 + (tid - 160)];
      __syncthreads();
      if (tid < 144) {
        int s = tid / 12, k = tid % 12;
        float a = 0.f;
        #pragma unroll
        for (int k2 = 0; k2 < 12; ++k2) a = fmaf(sW[s * 13 + k2], sMm[k2 * 13 + k], a);
        sPp[s * 13 + k] = a;
      }
      __syncthreads();
      if (tid < 12) {
        int s = tid;
        float mu = sb12[s];
        #pragma unroll
        for (int k = 0; k < 12; ++k) mu = fmaf(sW[s * 13 + k], sfb[k], mu);
        float e2 = 0.f;
        #pragma unroll
        for (int k = 0; k < 12; ++k) e2 = fmaf(sPp[s * 13 + k], sW[s * 13 + k], e2);
        float wf = mu - sb12[s];
        float var = fmaxf(e2 - wf * wf, 0.f);
        float is = 1.f / sqrtf(var + 1e-5f);
        sistd[s] = is;
        scc[s] = is * (sb12[s] - mu);
      }
      __syncthreads();
      if (tid < 144) {
        int i = tid / 12, j = tid % 12;
        float a = 0.f;
        #pragma unroll
        for (int k = 0; k < 12; ++k) a = fmaf(sW[i * 13 + k], sTt[k * 13 + j], a);
        sQq[i * 13 + j] = a;
        sNn[i * 13 + j] = sMm[i * 13 + j] + sistd[i] * sPp[i * 13 + j];
      }
      if (tid >= 144 && tid < 156) {
        int i = tid - 144;
        float a = 0.f;
        #pragma unroll
        for (int k = 0; k < 12; ++k) a = fmaf(sW[i * 13 + k], sdd12[k], a);
        swd[i] = a;
      }
      __syncthreads();
      if (tid < 144) {
        int i = tid / 12, j = tid % 12;
        sTt[i * 13 + j] += sistd[i] * sQq[i * 13 + j];
        float a = 0.f;
        #pragma unroll
        for (int k = 0; k < 12; ++k) a = fmaf(sNn[i * 13 + k], sW[j * 13 + k], a);
        sPp[i * 13 + j] = a;
      }
      if (tid >= 144 && tid < 156) {
        int i = tid - 144;
        sdd12[i] = sdd12[i] + sistd[i] * swd[i] + scc[i];
      }
      __syncthreads();
      if (tid < 144) {
        int i = tid / 12, j = tid % 12;
        sMm[i * 13 + j] = sNn[i * 13 + j] + sPp[i * 13 + j] * sistd[j]
                        + sfb[i] * scc[j] + scc[i] * sfb[j] - scc[i] * scc[j];
      }
      __syncthreads();
    }

    // ---- phase 3: output + q(new frame) ----
    if (tid < 12) {
      float a = 0.f;
      #pragma unroll
      for (int s = 0; s < 12; ++s) a = fmaf(smrg[s], sTt[s * 13 + tid], a);
      sVv[tid] = a;
    }
    if (tid == 200) {
      float a = 0.f;
      for (int s = 0; s < 12; ++s) a = fmaf(smrg[s], sdd12[s], a);
      misc[0] = a;
    }
    __syncthreads();
    if (tid < 66) {
      float a = 0.f;
      #pragma unroll
      for (int w = 0; w < 9; ++w) a = fmaf(sVv[1 + w], l_all[w][tid], a);
      a = fmaf(sVv[10], l_all[9][tid], a);
      lmix[tid] = a;
    }
    __syncthreads();
    if (tid < 66) {
      int c = tid;
      float vsr = 0.f, smw = 0.f;
      #pragma unroll
      for (int k = 1; k <= 10; ++k) vsr += sVv[k];
      #pragma unroll
      for (int s = 0; s < 12; ++s) smw += smrg[s];
      float lastv = l_all[9][c];
      float acc = sVv[0] * G_whp[(size_t)b * 66 + c]
                + vsr * tb_g0[c]
                + sVv[11] * gd[c]
                + misc[0] * tb_R[c]
                + smw * outb[c] + mrgb[0] + lastv;
      const float* krow = K2T + c * 66;
      for (int c2 = 0; c2 < 66; ++c2) acc = fmaf(lmix[c2], krow[c2], acc);
      outp[(size_t)b * XROW + c] = acc;
      last[(size_t)b * 66 + c] = acc;
      l_ring[((size_t)b * 10 + slot9) * 66 + c] = lastv;
      newf[c] = acc;
      unsigned short hi = f2bf(acc);
      float lo = acc - bf2f(hi);
      int cb = (((c >> 3) & 3) ^ SWROW(b)) & 3;
      size_t dst = (size_t)b * 96 + (size_t)(c & ~31) + cb * 8 + (c & 7);
      lpH[dst] = hi;
      lpL[dst] = f2bf(lo);
    }
    __syncthreads();
    if (tid < 66) {
      // q(new frame) for the next step, ring slot = ring0
      float a = 0.f;
      const float* k3r = tabs + tid * 66;
      for (int c2 = 0; c2 < 66; ++c2) a = fmaf(k3r[c2], newf[c2], a);
      q_ring[((size_t)b * 10 + ring0) * 66 + tid] = a;
    }
    return;
  }

  // ================= generic fallback (round-4 mlp, exact) =================
  __shared__ float red[4][24];
  __shared__ f2 mustd2[SS];
  __shared__ float g_lds[HH];
  __shared__ float nc[CC];

  const int h0 = tid;
  const int h1 = tid + 512;
  const float* lrow = last + (size_t)b * CC;
  f2 wnew[2];
  {
    f2 a0 = { encb[h0], encb[h0 + 256] };
    f2 a1 = { encb[h1], encb[h1 + 256] };
    #pragma unroll 11
    for (int k = 0; k < CC; ++k) {
      float lv = lrow[k];
      f2 lv2 = { lv, lv };
      f2 w0 = { encWT[(size_t)k * HH + h0], encWT[(size_t)k * HH + h0 + 256] };
      f2 w1 = { encWT[(size_t)k * HH + h1], encWT[(size_t)k * HH + h1 + 256] };
      a0 = __builtin_elementwise_fma(lv2, w0, a0);
      a1 = __builtin_elementwise_fma(lv2, w1, a1);
    }
    wnew[0] = a0; wnew[1] = a1;
    float* wd = wst + ((size_t)b * 10 + slot9) * HH;
    wd[h0] = a0.x; wd[h0 + 256] = a0.y;
    wd[h1] = a1.x; wd[h1 + 256] = a1.y;
  }

  f2 fr[2][SS];
  {
    const float* whb = whp + (size_t)b * HH;
    const float* hb  = hdec + (size_t)b * HH;
    fr[0][0]  = { whb[h0], whb[h0 + 256] };
    fr[1][0]  = { whb[h1], whb[h1 + 256] };
    fr[0][11] = { hb[h0], hb[h0 + 256] };
    fr[1][11] = { hb[h1], hb[h1 + 256] };
    #pragma unroll
    for (int w = 0; w < 9; ++w) {
      int slot = ring0 + w; if (slot >= 10) slot -= 10;
      const float* ws_ = wst + ((size_t)b * 10 + slot) * HH;
      fr[0][1 + w] = { ws_[h0], ws_[h0 + 256] };
      fr[1][1 + w] = { ws_[h1], ws_[h1 + 256] };
    }
    fr[0][10] = wnew[0];
    fr[1][10] = wnew[1];
  }

  #pragma unroll 1
  for (int l = 0; l < LL; ++l) {
    const float* W  = seqW + (size_t)l * SS * SS;
    const float* Bv = seqb + (size_t)l * SS;
    const float* lA = lnA + (size_t)l * HH;
    const float* lB = lnB + (size_t)l * HH;
    f2 al[2], be[2];
    al[0] = { lA[h0], lA[h0 + 256] };  al[1] = { lA[h1], lA[h1 + 256] };
    be[0] = { lB[h0], lB[h0 + 256] };  be[1] = { lB[h1], lB[h1 + 256] };

    f2 y[2][SS];
    #pragma unroll
    for (int s = 0; s < SS; ++s) {
      float bv = Bv[s];
      f2 a0 = { bv, bv }, a1 = { bv, bv };
      #pragma unroll
      for (int k = 0; k < SS; ++k) {
        float wv = W[s * SS + k];
        f2 wv2 = { wv, wv };
        a0 = __builtin_elementwise_fma(fr[0][k], wv2, a0);
        a1 = __builtin_elementwise_fma(fr[1][k], wv2, a1);
      }
      y[0][s] = a0; y[1][s] = a1;
      f2 pp = a0 + a1;
      float ps = wave_sum63(pp.x + pp.y);
      f2 qq = __builtin_elementwise_fma(a0, a0, a1 * a1);
      float pq = wave_sum63(qq.x + qq.y);
      if (lane == 63) { red[wid][s] = ps; red[wid][12 + s] = pq; }
    }
    __syncthreads();
    if (tid < SS) {
      float S = red[0][tid] + red[1][tid] + red[2][tid] + red[3][tid];
      float Q = red[0][12 + tid] + red[1][12 + tid] + red[2][12 + tid] + red[3][12 + tid];
      float mu = S * (1.f / HH);
      float var = Q * (1.f / HH) - mu * mu;
      mustd2[tid] = { mu, 1.f / sqrtf(var + 1e-5f) };
    }
    __syncthreads();
    #pragma unroll
    for (int s = 0; s < SS; ++s) {
      f2 mi = mustd2[s];
      f2 mus = { mi.x, mi.x };
      f2 isd = { mi.y, mi.y };
      #pragma unroll
      for (int p = 0; p < 2; ++p) {
        f2 t = (y[p][s] - mus) * isd;
        fr[p][s] = __builtin_elementwise_fma(t, al[p], fr[p][s]) + be[p];
      }
    }
    __syncthreads();
  }

  float smw = 0.f;
  f2 g[2] = { {0.f, 0.f}, {0.f, 0.f} };
  #pragma unroll
  for (int s = 0; s < SS; ++s) {
    float mv = mrgW[s];
    smw += mv;
    f2 mv2 = { mv, mv };
    g[0] = __builtin_elementwise_fma(mv2, fr[0][s], g[0]);
    g[1] = __builtin_elementwise_fma(mv2, fr[1][s], g[1]);
  }
  g_lds[h0] = g[0].x; g_lds[h0 + 256] = g[0].y;
  g_lds[h1] = g[1].x; g_lds[h1 + 256] = g[1].y;
  const float mbv = mrgb[0];
  __syncthreads();
  #pragma unroll 1
  for (int i = 0; i < 17; ++i) {
    int c = wid + 4 * i;
    if (c < CC) {
      const float* ow = outW + (size_t)c * HH;
      float acc = 0.f;
      #pragma unroll
      for (int q = 0; q < 16; ++q) acc = fmaf(g_lds[lane + q * 64], ow[lane + q * 64], acc);
      acc = wave_sum63(acc);
      if (lane == 63) nc[c] = acc + outb[c] * smw + mbv + lrow[c];
    }
  }
  __syncthreads();
  if (tid < CC) {
    float nv = nc[tid];
    outp[(size_t)b * XROW + tid] = nv;
    last[(size_t)b * CC + tid] = nv;
    unsigned short hi = f2bf(nv);
    float lo = nv - bf2f(hi);
    int cb = (((tid >> 3) & 3) ^ SWROW(b)) & 3;
    size_t dst = (size_t)b * 96 + (size_t)(tid & ~31) + cb * 8 + (tid & 7);
    lpH[dst] = hi;
    lpL[dst] = f2bf(lo);
  }
}

// ---------------------------------------------------------------------------
extern "C" void kernel_launch(void* const* d_in, const int* in_sizes, int n_in,
                              void* d_out, int out_size, void* d_ws, size_t ws_size,
                              hipStream_t stream) {
  const float* x    = (const float*)d_in[0];
  const float* gWi  = (const float*)d_in[1];
  const float* gWh  = (const float*)d_in[2];
  const float* gbi  = (const float*)d_in[3];
  const float* gbh  = (const float*)d_in[4];
  const float* encW = (const float*)d_in[5];
  const float* encb = (const float*)d_in[6];
  const float* seqW = (const float*)d_in[7];
  const float* seqb = (const float*)d_in[8];
  const float* lnA  = (const float*)d_in[9];
  const float* lnB  = (const float*)d_in[10];
  const float* outW = (const float*)d_in[11];
  const float* outb = (const float*)d_in[12];
  const float* mrgW = (const float*)d_in[13];
  const float* mrgb = (const float*)d_in[14];
  float* out = (float*)d_out;

  char* p = (char*)d_ws;
  auto alloc = [&](size_t bytes) { char* r = p; p += (bytes + 255) & ~(size_t)255; return r; };
  float* encWT = (float*)alloc((size_t)CC * HH * 4);
  float* last  = (float*)alloc((size_t)BB * CC * 4);
  float* wst   = (float*)alloc((size_t)BB * 10 * HH * 4);   // generic ring / fast overlay
  float* hf[3];
  for (int i = 0; i < 3; ++i) hf[i] = (float*)alloc((size_t)BB * HH * 4);
  unsigned short* WgH = (unsigned short*)alloc((size_t)4096 * 1120 * 2);
  unsigned short* WgL = (unsigned short*)alloc((size_t)4096 * 1120 * 2);
  unsigned short* XaH = (unsigned short*)alloc((size_t)TT * BB * 96 * 2);
  unsigned short* XaL = (unsigned short*)alloc((size_t)TT * BB * 96 * 2);
  unsigned short* hhi[3]; unsigned short* hlo[3];
  for (int i = 0; i < 3; ++i) {
    hhi[i] = (unsigned short*)alloc((size_t)BB * HH * 2);
    hlo[i] = (unsigned short*)alloc((size_t)BB * HH * 2);
  }
  unsigned short* lpH = (unsigned short*)alloc((size_t)BB * 96 * 2);
  unsigned short* lpL = (unsigned short*)alloc((size_t)BB * 96 * 2);
  int* flag = (int*)alloc(256);
  if ((size_t)(p - (char*)d_ws) > ws_size) return;  // insufficient workspace

  // fast-path overlay inside the wst region (mutually exclusive by flag)
  char* ov = (char*)wst;
  float* B144  = (float*)ov;                 ov += (size_t)1024 * 144 * 4;
  float* dp32  = (float*)ov;                 ov += (size_t)DPSEG * 1024 * 144 * 4;  // 18.9 MB
  float* l_ring= (float*)ov;                 ov += (size_t)1024 * 10 * 66 * 4;
  float* q_ring= (float*)ov;                 ov += (size_t)1024 * 10 * 66 * 4;
  float* u_whp = (float*)ov;                 ov += (size_t)1024 * 66 * 4;
  float* G_whp = (float*)ov;                 ov += (size_t)1024 * 66 * 4;
  float* e_whp = (float*)ov;                 ov += 4096;
  float* s_whp = (float*)ov;                 ov += 4096;
  float* tabs  = (float*)ov;                 ov += 9216 * 4;

  // ---- one-time prep ----
  hipMemsetAsync(flag, 0xFF, 4, stream);
  flag_kernel<<<dim3(96), 256, 0, stream>>>(lnA, lnB, flag);
  prep_wgc<<<dim3((4096u * 1120u) / 256u), 256, 0, stream>>>(gWh, gWi, WgH, WgL);
  prep_xall<<<dim3(((unsigned)TT * BB * 96) / 256u), 256, 0, stream>>>(x, XaH, XaL);
  transpose_encW<<<dim3(CC, HH/256), 256, 0, stream>>>(encW, encWT);
  copy_last_kernel<<<dim3((BB*CC + 255)/256), 256, 0, stream>>>(x, last);
  prep_b144<<<dim3(576), 256, 0, stream>>>(encW, outW, encb, B144);
  prep_tabs<<<dim3(2245), 256, 0, stream>>>(encW, encb, outW, tabs);
  linit_kernel<<<dim3((1024*9*66)/256), 256, 0, stream>>>(x, l_ring, flag);
  for (int w = 0; w < 10; ++w)   // slots 0..9 = q(x[54..63])
    qnew_kernel<<<dim3(128), 256, 0, stream>>>(x + (size_t)(54 + w) * CC, XROW,
                                               tabs, q_ring, w, flag);
  hipMemsetAsync(hf[0], 0, (size_t)BB * HH * 4, stream);
  hipMemsetAsync(hhi[0], 0, (size_t)BB * HH * 2, stream);
  hipMemsetAsync(hlo[0], 0, (size_t)BB * HH * 2, stream);

  const dim3 ggrid(512);

  // ---- encoder: 63 GRU steps (no dp) ----
  int cur = 0;
  for (int t = 0; t < 63; ++t) {
    int nxt = 1 - cur;
    gru_mfma<<<ggrid, 256, 0, stream>>>(
        hhi[cur], hlo[cur], hf[cur],
        XaH + (size_t)t * BB * 96, XaL + (size_t)t * BB * 96,
        WgH, WgL, gbi, gbh, hf[nxt], hhi[nxt], hlo[nxt],
        B144, dp32, flag, 0);
    cur = nxt;
  }
  // window_history GRU -> hf[2], with fused dp (whp's dp feeds fast_combine + t=0 tail)
  gru_mfma<<<ggrid, 256, 0, stream>>>(
      hhi[cur], hlo[cur], hf[cur],
      XaH + (size_t)63 * BB * 96, XaL + (size_t)63 * BB * 96,
      WgH, WgL, gbi, gbh, hf[2], hhi[2], hlo[2],
      B144, dp32, flag, 1);

  // whp-derived persistent fast-path arrays
  fast_combine<<<dim3(576), 256, 0, stream>>>(dp32, u_whp, G_whp, e_whp, s_whp, flag);

  // generic-path wst init (skipped when fast)
  for (int w = 0; w < 9; ++w)
    wst_row_kernel<<<dim3(HH/256, BB), 256, 0, stream>>>(
        x + (size_t)(54 + w) * CC, XROW, encWT, encb, wst + (size_t)w * HH, flag);

  // ---- decoder: 64 steps, 2 launches each ----
  int hc = 2;
  for (int t = 0; t < 64; ++t) {
    if (t > 0) {
      int hn = (t - 1) & 1;
      gru_mfma<<<ggrid, 256, 0, stream>>>(
          hhi[hc], hlo[hc], hf[hc], lpH, lpL,
          WgH, WgL, gbi, gbh, hf[hn], hhi[hn], hlo[hn],
          B144, dp32, flag, 1);
      hc = hn;
    }
    tail_kernel<<<dim3(BB), 256, 0, stream>>>(
        hf[hc], hf[2], last, l_ring, q_ring, dp32,
        u_whp, G_whp, e_whp, s_whp, tabs,
        wst, encWT, encb, seqW, seqb, lnA, lnB, outW, outb, mrgW, mrgb,
        t % 10, out + (size_t)t * CC, lpH, lpL, flag);
  }
}

// Round 9
// 7619.574 us; speedup vs baseline: 1.9855x; 1.0437x over previous
//
#include <hip/hip_runtime.h>
#include <hip/hip_bf16.h>
#include <cstddef>
#include <cstdint>

#define BB 1024
#define TT 64
#define CC 66
#define HH 1024
#define SS 12
#define LL 12
#define XROW (TT*CC)   // 4224 floats per batch row of x
#define DPSEG 32       // dp segments (one per jb)

typedef __attribute__((ext_vector_type(8))) __bf16 bfrag;
typedef __attribute__((ext_vector_type(4))) float f32x4;
typedef __attribute__((ext_vector_type(8))) short s8v;
typedef __attribute__((ext_vector_type(2))) float f2;

#define SWROW(r) (((r) >> 1) & 3)
// wave-internal LDS write->read ordering (no cross-wave data => no barrier)
#define WSYNC() asm volatile("s_waitcnt lgkmcnt(0)" ::: "memory")

__device__ __forceinline__ unsigned short f2bf(float f) {
  unsigned int u = __builtin_bit_cast(unsigned int, f);
  unsigned int r = u + 0x7FFFu + ((u >> 16) & 1u);
  return (unsigned short)(r >> 16);
}
__device__ __forceinline__ float bf2f(unsigned short h) {
  unsigned int u = ((unsigned int)h) << 16;
  return __builtin_bit_cast(float, u);
}

__device__ __forceinline__ void gload16(const void* g, void* l) {
  __builtin_amdgcn_global_load_lds(
      (const __attribute__((address_space(1))) unsigned int*)g,
      (__attribute__((address_space(3))) unsigned int*)l, 16, 0, 0);
}

template<int CTRL, int RM>
__device__ __forceinline__ float dppadd(float v) {
  int x = __builtin_amdgcn_update_dpp(0, __builtin_bit_cast(int, v),
                                      CTRL, RM, 0xF, true);
  return v + __builtin_bit_cast(float, x);
}
__device__ __forceinline__ float wave_sum63(float v) {
  v = dppadd<0x111, 0xF>(v);
  v = dppadd<0x112, 0xF>(v);
  v = dppadd<0x114, 0xF>(v);
  v = dppadd<0x118, 0xF>(v);
  v = dppadd<0x142, 0xa>(v);
  v = dppadd<0x143, 0xc>(v);
  return v;
}

// ---------------------------------------------------------------------------
// Split-bf16 MFMA GRU step (round-8 structure; dp layout now [b][jb][144]).
// ---------------------------------------------------------------------------
__global__ __launch_bounds__(256) void gru_mfma(
    const unsigned short* __restrict__ Ahi, const unsigned short* __restrict__ Alo,
    const float* __restrict__ hprev,
    const unsigned short* __restrict__ Xhi, const unsigned short* __restrict__ Xlo,
    const unsigned short* __restrict__ Whi, const unsigned short* __restrict__ Wlo,
    const float* __restrict__ bi, const float* __restrict__ bh,
    float* __restrict__ hout_f32,
    unsigned short* __restrict__ hout_hi, unsigned short* __restrict__ hout_lo,
    const float* __restrict__ B144, float* __restrict__ dp32,
    const int* __restrict__ flagp, int do_dp)
{
  __shared__ __align__(16) unsigned short AsH[3][64*32];
  __shared__ __align__(16) unsigned short AsL[3][64*32];
  __shared__ __align__(16) unsigned short BsH[3][128*32];
  __shared__ __align__(16) unsigned short BsL[3][128*32];

  const int tid = threadIdx.x, lane = tid & 63, wid = tid >> 6;
  const int bid = blockIdx.x;
  const int idx = bid >> 3;
  const int jb = (bid & 7) * 4 + (idx & 3);
  const int b0 = (idx >> 2) * 64;
  const int wm = wid >> 1, wn = wid & 1;
  const int aR = lane >> 2, aC = lane & 3;

  auto stage = [&](int bs, int kc) {
    const unsigned short *shi, *slo; size_t go;
    int row = wid * 16 + aR;
    if (kc < 32) {
      go = (size_t)(b0 + row) * 1024 + (size_t)kc * 32 + aC * 8;
      shi = Ahi; slo = Alo;
    } else {
      go = (size_t)(b0 + row) * 96 + (size_t)(kc - 32) * 32 + aC * 8;
      shi = Xhi; slo = Xlo;
    }
    gload16(shi + go, &AsH[bs][wid * 512]);
    gload16(slo + go, &AsL[bs][wid * 512]);
    size_t base = ((size_t)jb * 35 + kc) * 4096;
    size_t go0 = base + (size_t)(wid * 32 + aR) * 32 + aC * 8;
    gload16(Whi + go0,       &BsH[bs][wid * 1024]);
    gload16(Whi + go0 + 512, &BsH[bs][wid * 1024 + 512]);
    gload16(Wlo + go0,       &BsL[bs][wid * 1024]);
    gload16(Wlo + go0 + 512, &BsL[bs][wid * 1024 + 512]);
  };

  int offA[2], offB[4];
  #pragma unroll
  for (int mh = 0; mh < 2; ++mh) {
    int r = wm * 32 + mh * 16 + (lane & 15);
    int cb = (lane >> 4) ^ SWROW(r);
    offA[mh] = r * 32 + cb * 8;
  }
  #pragma unroll
  for (int g = 0; g < 4; ++g) {
    int r = wn * 64 + g * 16 + (lane & 15);
    int cb = (lane >> 4) ^ SWROW(r);
    offB[g] = r * 32 + cb * 8;
  }

  f32x4 acc[2][4] = {};

  stage(0, 0);
  stage(1, 1);

  int cur = 0;
  for (int kc = 0; kc < 34; ++kc) {
    asm volatile("s_waitcnt vmcnt(6)" ::: "memory");
    __builtin_amdgcn_s_barrier();
    asm volatile("" ::: "memory");

    bfrag ah[2], al[2], bhf[4], blf[4];
    #pragma unroll
    for (int mh = 0; mh < 2; ++mh) {
      ah[mh] = __builtin_bit_cast(bfrag, *(const s8v*)(&AsH[cur][offA[mh]]));
      al[mh] = __builtin_bit_cast(bfrag, *(const s8v*)(&AsL[cur][offA[mh]]));
    }
    #pragma unroll
    for (int g = 0; g < 4; ++g) {
      bhf[g] = __builtin_bit_cast(bfrag, *(const s8v*)(&BsH[cur][offB[g]]));
      blf[g] = __builtin_bit_cast(bfrag, *(const s8v*)(&BsL[cur][offB[g]]));
    }
    if (kc < 33) {
      int st = (cur >= 1) ? cur - 1 : 2;   // (cur+2)%3
      stage(st, kc + 2);
    }
    #pragma unroll
    for (int mh = 0; mh < 2; ++mh)
      #pragma unroll
      for (int g = 0; g < 4; ++g) {
        acc[mh][g] = __builtin_amdgcn_mfma_f32_16x16x32_bf16(ah[mh], bhf[g], acc[mh][g], 0, 0, 0);
        acc[mh][g] = __builtin_amdgcn_mfma_f32_16x16x32_bf16(ah[mh], blf[g], acc[mh][g], 0, 0, 0);
        acc[mh][g] = __builtin_amdgcn_mfma_f32_16x16x32_bf16(al[mh], bhf[g], acc[mh][g], 0, 0, 0);
      }
    cur = (cur < 2) ? cur + 1 : 0;
  }
  // peeled kc = 34 (cur == 1)
  {
    asm volatile("s_waitcnt vmcnt(0)" ::: "memory");
    __builtin_amdgcn_s_barrier();
    asm volatile("" ::: "memory");
    bfrag ah[2], al[2], bhf[4], blf[4];
    #pragma unroll
    for (int mh = 0; mh < 2; ++mh) {
      ah[mh] = __builtin_bit_cast(bfrag, *(const s8v*)(&AsH[1][offA[mh]]));
      al[mh] = __builtin_bit_cast(bfrag, *(const s8v*)(&AsL[1][offA[mh]]));
    }
    #pragma unroll
    for (int g = 0; g < 4; ++g) {
      bhf[g] = __builtin_bit_cast(bfrag, *(const s8v*)(&BsH[1][offB[g]]));
      blf[g] = __builtin_bit_cast(bfrag, *(const s8v*)(&BsL[1][offB[g]]));
    }
    #pragma unroll
    for (int mh = 0; mh < 2; ++mh)
      #pragma unroll
      for (int g = 0; g < 4; ++g) {
        acc[mh][g] = __builtin_amdgcn_mfma_f32_16x16x32_bf16(ah[mh], bhf[g], acc[mh][g], 0, 0, 0);
        acc[mh][g] = __builtin_amdgcn_mfma_f32_16x16x32_bf16(ah[mh], blf[g], acc[mh][g], 0, 0, 0);
        acc[mh][g] = __builtin_amdgcn_mfma_f32_16x16x32_bf16(al[mh], bhf[g], acc[mh][g], 0, 0, 0);
      }
  }

  const int j = jb * 32 + wn * 16 + (lane & 15);
  const float b_r  = bi[j] + bh[j];
  const float b_z  = bi[HH + j] + bh[HH + j];
  const float b_nh = bh[2 * HH + j];
  const float b_nx = bi[2 * HH + j];
  float hvv[2][4];
  #pragma unroll
  for (int mh = 0; mh < 2; ++mh)
    #pragma unroll
    for (int q = 0; q < 4; ++q) {
      int m = b0 + wm * 32 + mh * 16 + (lane >> 4) * 4 + q;
      float hpv = hprev[(size_t)m * HH + j];
      float rr = acc[mh][0][q] + b_r;
      float zz = acc[mh][1][q] + b_z;
      float nh = acc[mh][2][q] + b_nh;
      float nx = acc[mh][3][q] + b_nx;
      float r = 1.f / (1.f + __expf(-rr));
      float z = 1.f / (1.f + __expf(-zz));
      float n = tanhf(nx + r * nh);
      float hv = (1.f - z) * n + z * hpv;
      hvv[mh][q] = hv;
      hout_f32[(size_t)m * HH + j] = hv;
      unsigned short hi = f2bf(hv);
      float lo = hv - bf2f(hi);
      int cb = ((j >> 3) & 3) ^ SWROW(m);
      size_t dst = (size_t)m * 1024 + (size_t)(j & ~31) + cb * 8 + (j & 7);
      hout_hi[dst] = hi;
      hout_lo[dst] = f2bf(lo);
    }

  // fused dp partial: dp32[b][jb][144] = h_tile(64x32) @ B144-rows
  if (do_dp && *flagp) {
    float* hsf = reinterpret_cast<float*>(&AsH[0][0]);
    __syncthreads();
    #pragma unroll
    for (int mh = 0; mh < 2; ++mh)
      #pragma unroll
      for (int q = 0; q < 4; ++q) {
        int mloc = wm * 32 + mh * 16 + (lane >> 4) * 4 + q;
        int jloc = wn * 16 + (lane & 15);
        hsf[mloc * 33 + jloc] = hvv[mh][q];
      }
    __syncthreads();
    const int b_sub = tid & 63;
    const int cg = __builtin_amdgcn_readfirstlane(tid >> 6);
    const int base_c = cg * 36;
    float acc36[36];
    #pragma unroll
    for (int i = 0; i < 36; ++i) acc36[i] = 0.f;
    for (int kk = 0; kk < 32; ++kk) {
      float av = hsf[b_sub * 33 + kk];
      const float* brow = B144 + (size_t)(jb * 32 + kk) * 144 + base_c;
      #pragma unroll
      for (int qq = 0; qq < 9; ++qq) {
        f32x4 b4 = *(const f32x4*)(brow + qq * 4);
        acc36[qq*4+0] = fmaf(av, b4[0], acc36[qq*4+0]);
        acc36[qq*4+1] = fmaf(av, b4[1], acc36[qq*4+1]);
        acc36[qq*4+2] = fmaf(av, b4[2], acc36[qq*4+2]);
        acc36[qq*4+3] = fmaf(av, b4[3], acc36[qq*4+3]);
      }
    }
    float* drow = dp32 + ((size_t)(b0 + b_sub) * 32 + jb) * 144 + base_c;
    #pragma unroll
    for (int qq = 0; qq < 9; ++qq)
      *(f32x4*)(drow + qq * 4) = { acc36[qq*4+0], acc36[qq*4+1], acc36[qq*4+2], acc36[qq*4+3] };
  }
}

// ---------------------------------------------------------------------------
// Prep kernels (unchanged from round 8).
// ---------------------------------------------------------------------------
__global__ __launch_bounds__(256) void prep_wgc(
    const float* __restrict__ Wh, const float* __restrict__ Wi,
    unsigned short* __restrict__ Whi, unsigned short* __restrict__ Wlo)
{
  size_t idx = (size_t)blockIdx.x * 256 + threadIdx.x;
  if (idx >= (size_t)4096 * 1120) return;
  int k = (int)(idx % 1120);
  int rg = (int)(idx / 1120);
  int jbv = rg >> 7, r = rg & 127;
  int jhi = r >> 6, rem = r & 63, g = rem >> 4, jlo = rem & 15;
  int j = jbv * 32 + jhi * 16 + jlo;
  float v = 0.f;
  if (g == 0)      v = (k < 1024) ? Wh[(size_t)j * HH + k]            : ((k < 1090) ? Wi[(size_t)j * CC + (k - 1024)] : 0.f);
  else if (g == 1) v = (k < 1024) ? Wh[(size_t)(HH + j) * HH + k]     : ((k < 1090) ? Wi[(size_t)(HH + j) * CC + (k - 1024)] : 0.f);
  else if (g == 2) v = (k < 1024) ? Wh[(size_t)(2 * HH + j) * HH + k] : 0.f;
  else             v = (k >= 1024 && k < 1090) ? Wi[(size_t)(2 * HH + j) * CC + (k - 1024)] : 0.f;
  unsigned short hi = f2bf(v);
  float lo = v - bf2f(hi);
  int kc = k >> 5, kk = k & 31;
  int cb = ((kk >> 3) ^ SWROW(r)) & 3;
  size_t dst = (((size_t)jbv * 35 + kc) * 128 + r) * 32 + cb * 8 + (kk & 7);
  Whi[dst] = hi;
  Wlo[dst] = f2bf(lo);
}

__global__ __launch_bounds__(256) void prep_xall(
    const float* __restrict__ x,
    unsigned short* __restrict__ Xhi, unsigned short* __restrict__ Xlo)
{
  size_t idx = (size_t)blockIdx.x * 256 + threadIdx.x;
  if (idx >= (size_t)TT * BB * 96) return;
  int kx = (int)(idx % 96);
  size_t rem = idx / 96;
  int b = (int)(rem % BB);
  int t = (int)(rem / BB);
  float v = (kx < CC) ? x[(size_t)b * XROW + (size_t)t * CC + kx] : 0.f;
  unsigned short hi = f2bf(v);
  float lo = v - bf2f(hi);
  int cb = (((kx >> 3) & 3) ^ SWROW(b)) & 3;
  size_t dst = ((size_t)t * BB + b) * 96 + (size_t)(kx & ~31) + cb * 8 + (kx & 7);
  Xhi[dst] = hi;
  Xlo[dst] = f2bf(lo);
}

__global__ __launch_bounds__(256) void wst_row_kernel(
    const float* __restrict__ src, int src_stride,
    const float* __restrict__ encWT, const float* __restrict__ encb,
    float* __restrict__ dst, const int* __restrict__ flagp)
{
  if (*flagp) return;
  __shared__ float s[CC];
  int b = blockIdx.y;
  int h = blockIdx.x * 256 + threadIdx.x;
  if (threadIdx.x < CC) s[threadIdx.x] = src[(size_t)b * src_stride + threadIdx.x];
  __syncthreads();
  float acc = encb[h];
  #pragma unroll
  for (int k = 0; k < CC; ++k) acc = fmaf(s[k], encWT[(size_t)k * HH + h], acc);
  dst[(size_t)b * (10 * HH) + h] = acc;
}

__global__ __launch_bounds__(256) void transpose_encW(
    const float* __restrict__ W, float* __restrict__ WT)
{
  int k = blockIdx.x;
  int h = blockIdx.y * 256 + threadIdx.x;
  WT[(size_t)k * HH + h] = W[(size_t)h * CC + k];
}

__global__ __launch_bounds__(256) void copy_last_kernel(
    const float* __restrict__ x, float* __restrict__ last)
{
  int idx = blockIdx.x * 256 + threadIdx.x;
  if (idx < BB * CC) {
    int b = idx / CC, c = idx - b * CC;
    last[idx] = x[(size_t)b * XROW + 63 * CC + c];
  }
}

__global__ __launch_bounds__(256) void flag_kernel(
    const float* __restrict__ lnA, const float* __restrict__ lnB, int* flagp)
{
  int idx = blockIdx.x * 256 + threadIdx.x;
  bool ok;
  if (idx < LL * HH) ok = (lnA[idx] == 1.0f);
  else ok = (lnB[idx - LL * HH] == 0.0f);
  if (!ok) atomicAnd(flagp, 0);
}

__global__ __launch_bounds__(256) void prep_tabs(
    const float* __restrict__ encW, const float* __restrict__ encb,
    const float* __restrict__ outW, float* __restrict__ tabs)
{
  const int lane = threadIdx.x & 63, wid = threadIdx.x >> 6;
  int idx = blockIdx.x * 4 + wid;
  if (idx >= 8978) return;
  float a = 0.f;
  if (idx < 4356) {
    int c1 = idx / 66, c2 = idx % 66;
    for (int h = lane; h < HH; h += 64) a = fmaf(encW[h * CC + c1], encW[h * CC + c2], a);
  } else if (idx < 8712) {
    int p = idx - 4356; int c = p / 66, c1 = p % 66;
    for (int h = lane; h < HH; h += 64) a = fmaf(encW[h * CC + c1], outW[(size_t)c * HH + h], a);
  } else if (idx < 8778) {
    int c1 = idx - 8712;
    for (int h = lane; h < HH; h += 64) a = fmaf(encW[h * CC + c1], encb[h], a);
  } else if (idx < 8844) {
    int c1 = idx - 8778;
    for (int h = lane; h < HH; h += 64) a += encW[h * CC + c1];
  } else if (idx < 8910) {
    int c = idx - 8844;
    for (int h = lane; h < HH; h += 64) a = fmaf(encb[h], outW[(size_t)c * HH + h], a);
  } else if (idx < 8976) {
    int c = idx - 8910;
    for (int h = lane; h < HH; h += 64) a += outW[(size_t)c * HH + h];
  } else if (idx == 8976) {
    for (int h = lane; h < HH; h += 64) a = fmaf(encb[h], encb[h], a);
  } else {
    for (int h = lane; h < HH; h += 64) a += encb[h];
  }
  a = wave_sum63(a);
  if (lane == 63) tabs[idx] = a;
}

__global__ __launch_bounds__(256) void prep_b144(
    const float* __restrict__ encW, const float* __restrict__ outW,
    const float* __restrict__ encb, float* __restrict__ B144)
{
  int idx = blockIdx.x * 256 + threadIdx.x;
  if (idx >= 1024 * 144) return;
  int k = idx / 144, n = idx % 144;
  float v;
  if (n < 66) v = encW[k * CC + n];
  else if (n < 132) v = outW[(size_t)(n - 66) * HH + k];
  else if (n == 132) v = encb[k];
  else if (n == 133) v = 1.f;
  else v = 0.f;
  B144[idx] = v;
}

__global__ __launch_bounds__(256) void linit_kernel(
    const float* __restrict__ x, float* __restrict__ l_ring,
    const int* __restrict__ flagp)
{
  if (!*flagp) return;
  int idx = blockIdx.x * 256 + threadIdx.x;
  if (idx >= 1024 * 9 * 66) return;
  int c = idx % 66; int r = idx / 66; int w = r % 9; int b = r / 9;
  l_ring[((size_t)b * 10 + w) * 66 + c] = x[(size_t)b * XROW + (54 + w) * CC + c];
}

__global__ __launch_bounds__(256) void qnew_kernel(
    const float* __restrict__ src, int sstride, const float* __restrict__ K3,
    float* __restrict__ q_ring, int slot, const int* __restrict__ flagp)
{
  if (!*flagp) return;
  __shared__ float Ks[4356];
  __shared__ float ls[8][66];
  int tid = threadIdx.x, b0 = blockIdx.x * 8;
  for (int i = tid; i < 4356; i += 256) Ks[i] = K3[i];
  for (int i = tid; i < 8 * 66; i += 256)
    ls[i / 66][i % 66] = src[(size_t)(b0 + i / 66) * sstride + (i % 66)];
  __syncthreads();
  for (int o = tid; o < 528; o += 256) {
    int bi = o / 66, c1 = o % 66;
    float a = 0.f;
    for (int c2 = 0; c2 < 66; ++c2) a = fmaf(Ks[c1 * 66 + c2], ls[bi][c2], a);
    q_ring[((size_t)(b0 + bi) * 10 + slot) * 66 + c1] = a;
  }
}

__global__ __launch_bounds__(256) void fast_combine(
    const float* __restrict__ dp, float* __restrict__ u, float* __restrict__ G,
    float* __restrict__ e, float* __restrict__ s, const int* __restrict__ flagp)
{
  if (!*flagp) return;
  int o = blockIdx.x * 256 + threadIdx.x;
  if (o >= 1024 * 144) return;
  int b = o / 144, c = o % 144;
  float a = 0.f;
  #pragma unroll
  for (int g = 0; g < DPSEG; ++g) a += dp[((size_t)b * 32 + g) * 144 + c];
  if (c < 66) u[b * 66 + c] = a;
  else if (c < 132) G[b * 66 + (c - 66)] = a;
  else if (c == 132) e[b] = a;
  else if (c == 133) s[b] = a;
}

// ---------------------------------------------------------------------------
// tail_kernel v2: fast path = cooperative phase-0 (1 barrier), then wave 0
// runs the Gram + 12-layer recursion + output solo (WSYNC only, no barriers).
// Generic path = round-4 mlp (unchanged). One block per b.
// ---------------------------------------------------------------------------
__global__ __launch_bounds__(256) void tail_kernel(
    const float* __restrict__ hdec, const float* __restrict__ whp,
    float* __restrict__ last, float* __restrict__ l_ring,
    float* __restrict__ q_ring, const float* __restrict__ dp,
    const float* __restrict__ u_whp, const float* __restrict__ G_whp,
    const float* __restrict__ e_whp, const float* __restrict__ s_whp,
    const float* __restrict__ tabs,
    float* __restrict__ wst, const float* __restrict__ encWT,
    const float* __restrict__ encb,
    const float* __restrict__ seqW, const float* __restrict__ seqb,
    const float* __restrict__ lnA, const float* __restrict__ lnB,
    const float* __restrict__ outW, const float* __restrict__ outb,
    const float* __restrict__ mrgW, const float* __restrict__ mrgb,
    int ring0, float* __restrict__ outp,
    unsigned short* __restrict__ lpH, unsigned short* __restrict__ lpL,
    const int* __restrict__ flagp)
{
  const int b = blockIdx.x, tid = threadIdx.x;
  const int lane = tid & 63, wid = tid >> 6;
  const int slot9 = (ring0 == 0) ? 9 : ring0 - 1;   // == (ring0+9)%10

  if (*flagp) {
    // ================= fast path =================
    __shared__ float l_all[10][66], Qv[10][66];
    __shared__ float yd[66], gd[66], uw[66], se1[66], scs[66], lmix[66], newf[66];
    __shared__ float sWall[LL * 156];
    __shared__ float sMa[156], sMb[156], sTt[156], sPp[156], sQq[156];
    __shared__ float sfb[16], sdd[16], swd[16], sistd[16], sccv[16], sVv[16], smrg[16];
    __shared__ float sred[12], misc[8];

    const float* K2T   = tabs + 4356;
    const float* tb_e1 = tabs + 8712;
    const float* tb_cs = tabs + 8778;
    const float* tb_g0 = tabs + 8844;
    const float* tb_R  = tabs + 8910;

    // ---- phase 0 (cooperative, 256 threads) ----
    for (int i = tid; i < 660; i += 256) {
      int w = i / 66, c = i % 66;
      int slot = ring0 + w; if (slot >= 10) slot -= 10;
      Qv[w][c] = q_ring[((size_t)b * 10 + slot) * 66 + c];
      if (w < 9) l_all[w][c] = l_ring[((size_t)b * 10 + slot) * 66 + c];
      else       l_all[9][c] = last[(size_t)b * 66 + c];
    }
    for (int i = tid; i < 66; i += 256) {
      uw[i]  = u_whp[(size_t)b * 66 + i];
      se1[i] = tb_e1[i];
      scs[i] = tb_cs[i];
    }
    for (int i = tid; i < LL * 144; i += 256) {
      int l = i / 144, e = i % 144;
      sWall[l * 156 + (e / 12) * 13 + (e % 12)] = seqW[i];
    }
    if (tid < 134) {
      float a = 0.f;
      #pragma unroll
      for (int g = 0; g < DPSEG; ++g) a += dp[((size_t)b * 32 + g) * 144 + tid];
      if (tid < 66) yd[tid] = a;
      else if (tid < 132) gd[tid - 66] = a;
      else if (tid == 132) misc[1] = a;   // <hdec, encb>
      else misc[2] = a;                   // sum_h hdec
    }
    if (tid == 134) misc[6] = tabs[8976];   // be
    if (tid == 135) misc[7] = tabs[8977];   // sum_encb
    if (tid >= 160 && tid < 172) smrg[tid - 160] = mrgW[tid - 160];
    {
      f32x4 hv = *(const f32x4*)&hdec[(size_t)b * 1024 + tid * 4];
      f32x4 wv = *(const f32x4*)&whp[(size_t)b * 1024 + tid * 4];
      float d2 = hv[0]*hv[0] + hv[1]*hv[1] + hv[2]*hv[2] + hv[3]*hv[3];
      float dw = hv[0]*wv[0] + hv[1]*wv[1] + hv[2]*wv[2] + hv[3]*wv[3];
      float w2 = wv[0]*wv[0] + wv[1]*wv[1] + wv[2]*wv[2] + wv[3]*wv[3];
      d2 = wave_sum63(d2); dw = wave_sum63(dw); w2 = wave_sum63(w2);
      if (lane == 63) { sred[wid*3] = d2; sred[wid*3+1] = dw; sred[wid*3+2] = w2; }
    }
    __syncthreads();
    if (wid != 0) return;   // wave 0 continues alone; no barriers below

    if (lane < 3) misc[3 + lane] = sred[lane] + sred[3 + lane] + sred[6 + lane] + sred[9 + lane];
    WSYNC();

    // ---- phase 1: Gram + fbar + init (entries e = lane, +64, +128) ----
    #pragma unroll
    for (int rep = 0; rep < 3; ++rep) {
      int e = lane + rep * 64;
      if (e < 144) {
        int i = e / 12, j = e % 12;
        float gv;
        if (i == 0 && j == 0) gv = misc[5];
        else if (i == 11 && j == 11) gv = misc[3];
        else if ((i == 0 && j == 11) || (i == 11 && j == 0)) gv = misc[4];
        else if (i == 0 || j == 0) {
          int w = (i == 0 ? j : i) - 1;
          float a = e_whp[b];
          for (int c = 0; c < 66; ++c) a = fmaf(uw[c], l_all[w][c], a);
          gv = a;
        } else if (i == 11 || j == 11) {
          int w = (i == 11 ? j : i) - 1;
          float a = misc[1];
          for (int c = 0; c < 66; ++c) a = fmaf(yd[c], l_all[w][c], a);
          gv = a;
        } else {
          int wi = i - 1, wj = j - 1;
          float a = misc[6];
          for (int c = 0; c < 66; ++c) a = fmaf(se1[c], l_all[wi][c] + l_all[wj][c], a);
          for (int c = 0; c < 66; ++c) a = fmaf(l_all[wi][c], Qv[wj][c], a);
          gv = a;
        }
        sMa[i * 13 + j] = gv * (1.f / 1024.f);
        sTt[i * 13 + j] = (i == j) ? 1.f : 0.f;
      } else if (e < 156) {
        int k = e - 144;
        float fb;
        if (k == 0) fb = s_whp[b] * (1.f / 1024.f);
        else if (k == 11) fb = misc[2] * (1.f / 1024.f);
        else {
          float a = misc[7];
          for (int c = 0; c < 66; ++c) a = fmaf(scs[c], l_all[k - 1][c], a);
          fb = a * (1.f / 1024.f);
        }
        sfb[k] = fb;
        sdd[k] = 0.f;
      }
    }
    WSYNC();

    // ---- phase 2: 12-layer recursion (3 WSYNCs/layer, wave-private) ----
    for (int l = 0; l < LL; ++l) {
      const float* Wl = sWall + l * 156;
      float* Mr = (l & 1) ? sMb : sMa;
      float* Mw = (l & 1) ? sMa : sMb;
      // phase A: P = W*M, Q = W*T, Wd = W*d
      #pragma unroll
      for (int rep = 0; rep < 3; ++rep) {
        int e = lane + rep * 64;
        if (e < 144) {
          int i = e / 12, j = e % 12;
          float ap = 0.f, aq = 0.f;
          #pragma unroll
          for (int k = 0; k < 12; ++k) {
            float wv = Wl[i * 13 + k];
            ap = fmaf(wv, Mr[k * 13 + j], ap);
            aq = fmaf(wv, sTt[k * 13 + j], aq);
          }
          sPp[i * 13 + j] = ap;
          sQq[i * 13 + j] = aq;
        } else if (e < 156) {
          int i = e - 144;
          float a = 0.f;
          #pragma unroll
          for (int k = 0; k < 12; ++k) a = fmaf(Wl[i * 13 + k], sdd[k], a);
          swd[i] = a;
        }
      }
      WSYNC();
      // phase B: stats (lanes 0-11)
      if (lane < 12) {
        int s = lane;
        float bv = seqb[l * 12 + s];
        float mu = bv;
        #pragma unroll
        for (int k = 0; k < 12; ++k) mu = fmaf(Wl[s * 13 + k], sfb[k], mu);
        float e2 = 0.f;
        #pragma unroll
        for (int k = 0; k < 12; ++k) e2 = fmaf(sPp[s * 13 + k], Wl[s * 13 + k], e2);
        float wf = mu - bv;
        float var = fmaxf(e2 - wf * wf, 0.f);
        float is = 1.f / sqrtf(var + 1e-5f);
        sistd[s] = is;
        sccv[s] = is * (bv - mu);
      }
      WSYNC();
      // phase C: T += D*Q ; M' = N + (N*W^T)*D + rank-1 ; d'
      #pragma unroll
      for (int rep = 0; rep < 3; ++rep) {
        int e = lane + rep * 64;
        if (e < 144) {
          int i = e / 12, j = e % 12;
          float Di = sistd[i];
          sTt[i * 13 + j] += Di * sQq[i * 13 + j];
          float p2 = 0.f;
          #pragma unroll
          for (int k = 0; k < 12; ++k) {
            float n_ik = Mr[i * 13 + k] + Di * sPp[i * 13 + k];
            p2 = fmaf(n_ik, Wl[j * 13 + k], p2);
          }
          float n_ij = Mr[i * 13 + j] + Di * sPp[i * 13 + j];
          Mw[i * 13 + j] = n_ij + p2 * sistd[j]
                         + sfb[i] * sccv[j] + sccv[i] * sfb[j] - sccv[i] * sccv[j];
        } else if (e < 156) {
          int i = e - 144;
          sdd[i] = sdd[i] + sistd[i] * swd[i] + sccv[i];
        }
      }
      WSYNC();
    }

    // ---- phase 3: output + q(new frame) ----
    if (lane < 12) {
      float a = 0.f;
      #pragma unroll
      for (int s = 0; s < 12; ++s) a = fmaf(smrg[s], sTt[s * 13 + lane], a);
      sVv[lane] = a;
    }
    if (lane == 12) {
      float a = 0.f;
      for (int s = 0; s < 12; ++s) a = fmaf(smrg[s], sdd[s], a);
      misc[0] = a;  // cv
    }
    WSYNC();
    for (int c = lane; c < 66; c += 64) {
      float a = 0.f;
      #pragma unroll
      for (int w = 0; w < 9; ++w) a = fmaf(sVv[1 + w], l_all[w][c], a);
      a = fmaf(sVv[10], l_all[9][c], a);
      lmix[c] = a;
    }
    WSYNC();
    for (int c = lane; c < 66; c += 64) {
      float vsr = 0.f, smw = 0.f;
      #pragma unroll
      for (int k = 1; k <= 10; ++k) vsr += sVv[k];
      #pragma unroll
      for (int s = 0; s < 12; ++s) smw += smrg[s];
      float lastv = l_all[9][c];
      float acc = sVv[0] * G_whp[(size_t)b * 66 + c]
                + vsr * tb_g0[c]
                + sVv[11] * gd[c]
                + misc[0] * tb_R[c]
                + smw * outb[c] + mrgb[0] + lastv;
      const float* krow = K2T + c * 66;
      for (int c2 = 0; c2 < 66; ++c2) acc = fmaf(lmix[c2], krow[c2], acc);
      outp[(size_t)b * XROW + c] = acc;
      last[(size_t)b * 66 + c] = acc;
      l_ring[((size_t)b * 10 + slot9) * 66 + c] = lastv;
      newf[c] = acc;
      unsigned short hi = f2bf(acc);
      float lo = acc - bf2f(hi);
      int cb = (((c >> 3) & 3) ^ SWROW(b)) & 3;
      size_t dst = (size_t)b * 96 + (size_t)(c & ~31) + cb * 8 + (c & 7);
      lpH[dst] = hi;
      lpL[dst] = f2bf(lo);
    }
    WSYNC();
    for (int c = lane; c < 66; c += 64) {
      float a = 0.f;
      const float* k3r = tabs + c * 66;
      for (int c2 = 0; c2 < 66; ++c2) a = fmaf(k3r[c2], newf[c2], a);
      q_ring[((size_t)b * 10 + ring0) * 66 + c] = a;
    }
    return;
  }

  // ================= generic fallback (round-4 mlp, exact) =================
  __shared__ float red[4][24];
  __shared__ f2 mustd2[SS];
  __shared__ float g_lds[HH];
  __shared__ float nc[CC];

  const int h0 = tid;
  const int h1 = tid + 512;
  const float* lrow = last + (size_t)b * CC;
  f2 wnew[2];
  {
    f2 a0 = { encb[h0], encb[h0 + 256] };
    f2 a1 = { encb[h1], encb[h1 + 256] };
    #pragma unroll 11
    for (int k = 0; k < CC; ++k) {
      float lv = lrow[k];
      f2 lv2 = { lv, lv };
      f2 w0 = { encWT[(size_t)k * HH + h0], encWT[(size_t)k * HH + h0 + 256] };
      f2 w1 = { encWT[(size_t)k * HH + h1], encWT[(size_t)k * HH + h1 + 256] };
      a0 = __builtin_elementwise_fma(lv2, w0, a0);
      a1 = __builtin_elementwise_fma(lv2, w1, a1);
    }
    wnew[0] = a0; wnew[1] = a1;
    float* wd = wst + ((size_t)b * 10 + slot9) * HH;
    wd[h0] = a0.x; wd[h0 + 256] = a0.y;
    wd[h1] = a1.x; wd[h1 + 256] = a1.y;
  }

  f2 fr[2][SS];
  {
    const float* whb = whp + (size_t)b * HH;
    const float* hb  = hdec + (size_t)b * HH;
    fr[0][0]  = { whb[h0], whb[h0 + 256] };
    fr[1][0]  = { whb[h1], whb[h1 + 256] };
    fr[0][11] = { hb[h0], hb[h0 + 256] };
    fr[1][11] = { hb[h1], hb[h1 + 256] };
    #pragma unroll
    for (int w = 0; w < 9; ++w) {
      int slot = ring0 + w; if (slot >= 10) slot -= 10;
      const float* ws_ = wst + ((size_t)b * 10 + slot) * HH;
      fr[0][1 + w] = { ws_[h0], ws_[h0 + 256] };
      fr[1][1 + w] = { ws_[h1], ws_[h1 + 256] };
    }
    fr[0][10] = wnew[0];
    fr[1][10] = wnew[1];
  }

  #pragma unroll 1
  for (int l = 0; l < LL; ++l) {
    const float* W  = seqW + (size_t)l * SS * SS;
    const float* Bv = seqb + (size_t)l * SS;
    const float* lA = lnA + (size_t)l * HH;
    const float* lB = lnB + (size_t)l * HH;
    f2 al[2], be[2];
    al[0] = { lA[h0], lA[h0 + 256] };  al[1] = { lA[h1], lA[h1 + 256] };
    be[0] = { lB[h0], lB[h0 + 256] };  be[1] = { lB[h1], lB[h1 + 256] };

    f2 y[2][SS];
    #pragma unroll
    for (int s = 0; s < SS; ++s) {
      float bv = Bv[s];
      f2 a0 = { bv, bv }, a1 = { bv, bv };
      #pragma unroll
      for (int k = 0; k < SS; ++k) {
        float wv = W[s * SS + k];
        f2 wv2 = { wv, wv };
        a0 = __builtin_elementwise_fma(fr[0][k], wv2, a0);
        a1 = __builtin_elementwise_fma(fr[1][k], wv2, a1);
      }
      y[0][s] = a0; y[1][s] = a1;
      f2 pp = a0 + a1;
      float ps = wave_sum63(pp.x + pp.y);
      f2 qq = __builtin_elementwise_fma(a0, a0, a1 * a1);
      float pq = wave_sum63(qq.x + qq.y);
      if (lane == 63) { red[wid][s] = ps; red[wid][12 + s] = pq; }
    }
    __syncthreads();
    if (tid < SS) {
      float S = red[0][tid] + red[1][tid] + red[2][tid] + red[3][tid];
      float Q = red[0][12 + tid] + red[1][12 + tid] + red[2][12 + tid] + red[3][12 + tid];
      float mu = S * (1.f / HH);
      float var = Q * (1.f / HH) - mu * mu;
      mustd2[tid] = { mu, 1.f / sqrtf(var + 1e-5f) };
    }
    __syncthreads();
    #pragma unroll
    for (int s = 0; s < SS; ++s) {
      f2 mi = mustd2[s];
      f2 mus = { mi.x, mi.x };
      f2 isd = { mi.y, mi.y };
      #pragma unroll
      for (int p = 0; p < 2; ++p) {
        f2 t = (y[p][s] - mus) * isd;
        fr[p][s] = __builtin_elementwise_fma(t, al[p], fr[p][s]) + be[p];
      }
    }
    __syncthreads();
  }

  float smw = 0.f;
  f2 g[2] = { {0.f, 0.f}, {0.f, 0.f} };
  #pragma unroll
  for (int s = 0; s < SS; ++s) {
    float mv = mrgW[s];
    smw += mv;
    f2 mv2 = { mv, mv };
    g[0] = __builtin_elementwise_fma(mv2, fr[0][s], g[0]);
    g[1] = __builtin_elementwise_fma(mv2, fr[1][s], g[1]);
  }
  g_lds[h0] = g[0].x; g_lds[h0 + 256] = g[0].y;
  g_lds[h1] = g[1].x; g_lds[h1 + 256] = g[1].y;
  const float mbv = mrgb[0];
  __syncthreads();
  #pragma unroll 1
  for (int i = 0; i < 17; ++i) {
    int c = wid + 4 * i;
    if (c < CC) {
      const float* ow = outW + (size_t)c * HH;
      float acc = 0.f;
      #pragma unroll
      for (int q = 0; q < 16; ++q) acc = fmaf(g_lds[lane + q * 64], ow[lane + q * 64], acc);
      acc = wave_sum63(acc);
      if (lane == 63) nc[c] = acc + outb[c] * smw + mbv + lrow[c];
    }
  }
  __syncthreads();
  if (tid < CC) {
    float nv = nc[tid];
    outp[(size_t)b * XROW + tid] = nv;
    last[(size_t)b * CC + tid] = nv;
    unsigned short hi = f2bf(nv);
    float lo = nv - bf2f(hi);
    int cb = (((tid >> 3) & 3) ^ SWROW(b)) & 3;
    size_t dst = (size_t)b * 96 + (size_t)(tid & ~31) + cb * 8 + (tid & 7);
    lpH[dst] = hi;
    lpL[dst] = f2bf(lo);
  }
}

// ---------------------------------------------------------------------------
extern "C" void kernel_launch(void* const* d_in, const int* in_sizes, int n_in,
                              void* d_out, int out_size, void* d_ws, size_t ws_size,
                              hipStream_t stream) {
  const float* x    = (const float*)d_in[0];
  const float* gWi  = (const float*)d_in[1];
  const float* gWh  = (const float*)d_in[2];
  const float* gbi  = (const float*)d_in[3];
  const float* gbh  = (const float*)d_in[4];
  const float* encW = (const float*)d_in[5];
  const float* encb = (const float*)d_in[6];
  const float* seqW = (const float*)d_in[7];
  const float* seqb = (const float*)d_in[8];
  const float* lnA  = (const float*)d_in[9];
  const float* lnB  = (const float*)d_in[10];
  const float* outW = (const float*)d_in[11];
  const float* outb = (const float*)d_in[12];
  const float* mrgW = (const float*)d_in[13];
  const float* mrgb = (const float*)d_in[14];
  float* out = (float*)d_out;

  char* p = (char*)d_ws;
  auto alloc = [&](size_t bytes) { char* r = p; p += (bytes + 255) & ~(size_t)255; return r; };
  float* encWT = (float*)alloc((size_t)CC * HH * 4);
  float* last  = (float*)alloc((size_t)BB * CC * 4);
  float* wst   = (float*)alloc((size_t)BB * 10 * HH * 4);   // generic ring / fast overlay
  float* hf[3];
  for (int i = 0; i < 3; ++i) hf[i] = (float*)alloc((size_t)BB * HH * 4);
  unsigned short* WgH = (unsigned short*)alloc((size_t)4096 * 1120 * 2);
  unsigned short* WgL = (unsigned short*)alloc((size_t)4096 * 1120 * 2);
  unsigned short* XaH = (unsigned short*)alloc((size_t)TT * BB * 96 * 2);
  unsigned short* XaL = (unsigned short*)alloc((size_t)TT * BB * 96 * 2);
  unsigned short* hhi[3]; unsigned short* hlo[3];
  for (int i = 0; i < 3; ++i) {
    hhi[i] = (unsigned short*)alloc((size_t)BB * HH * 2);
    hlo[i] = (unsigned short*)alloc((size_t)BB * HH * 2);
  }
  unsigned short* lpH = (unsigned short*)alloc((size_t)BB * 96 * 2);
  unsigned short* lpL = (unsigned short*)alloc((size_t)BB * 96 * 2);
  int* flag = (int*)alloc(256);
  if ((size_t)(p - (char*)d_ws) > ws_size) return;  // insufficient workspace

  // fast-path overlay inside the wst region (mutually exclusive by flag)
  char* ov = (char*)wst;
  float* B144  = (float*)ov;                 ov += (size_t)1024 * 144 * 4;
  float* dp32  = (float*)ov;                 ov += (size_t)DPSEG * 1024 * 144 * 4;  // 18.9 MB
  float* l_ring= (float*)ov;                 ov += (size_t)1024 * 10 * 66 * 4;
  float* q_ring= (float*)ov;                 ov += (size_t)1024 * 10 * 66 * 4;
  float* u_whp = (float*)ov;                 ov += (size_t)1024 * 66 * 4;
  float* G_whp = (float*)ov;                 ov += (size_t)1024 * 66 * 4;
  float* e_whp = (float*)ov;                 ov += 4096;
  float* s_whp = (float*)ov;                 ov += 4096;
  float* tabs  = (float*)ov;                 ov += 9216 * 4;

  // ---- one-time prep ----
  hipMemsetAsync(flag, 0xFF, 4, stream);
  flag_kernel<<<dim3(96), 256, 0, stream>>>(lnA, lnB, flag);
  prep_wgc<<<dim3((4096u * 1120u) / 256u), 256, 0, stream>>>(gWh, gWi, WgH, WgL);
  prep_xall<<<dim3(((unsigned)TT * BB * 96) / 256u), 256, 0, stream>>>(x, XaH, XaL);
  transpose_encW<<<dim3(CC, HH/256), 256, 0, stream>>>(encW, encWT);
  copy_last_kernel<<<dim3((BB*CC + 255)/256), 256, 0, stream>>>(x, last);
  prep_b144<<<dim3(576), 256, 0, stream>>>(encW, outW, encb, B144);
  prep_tabs<<<dim3(2245), 256, 0, stream>>>(encW, encb, outW, tabs);
  linit_kernel<<<dim3((1024*9*66)/256), 256, 0, stream>>>(x, l_ring, flag);
  for (int w = 0; w < 10; ++w)   // slots 0..9 = q(x[54..63])
    qnew_kernel<<<dim3(128), 256, 0, stream>>>(x + (size_t)(54 + w) * CC, XROW,
                                               tabs, q_ring, w, flag);
  hipMemsetAsync(hf[0], 0, (size_t)BB * HH * 4, stream);
  hipMemsetAsync(hhi[0], 0, (size_t)BB * HH * 2, stream);
  hipMemsetAsync(hlo[0], 0, (size_t)BB * HH * 2, stream);

  const dim3 ggrid(512);

  // ---- encoder: 63 GRU steps (no dp) ----
  int cur = 0;
  for (int t = 0; t < 63; ++t) {
    int nxt = 1 - cur;
    gru_mfma<<<ggrid, 256, 0, stream>>>(
        hhi[cur], hlo[cur], hf[cur],
        XaH + (size_t)t * BB * 96, XaL + (size_t)t * BB * 96,
        WgH, WgL, gbi, gbh, hf[nxt], hhi[nxt], hlo[nxt],
        B144, dp32, flag, 0);
    cur = nxt;
  }
  // window_history GRU -> hf[2], with fused dp
  gru_mfma<<<ggrid, 256, 0, stream>>>(
      hhi[cur], hlo[cur], hf[cur],
      XaH + (size_t)63 * BB * 96, XaL + (size_t)63 * BB * 96,
      WgH, WgL, gbi, gbh, hf[2], hhi[2], hlo[2],
      B144, dp32, flag, 1);

  // whp-derived persistent fast-path arrays
  fast_combine<<<dim3(576), 256, 0, stream>>>(dp32, u_whp, G_whp, e_whp, s_whp, flag);

  // generic-path wst init (skipped when fast)
  for (int w = 0; w < 9; ++w)
    wst_row_kernel<<<dim3(HH/256, BB), 256, 0, stream>>>(
        x + (size_t)(54 + w) * CC, XROW, encWT, encb, wst + (size_t)w * HH, flag);

  // ---- decoder: 64 steps, 2 launches each ----
  int hc = 2;
  for (int t = 0; t < 64; ++t) {
    if (t > 0) {
      int hn = (t - 1) & 1;
      gru_mfma<<<ggrid, 256, 0, stream>>>(
          hhi[hc], hlo[hc], hf[hc], lpH, lpL,
          WgH, WgL, gbi, gbh, hf[hn], hhi[hn], hlo[hn],
          B144, dp32, flag, 1);
      hc = hn;
    }
    tail_kernel<<<dim3(BB), 256, 0, stream>>>(
        hf[hc], hf[2], last, l_ring, q_ring, dp32,
        u_whp, G_whp, e_whp, s_whp, tabs,
        wst, encWT, encb, seqW, seqb, lnA, lnB, outW, outb, mrgW, mrgb,
        t % 10, out + (size_t)t * CC, lpH, lpL, flag);
  }
}